// Round 1
// baseline (5271.988 us; speedup 1.0000x reference)
//
#include <hip/hip_runtime.h>
#include <math.h>

#define N_ENT   100000
#define N_REL2  1000
#define E_TOT   500000
#define E_HALF  250000
#define DIM     200
#define BB      256
#define NFILT   200
#define FLATK   39200
#define EPS_BN  1e-5f

// ---------------------------------------------------------------------------
// scatter: for each edge, atomically add (x[src] - r[etype]) into agg[dst].
// First half of edges -> bufA/degI (w_in side), second half -> bufB/degO.
// Work item = (edge, float4-group); 50 groups per 200-dim row.
// ---------------------------------------------------------------------------
__global__ void scatter_kernel(const float* __restrict__ x, const float* __restrict__ r,
                               const int* __restrict__ ei, const int* __restrict__ et,
                               float* __restrict__ bufA, float* __restrict__ bufB,
                               float* __restrict__ degI, float* __restrict__ degO) {
    unsigned g = blockIdx.x * 256u + threadIdx.x;
    unsigned e = g / 50u;
    unsigned f = g - e * 50u;
    if (e >= E_TOT) return;
    int s = ei[e];
    int d = ei[E_TOT + e];
    int t = et[e];
    const float4 xv = *(const float4*)(x + (size_t)s * DIM + f * 4);
    const float4 rv = *(const float4*)(r + (size_t)t * DIM + f * 4);
    float* dst = (e < E_HALF ? bufA : bufB) + (size_t)d * DIM + f * 4;
    atomicAdd(dst + 0, xv.x - rv.x);
    atomicAdd(dst + 1, xv.y - rv.y);
    atomicAdd(dst + 2, xv.z - rv.z);
    atomicAdd(dst + 3, xv.w - rv.w);
    if (f == 0) atomicAdd((e < E_HALF ? degI : degO) + d, 1.0f);
}

// ---------------------------------------------------------------------------
// lv = loop_rel @ w_loop   (one 200-vector)
// ---------------------------------------------------------------------------
__global__ void lv_kernel(const float* __restrict__ lr, const float* __restrict__ wl,
                          float* __restrict__ lv) {
    int j = blockIdx.x * blockDim.x + threadIdx.x;
    if (j >= DIM) return;
    float acc = 0.f;
    for (int k = 0; k < DIM; ++k) acc += lr[k] * wl[k * DIM + j];
    lv[j] = acc;
}

// ---------------------------------------------------------------------------
// r_out = r_in @ w   [rows x 200] @ [200 x 200], tiny (rows=1000)
// ---------------------------------------------------------------------------
__global__ void rgemm_kernel(const float* __restrict__ r, const float* __restrict__ w,
                             float* __restrict__ out, int rows) {
    int g = blockIdx.x * 256 + threadIdx.x;
    if (g >= rows * DIM) return;
    int i = g / DIM, j = g - i * DIM;
    float acc = 0.f;
    for (int k = 0; k < DIM; ++k) acc += r[i * DIM + k] * w[k * DIM + j];
    out[g] = acc;
}

// ---------------------------------------------------------------------------
// fused layer GEMM:
//   out = tanh( ((aggI/degI)@wIn + (aggO/degO)@wOut + xin@wLoop - lv)/3 + bias )
// tile: 64 rows x 200 cols, 256 threads, thread = 2 rows x 25 cols.
// Safe to call with out == aggI (rows are read fully before the final write,
// and no block touches another block's rows).
// ---------------------------------------------------------------------------
__global__ void layer_kernel(const float* __restrict__ aggI, const float* __restrict__ aggO,
                             const float* __restrict__ xin,
                             const float* __restrict__ degI, const float* __restrict__ degO,
                             const float* __restrict__ wIn, const float* __restrict__ wOut,
                             const float* __restrict__ wLoop,
                             const float* __restrict__ lv, const float* __restrict__ bias,
                             float* __restrict__ out) {
    __shared__ float A[64][9];     // +1 pad breaks 4-way bank conflict
    __shared__ float W[8][200];
    const int tid  = threadIdx.x;
    const int row0 = blockIdx.x * 64;
    const int r2   = tid >> 3;     // 0..31 -> rows 2*r2, 2*r2+1
    const int cg   = tid & 7;      // 0..7  -> cols cg*25 .. +24

    float acc[2][25];
#pragma unroll
    for (int i = 0; i < 2; ++i)
#pragma unroll
        for (int c = 0; c < 25; ++c) acc[i][c] = 0.f;

    for (int p = 0; p < 3; ++p) {
        const float* Ap = (p == 0) ? aggI : (p == 1) ? aggO : xin;
        const float* Wp = (p == 0) ? wIn  : (p == 1) ? wOut : wLoop;
        const float* dg = (p == 0) ? degI : degO;
        for (int k0 = 0; k0 < DIM; k0 += 8) {
            __syncthreads();
            // stage A: 64 rows x 8 k
            for (int idx = tid; idx < 512; idx += 256) {
                int rr = idx >> 3, kk = idx & 7;
                int grow = row0 + rr;
                float v = 0.f;
                if (grow < N_ENT) {
                    v = Ap[(size_t)grow * DIM + k0 + kk];
                    if (p < 2) v *= 1.0f / fmaxf(dg[grow], 1.0f);
                }
                A[rr][kk] = v;
            }
            // stage W: 8 k x 200 cols
            for (int idx = tid; idx < 1600; idx += 256) {
                int kk = idx / 200, col = idx - kk * 200;
                W[kk][col] = Wp[(k0 + kk) * DIM + col];
            }
            __syncthreads();
#pragma unroll
            for (int kk = 0; kk < 8; ++kk) {
                float a0 = A[2 * r2][kk], a1 = A[2 * r2 + 1][kk];
#pragma unroll
                for (int c = 0; c < 25; ++c) {
                    float w = W[kk][cg * 25 + c];
                    acc[0][c] += a0 * w;
                    acc[1][c] += a1 * w;
                }
            }
        }
    }
#pragma unroll
    for (int i = 0; i < 2; ++i) {
        int grow = row0 + 2 * r2 + i;
        if (grow < N_ENT) {
#pragma unroll
            for (int c = 0; c < 25; ++c) {
                int col = cg * 25 + c;
                float v = (acc[i][c] - lv[col]) * (1.0f / 3.0f) + bias[col];
                out[(size_t)grow * DIM + col] = tanhf(v);
            }
        }
    }
}

// ---------------------------------------------------------------------------
// build ConvE input images with BN0: img[b][l], l = h*20+w, value from
// sub_emb (l even) or rel_emb (l odd), channel index d = l>>1.
// ---------------------------------------------------------------------------
__global__ void img_kernel(const float* __restrict__ x, const float* __restrict__ r,
                           const int* __restrict__ sub, const int* __restrict__ rel,
                           const float* __restrict__ bn0g, const float* __restrict__ bn0b,
                           float* __restrict__ img) {
    int g = blockIdx.x * 256 + threadIdx.x;
    if (g >= BB * 2 * DIM) return;
    int b = g / 400, l = g - b * 400;
    int d = l >> 1;
    float v = (l & 1) ? r[(size_t)rel[b] * DIM + d] : x[(size_t)sub[b] * DIM + d];
    float s0 = bn0g[0] * rsqrtf(1.0f + EPS_BN);
    img[g] = v * s0 + bn0b[0];
}

// ---------------------------------------------------------------------------
// conv 7x7 valid + bias + BN1 + relu. Block = (filter f, group of 64 batches).
// Output transposed: out_t[k][b], k = f*196 + h*14 + w  (fc-friendly layout).
// ---------------------------------------------------------------------------
__global__ void conv_kernel(const float* __restrict__ img, const float* __restrict__ cw,
                            const float* __restrict__ cb, const float* __restrict__ bn1g,
                            const float* __restrict__ bn1b, float* __restrict__ out_t) {
    __shared__ float im[64][401];   // pad 401: 17*b_l mod 32 -> conflict-free-ish
    __shared__ float wt[49];
    const int f  = blockIdx.x >> 2;
    const int b0 = (blockIdx.x & 3) * 64;
    const int tid = threadIdx.x;
    if (tid < 49) wt[tid] = cw[f * 49 + tid];
    for (int idx = tid; idx < 64 * 400; idx += 256) {
        int bb = idx / 400, l = idx - bb * 400;
        im[bb][l] = img[(size_t)(b0 + bb) * 400 + l];
    }
    __syncthreads();
    const float s1 = bn1g[f] * rsqrtf(1.0f + EPS_BN);
    const float t1 = bn1b[f];
    const float cbf = cb[f];
    const int b_l = tid & 63;
    const int oq  = tid >> 6;   // 0..3, 49 positions each
    for (int q = 0; q < 49; ++q) {
        int p = oq * 49 + q;
        int h = p / 14, w2 = p - h * 14;
        float s = 0.f;
#pragma unroll
        for (int i = 0; i < 7; ++i)
#pragma unroll
            for (int j = 0; j < 7; ++j)
                s += im[b_l][(h + i) * 20 + (w2 + j)] * wt[i * 7 + j];
        float v = fmaxf((s + cbf) * s1 + t1, 0.f);
        out_t[(size_t)(f * 196 + p) * BB + b0 + b_l] = v;
    }
}

// ---------------------------------------------------------------------------
// fc partial GEMM: acc_t[j][b] += sum_k out_t[k][b] * fc_w[k][j]
// grid = 98 k-chunks (400 k each) x 4 col-groups (50 cols). thread = one b.
// ---------------------------------------------------------------------------
__global__ void fc_kernel(const float* __restrict__ xt, const float* __restrict__ fw,
                          float* __restrict__ acc_t) {
    __shared__ float w[100][50];
    const int kc = blockIdx.x >> 2;
    const int j0 = (blockIdx.x & 3) * 50;
    const int b  = threadIdx.x;
    float acc[50];
#pragma unroll
    for (int c = 0; c < 50; ++c) acc[c] = 0.f;
    for (int ks = 0; ks < 4; ++ks) {
        int k0 = kc * 400 + ks * 100;
        __syncthreads();
        for (int idx = b; idx < 5000; idx += 256) {
            int kk = idx / 50, jj = idx - kk * 50;
            w[kk][jj] = fw[(size_t)(k0 + kk) * DIM + j0 + jj];
        }
        __syncthreads();
        for (int kk = 0; kk < 100; ++kk) {
            float xv = xt[(size_t)(k0 + kk) * BB + b];
#pragma unroll
            for (int c = 0; c < 50; ++c) acc[c] += xv * w[kk][c];
        }
    }
    for (int c = 0; c < 50; ++c)
        atomicAdd(&acc_t[(size_t)(j0 + c) * BB + b], acc[c]);
}

// h_t[j][b] = relu( (acc + fc_b) * bn2_scale + bn2_b )
__global__ void fc_epi_kernel(const float* __restrict__ acc_t, const float* __restrict__ fcb,
                              const float* __restrict__ g2, const float* __restrict__ b2v,
                              float* __restrict__ h_t) {
    int g = blockIdx.x * 256 + threadIdx.x;
    if (g >= DIM * BB) return;
    int j = g >> 8;
    float v = (acc_t[g] + fcb[j]) * (g2[j] * rsqrtf(1.0f + EPS_BN)) + b2v[j];
    h_t[g] = fmaxf(v, 0.f);
}

// ---------------------------------------------------------------------------
// logits: out[b][n] = sigmoid( h[b]·x[n] + ent_bias[n] )
// tile 64 ents x 128 b; thread = 4 ents x 8 b.
// ---------------------------------------------------------------------------
__global__ void logits_kernel(const float* __restrict__ x, const float* __restrict__ ht,
                              const float* __restrict__ eb, float* __restrict__ out) {
    __shared__ float xs[64][9];
    __shared__ float hs[8][128];
    const int tid = threadIdx.x;
    const int e0 = (blockIdx.x >> 1) * 64;
    const int b0 = (blockIdx.x & 1) * 128;
    const int et = tid & 15;    // 16 ent-groups x 4
    const int bt = tid >> 4;    // 16 b-groups x 8
    float acc[4][8];
#pragma unroll
    for (int i = 0; i < 4; ++i)
#pragma unroll
        for (int j = 0; j < 8; ++j) acc[i][j] = 0.f;

    for (int k0 = 0; k0 < DIM; k0 += 8) {
        __syncthreads();
        for (int idx = tid; idx < 512; idx += 256) {
            int ee = idx >> 3, kk = idx & 7;
            int ge = e0 + ee;
            xs[ee][kk] = (ge < N_ENT) ? x[(size_t)ge * DIM + k0 + kk] : 0.f;
        }
        for (int idx = tid; idx < 1024; idx += 256) {
            int kk = idx >> 7, bbx = idx & 127;
            hs[kk][bbx] = ht[(size_t)(k0 + kk) * BB + b0 + bbx];
        }
        __syncthreads();
#pragma unroll
        for (int kk = 0; kk < 8; ++kk) {
            float a[4], hb[8];
#pragma unroll
            for (int i = 0; i < 4; ++i) a[i] = xs[et * 4 + i][kk];
#pragma unroll
            for (int j = 0; j < 8; ++j) hb[j] = hs[kk][bt * 8 + j];
#pragma unroll
            for (int i = 0; i < 4; ++i)
#pragma unroll
                for (int j = 0; j < 8; ++j) acc[i][j] += a[i] * hb[j];
        }
    }
#pragma unroll
    for (int i = 0; i < 4; ++i) {
        int n = e0 + et * 4 + i;
        if (n < N_ENT) {
            float bias = eb[n];
#pragma unroll
            for (int j = 0; j < 8; ++j) {
                float v = acc[i][j] + bias;
                out[(size_t)(b0 + bt * 8 + j) * N_ENT + n] = 1.0f / (1.0f + expf(-v));
            }
        }
    }
}

// ---------------------------------------------------------------------------
extern "C" void kernel_launch(void* const* d_in, const int* in_sizes, int n_in,
                              void* d_out, int out_size, void* d_ws, size_t ws_size,
                              hipStream_t stream) {
    const int*   sub        = (const int*)  d_in[0];
    const int*   rel        = (const int*)  d_in[1];
    const int*   edge_index = (const int*)  d_in[2];
    const int*   edge_type  = (const int*)  d_in[3];
    const float* init_embed = (const float*)d_in[4];
    const float* init_rel   = (const float*)d_in[5];
    const float* loop_rel1  = (const float*)d_in[6];
    const float* loop_rel2  = (const float*)d_in[7];
    const float* w_in1      = (const float*)d_in[8];
    const float* w_out1     = (const float*)d_in[9];
    const float* w_loop1    = (const float*)d_in[10];
    const float* w_rel1     = (const float*)d_in[11];
    const float* b1         = (const float*)d_in[12];
    const float* w_in2      = (const float*)d_in[13];
    const float* w_out2     = (const float*)d_in[14];
    const float* w_loop2    = (const float*)d_in[15];
    const float* w_rel2     = (const float*)d_in[16];
    const float* b2         = (const float*)d_in[17];
    const float* conv_w     = (const float*)d_in[18];
    const float* conv_b     = (const float*)d_in[19];
    const float* bn0_g      = (const float*)d_in[20];
    const float* bn0_b      = (const float*)d_in[21];
    const float* bn1_g      = (const float*)d_in[22];
    const float* bn1_b      = (const float*)d_in[23];
    const float* bn2_g      = (const float*)d_in[24];
    const float* bn2_b      = (const float*)d_in[25];
    const float* fc_w       = (const float*)d_in[26];
    const float* fc_b       = (const float*)d_in[27];
    const float* ent_bias   = (const float*)d_in[28];

    float* ws   = (float*)d_ws;
    float* bufA = ws;                       // 20,000,000  (agg_in; layer-2 output in-place)
    float* bufB = bufA + 20000000;          // 20,000,000  (agg_out)
    float* bufX = bufB + 20000000;          // 20,000,000  (x1)
    float* degI = bufX + 20000000;          // 100,000
    float* degO = degI + 100000;            // 100,000
    float* r1   = degO + 100000;            // 200,000
    float* r2   = r1   + 200000;            // 200,000
    float* lv   = r2   + 200000;            // 256
    float* img  = lv   + 256;               // 102,400
    float* outT = img  + 102400;            // 10,035,200
    float* accT = outT + 10035200;          // 51,200
    float* hT   = accT + 51200;             // 51,200

    const int scatter_blocks = (E_TOT * 50 + 255) / 256;
    const int layer_blocks   = (N_ENT + 63) / 64;

    // ---- layer 1 ----
    hipMemsetAsync(bufA, 0, (size_t)20000000 * 4, stream);
    hipMemsetAsync(bufB, 0, (size_t)20000000 * 4, stream);
    hipMemsetAsync(degI, 0, (size_t)200000 * 4, stream);   // degI+degO contiguous
    scatter_kernel<<<scatter_blocks, 256, 0, stream>>>(init_embed, init_rel, edge_index,
                                                       edge_type, bufA, bufB, degI, degO);
    lv_kernel<<<1, 256, 0, stream>>>(loop_rel1, w_loop1, lv);
    layer_kernel<<<layer_blocks, 256, 0, stream>>>(bufA, bufB, init_embed, degI, degO,
                                                   w_in1, w_out1, w_loop1, lv, b1, bufX);
    rgemm_kernel<<<(N_REL2 * DIM + 255) / 256, 256, 0, stream>>>(init_rel, w_rel1, r1, N_REL2);

    // ---- layer 2 ----
    hipMemsetAsync(bufA, 0, (size_t)20000000 * 4, stream);
    hipMemsetAsync(bufB, 0, (size_t)20000000 * 4, stream);
    hipMemsetAsync(degI, 0, (size_t)200000 * 4, stream);
    scatter_kernel<<<scatter_blocks, 256, 0, stream>>>(bufX, r1, edge_index, edge_type,
                                                       bufA, bufB, degI, degO);
    lv_kernel<<<1, 256, 0, stream>>>(loop_rel2, w_loop2, lv);
    layer_kernel<<<layer_blocks, 256, 0, stream>>>(bufA, bufB, bufX, degI, degO,
                                                   w_in2, w_out2, w_loop2, lv, b2, bufA);
    rgemm_kernel<<<(N_REL2 * DIM + 255) / 256, 256, 0, stream>>>(r1, w_rel2, r2, N_REL2);

    // ---- ConvE ----
    img_kernel<<<(BB * 400 + 255) / 256, 256, 0, stream>>>(bufA, r2, sub, rel,
                                                           bn0_g, bn0_b, img);
    conv_kernel<<<NFILT * 4, 256, 0, stream>>>(img, conv_w, conv_b, bn1_g, bn1_b, outT);
    hipMemsetAsync(accT, 0, (size_t)51200 * 4, stream);
    fc_kernel<<<98 * 4, 256, 0, stream>>>(outT, fc_w, accT);
    fc_epi_kernel<<<(DIM * BB + 255) / 256, 256, 0, stream>>>(accT, fc_b, bn2_g, bn2_b, hT);

    // ---- logits ----
    logits_kernel<<<layer_blocks * 2, 256, 0, stream>>>(bufA, hT, ent_bias, (float*)d_out);
}

// Round 2
// 2628.274 us; speedup vs baseline: 2.0059x; 2.0059x over previous
//
#include <hip/hip_runtime.h>
#include <math.h>

#define N_ENT   100000
#define N_REL2  1000
#define E_TOT   500000
#define E_HALF  250000
#define DIM     200
#define BB      256
#define NFILT   200
#define FLATK   39200
#define EPS_BN  1e-5f

#define NROWS   200000          // 100k in-rows + 100k out-rows
#define SCHUNK  2048
#define SNBLK   ((NROWS + SCHUNK - 1) / SCHUNK)   // 98

// ---------------------------------------------------------------------------
// CSR build: histogram -> scan -> fill. Row id = dst + (e<E_HALF ? 0 : N_ENT).
// ---------------------------------------------------------------------------
__global__ void hist_kernel(const int* __restrict__ ei, int* __restrict__ cnt) {
    int e = blockIdx.x * 256 + threadIdx.x;
    if (e >= E_TOT) return;
    int row = ei[E_TOT + e] + (e < E_HALF ? 0 : N_ENT);
    atomicAdd(&cnt[row], 1);
}

__global__ void scan1_kernel(const int* __restrict__ cnt, int* __restrict__ row_start,
                             int* __restrict__ blockSum) {
    __shared__ int tsum[256];
    const int t = threadIdx.x;
    const int base = blockIdx.x * SCHUNK + t * 8;
    int v[8];
    int s = 0;
#pragma unroll
    for (int i = 0; i < 8; ++i) {
        int idx = base + i;
        int c = (idx < NROWS) ? cnt[idx] : 0;
        v[i] = s;
        s += c;
    }
    tsum[t] = s;
    __syncthreads();
    for (int off = 1; off < 256; off <<= 1) {
        int x = (t >= off) ? tsum[t - off] : 0;
        __syncthreads();
        if (t >= off) tsum[t] += x;
        __syncthreads();
    }
    int texc = (t == 0) ? 0 : tsum[t - 1];
    if (t == 0) blockSum[blockIdx.x] = tsum[255];
#pragma unroll
    for (int i = 0; i < 8; ++i) {
        int idx = base + i;
        if (idx < NROWS) row_start[idx] = texc + v[i];
    }
}

__global__ void scan2_kernel(int* __restrict__ blockSum) {
    int s = 0;
    for (int i = 0; i < SNBLK; ++i) { int c = blockSum[i]; blockSum[i] = s; s += c; }
}

__global__ void scan3_kernel(int* __restrict__ row_start, int* __restrict__ row_cur,
                             const int* __restrict__ blockSum) {
    int i = blockIdx.x * 256 + threadIdx.x;
    if (i >= NROWS) return;
    int v = row_start[i] + blockSum[i / SCHUNK];
    row_start[i] = v;
    row_cur[i] = v;
}

__global__ void fill_kernel(const int* __restrict__ ei, const int* __restrict__ et,
                            int* __restrict__ row_cur,
                            int* __restrict__ esrc, int* __restrict__ eet) {
    int e = blockIdx.x * 256 + threadIdx.x;
    if (e >= E_TOT) return;
    int row = ei[E_TOT + e] + (e < E_HALF ? 0 : N_ENT);
    int pos = atomicAdd(&row_cur[row], 1);
    esrc[pos] = ei[e];
    eet[pos] = et[e];
}

// ---------------------------------------------------------------------------
// gather: one wave per CSR row. Lanes 0..49 each own one float4 chunk of the
// 200-dim row; loop over the row's edges summing x[src]-r[et]; write the
// degree-normalized row once (rows with deg 0 get zeros -> no memset needed).
// agg spans bufA (rows 0..N_ENT) then bufB (rows N_ENT..2*N_ENT), contiguous.
// ---------------------------------------------------------------------------
__global__ void gather_kernel(const float* __restrict__ x, const float* __restrict__ r,
                              const int* __restrict__ esrc, const int* __restrict__ eet,
                              const int* __restrict__ row_start, const int* __restrict__ cnt,
                              float* __restrict__ agg) {
    int wid = blockIdx.x * 4 + (threadIdx.x >> 6);
    if (wid >= NROWS) return;
    int lane = threadIdx.x & 63;
    if (lane >= 50) return;
    int start = row_start[wid];
    int deg = cnt[wid];
    float ax = 0.f, ay = 0.f, az = 0.f, aw = 0.f;
    for (int i = 0; i < deg; ++i) {
        int s = esrc[start + i];
        int t = eet[start + i];
        const float4 xv = *(const float4*)(x + (size_t)s * DIM + lane * 4);
        const float4 rv = *(const float4*)(r + (size_t)t * DIM + lane * 4);
        ax += xv.x - rv.x;
        ay += xv.y - rv.y;
        az += xv.z - rv.z;
        aw += xv.w - rv.w;
    }
    float sc = 1.0f / fmaxf((float)deg, 1.0f);
    float4 o;
    o.x = ax * sc; o.y = ay * sc; o.z = az * sc; o.w = aw * sc;
    *(float4*)(agg + (size_t)wid * DIM + lane * 4) = o;
}

// ---------------------------------------------------------------------------
// lv = loop_rel @ w_loop   (one 200-vector)
// ---------------------------------------------------------------------------
__global__ void lv_kernel(const float* __restrict__ lr, const float* __restrict__ wl,
                          float* __restrict__ lv) {
    int j = blockIdx.x * blockDim.x + threadIdx.x;
    if (j >= DIM) return;
    float acc = 0.f;
    for (int k = 0; k < DIM; ++k) acc += lr[k] * wl[k * DIM + j];
    lv[j] = acc;
}

// ---------------------------------------------------------------------------
// r_out = r_in @ w   [rows x 200] @ [200 x 200], tiny (rows=1000)
// ---------------------------------------------------------------------------
__global__ void rgemm_kernel(const float* __restrict__ r, const float* __restrict__ w,
                             float* __restrict__ out, int rows) {
    int g = blockIdx.x * 256 + threadIdx.x;
    if (g >= rows * DIM) return;
    int i = g / DIM, j = g - i * DIM;
    float acc = 0.f;
    for (int k = 0; k < DIM; ++k) acc += r[i * DIM + k] * w[k * DIM + j];
    out[g] = acc;
}

// ---------------------------------------------------------------------------
// fused layer GEMM (agg rows already deg-normalized):
//   out = tanh( (aggI@wIn + aggO@wOut + xin@wLoop - lv)/3 + bias )
// tile: 64 rows x 200 cols, 256 threads, thread = 2 rows x 25 cols.
// Safe with out == aggI (each block writes only rows it alone read, at end).
// ---------------------------------------------------------------------------
__global__ void layer_kernel(const float* __restrict__ aggI, const float* __restrict__ aggO,
                             const float* __restrict__ xin,
                             const float* __restrict__ wIn, const float* __restrict__ wOut,
                             const float* __restrict__ wLoop,
                             const float* __restrict__ lv, const float* __restrict__ bias,
                             float* __restrict__ out) {
    __shared__ float A[64][9];     // +1 pad breaks bank conflict
    __shared__ float W[8][200];
    const int tid  = threadIdx.x;
    const int row0 = blockIdx.x * 64;
    const int r2   = tid >> 3;     // 0..31 -> rows 2*r2, 2*r2+1
    const int cg   = tid & 7;      // 0..7  -> cols cg*25 .. +24

    float acc[2][25];
#pragma unroll
    for (int i = 0; i < 2; ++i)
#pragma unroll
        for (int c = 0; c < 25; ++c) acc[i][c] = 0.f;

    for (int p = 0; p < 3; ++p) {
        const float* Ap = (p == 0) ? aggI : (p == 1) ? aggO : xin;
        const float* Wp = (p == 0) ? wIn  : (p == 1) ? wOut : wLoop;
        for (int k0 = 0; k0 < DIM; k0 += 8) {
            __syncthreads();
            for (int idx = tid; idx < 512; idx += 256) {
                int rr = idx >> 3, kk = idx & 7;
                int grow = row0 + rr;
                A[rr][kk] = (grow < N_ENT) ? Ap[(size_t)grow * DIM + k0 + kk] : 0.f;
            }
            for (int idx = tid; idx < 1600; idx += 256) {
                int kk = idx / 200, col = idx - kk * 200;
                W[kk][col] = Wp[(k0 + kk) * DIM + col];
            }
            __syncthreads();
#pragma unroll
            for (int kk = 0; kk < 8; ++kk) {
                float a0 = A[2 * r2][kk], a1 = A[2 * r2 + 1][kk];
#pragma unroll
                for (int c = 0; c < 25; ++c) {
                    float w = W[kk][cg * 25 + c];
                    acc[0][c] += a0 * w;
                    acc[1][c] += a1 * w;
                }
            }
        }
    }
#pragma unroll
    for (int i = 0; i < 2; ++i) {
        int grow = row0 + 2 * r2 + i;
        if (grow < N_ENT) {
#pragma unroll
            for (int c = 0; c < 25; ++c) {
                int col = cg * 25 + c;
                float v = (acc[i][c] - lv[col]) * (1.0f / 3.0f) + bias[col];
                out[(size_t)grow * DIM + col] = tanhf(v);
            }
        }
    }
}

// ---------------------------------------------------------------------------
// build ConvE input images with BN0
// ---------------------------------------------------------------------------
__global__ void img_kernel(const float* __restrict__ x, const float* __restrict__ r,
                           const int* __restrict__ sub, const int* __restrict__ rel,
                           const float* __restrict__ bn0g, const float* __restrict__ bn0b,
                           float* __restrict__ img) {
    int g = blockIdx.x * 256 + threadIdx.x;
    if (g >= BB * 2 * DIM) return;
    int b = g / 400, l = g - b * 400;
    int d = l >> 1;
    float v = (l & 1) ? r[(size_t)rel[b] * DIM + d] : x[(size_t)sub[b] * DIM + d];
    float s0 = bn0g[0] * rsqrtf(1.0f + EPS_BN);
    img[g] = v * s0 + bn0b[0];
}

// ---------------------------------------------------------------------------
// conv 7x7 valid + bias + BN1 + relu, output transposed [k][b]
// ---------------------------------------------------------------------------
__global__ void conv_kernel(const float* __restrict__ img, const float* __restrict__ cw,
                            const float* __restrict__ cb, const float* __restrict__ bn1g,
                            const float* __restrict__ bn1b, float* __restrict__ out_t) {
    __shared__ float im[64][401];
    __shared__ float wt[49];
    const int f  = blockIdx.x >> 2;
    const int b0 = (blockIdx.x & 3) * 64;
    const int tid = threadIdx.x;
    if (tid < 49) wt[tid] = cw[f * 49 + tid];
    for (int idx = tid; idx < 64 * 400; idx += 256) {
        int bb = idx / 400, l = idx - bb * 400;
        im[bb][l] = img[(size_t)(b0 + bb) * 400 + l];
    }
    __syncthreads();
    const float s1 = bn1g[f] * rsqrtf(1.0f + EPS_BN);
    const float t1 = bn1b[f];
    const float cbf = cb[f];
    const int b_l = tid & 63;
    const int oq  = tid >> 6;
    for (int q = 0; q < 49; ++q) {
        int p = oq * 49 + q;
        int h = p / 14, w2 = p - h * 14;
        float s = 0.f;
#pragma unroll
        for (int i = 0; i < 7; ++i)
#pragma unroll
            for (int j = 0; j < 7; ++j)
                s += im[b_l][(h + i) * 20 + (w2 + j)] * wt[i * 7 + j];
        float v = fmaxf((s + cbf) * s1 + t1, 0.f);
        out_t[(size_t)(f * 196 + p) * BB + b0 + b_l] = v;
    }
}

// ---------------------------------------------------------------------------
// fc partial GEMM: acc_t[j][b] += sum_k out_t[k][b] * fc_w[k][j]
// ---------------------------------------------------------------------------
__global__ void fc_kernel(const float* __restrict__ xt, const float* __restrict__ fw,
                          float* __restrict__ acc_t) {
    __shared__ float w[100][50];
    const int kc = blockIdx.x >> 2;
    const int j0 = (blockIdx.x & 3) * 50;
    const int b  = threadIdx.x;
    float acc[50];
#pragma unroll
    for (int c = 0; c < 50; ++c) acc[c] = 0.f;
    for (int ks = 0; ks < 4; ++ks) {
        int k0 = kc * 400 + ks * 100;
        __syncthreads();
        for (int idx = b; idx < 5000; idx += 256) {
            int kk = idx / 50, jj = idx - kk * 50;
            w[kk][jj] = fw[(size_t)(k0 + kk) * DIM + j0 + jj];
        }
        __syncthreads();
        for (int kk = 0; kk < 100; ++kk) {
            float xv = xt[(size_t)(k0 + kk) * BB + b];
#pragma unroll
            for (int c = 0; c < 50; ++c) acc[c] += xv * w[kk][c];
        }
    }
    for (int c = 0; c < 50; ++c)
        atomicAdd(&acc_t[(size_t)(j0 + c) * BB + b], acc[c]);
}

__global__ void fc_epi_kernel(const float* __restrict__ acc_t, const float* __restrict__ fcb,
                              const float* __restrict__ g2, const float* __restrict__ b2v,
                              float* __restrict__ h_t) {
    int g = blockIdx.x * 256 + threadIdx.x;
    if (g >= DIM * BB) return;
    int j = g >> 8;
    float v = (acc_t[g] + fcb[j]) * (g2[j] * rsqrtf(1.0f + EPS_BN)) + b2v[j];
    h_t[g] = fmaxf(v, 0.f);
}

// ---------------------------------------------------------------------------
// logits: out[b][n] = sigmoid( h[b]·x[n] + ent_bias[n] )
// ---------------------------------------------------------------------------
__global__ void logits_kernel(const float* __restrict__ x, const float* __restrict__ ht,
                              const float* __restrict__ eb, float* __restrict__ out) {
    __shared__ float xs[64][9];
    __shared__ float hs[8][128];
    const int tid = threadIdx.x;
    const int e0 = (blockIdx.x >> 1) * 64;
    const int b0 = (blockIdx.x & 1) * 128;
    const int et = tid & 15;
    const int bt = tid >> 4;
    float acc[4][8];
#pragma unroll
    for (int i = 0; i < 4; ++i)
#pragma unroll
        for (int j = 0; j < 8; ++j) acc[i][j] = 0.f;

    for (int k0 = 0; k0 < DIM; k0 += 8) {
        __syncthreads();
        for (int idx = tid; idx < 512; idx += 256) {
            int ee = idx >> 3, kk = idx & 7;
            int ge = e0 + ee;
            xs[ee][kk] = (ge < N_ENT) ? x[(size_t)ge * DIM + k0 + kk] : 0.f;
        }
        for (int idx = tid; idx < 1024; idx += 256) {
            int kk = idx >> 7, bbx = idx & 127;
            hs[kk][bbx] = ht[(size_t)(k0 + kk) * BB + b0 + bbx];
        }
        __syncthreads();
#pragma unroll
        for (int kk = 0; kk < 8; ++kk) {
            float a[4], hb[8];
#pragma unroll
            for (int i = 0; i < 4; ++i) a[i] = xs[et * 4 + i][kk];
#pragma unroll
            for (int j = 0; j < 8; ++j) hb[j] = hs[kk][bt * 8 + j];
#pragma unroll
            for (int i = 0; i < 4; ++i)
#pragma unroll
                for (int j = 0; j < 8; ++j) acc[i][j] += a[i] * hb[j];
        }
    }
#pragma unroll
    for (int i = 0; i < 4; ++i) {
        int n = e0 + et * 4 + i;
        if (n < N_ENT) {
            float bias = eb[n];
#pragma unroll
            for (int j = 0; j < 8; ++j) {
                float v = acc[i][j] + bias;
                out[(size_t)(b0 + bt * 8 + j) * N_ENT + n] = 1.0f / (1.0f + expf(-v));
            }
        }
    }
}

// ---------------------------------------------------------------------------
extern "C" void kernel_launch(void* const* d_in, const int* in_sizes, int n_in,
                              void* d_out, int out_size, void* d_ws, size_t ws_size,
                              hipStream_t stream) {
    const int*   sub        = (const int*)  d_in[0];
    const int*   rel        = (const int*)  d_in[1];
    const int*   edge_index = (const int*)  d_in[2];
    const int*   edge_type  = (const int*)  d_in[3];
    const float* init_embed = (const float*)d_in[4];
    const float* init_rel   = (const float*)d_in[5];
    const float* loop_rel1  = (const float*)d_in[6];
    const float* loop_rel2  = (const float*)d_in[7];
    const float* w_in1      = (const float*)d_in[8];
    const float* w_out1     = (const float*)d_in[9];
    const float* w_loop1    = (const float*)d_in[10];
    const float* w_rel1     = (const float*)d_in[11];
    const float* b1         = (const float*)d_in[12];
    const float* w_in2      = (const float*)d_in[13];
    const float* w_out2     = (const float*)d_in[14];
    const float* w_loop2    = (const float*)d_in[15];
    const float* w_rel2     = (const float*)d_in[16];
    const float* b2         = (const float*)d_in[17];
    const float* conv_w     = (const float*)d_in[18];
    const float* conv_b     = (const float*)d_in[19];
    const float* bn0_g      = (const float*)d_in[20];
    const float* bn0_b      = (const float*)d_in[21];
    const float* bn1_g      = (const float*)d_in[22];
    const float* bn1_b      = (const float*)d_in[23];
    const float* bn2_g      = (const float*)d_in[24];
    const float* bn2_b      = (const float*)d_in[25];
    const float* fc_w       = (const float*)d_in[26];
    const float* fc_b       = (const float*)d_in[27];
    const float* ent_bias   = (const float*)d_in[28];

    float* ws   = (float*)d_ws;
    float* bufA = ws;                       // 20,000,000  (in-agg; layer-2 out in-place)
    float* bufB = bufA + 20000000;          // 20,000,000  (out-agg; MUST stay adjacent to bufA)
    float* bufX = bufB + 20000000;          // 20,000,000  (x1)
    float* r1   = bufX + 20000000;          // 200,000
    float* r2   = r1   + 200000;            // 200,000
    float* lv   = r2   + 200000;            // 256
    float* img  = lv   + 256;               // 102,400
    float* outT = img  + 102400;            // 10,035,200
    float* accT = outT + 10035200;          // 51,200
    float* hT   = accT + 51200;             // 51,200

    // CSR arrays alias outT: last CSR read (gather2) precedes first outT write.
    int* esrc      = (int*)outT;            // 500,000
    int* eet       = esrc + E_TOT;          // 500,000
    int* cnt       = eet  + E_TOT;          // 200,000
    int* row_start = cnt  + NROWS;          // 200,000
    int* row_cur   = row_start + NROWS;     // 200,000
    int* blockSum  = row_cur + NROWS;       // 98

    const int layer_blocks  = (N_ENT + 63) / 64;
    const int gather_blocks = (NROWS + 3) / 4;

    // ---- build CSR once (same graph for both layers) ----
    hipMemsetAsync(cnt, 0, (size_t)NROWS * 4, stream);
    hist_kernel<<<(E_TOT + 255) / 256, 256, 0, stream>>>(edge_index, cnt);
    scan1_kernel<<<SNBLK, 256, 0, stream>>>(cnt, row_start, blockSum);
    scan2_kernel<<<1, 1, 0, stream>>>(blockSum);
    scan3_kernel<<<(NROWS + 255) / 256, 256, 0, stream>>>(row_start, row_cur, blockSum);
    fill_kernel<<<(E_TOT + 255) / 256, 256, 0, stream>>>(edge_index, edge_type, row_cur,
                                                         esrc, eet);

    // ---- layer 1 ----
    gather_kernel<<<gather_blocks, 256, 0, stream>>>(init_embed, init_rel, esrc, eet,
                                                     row_start, cnt, bufA);
    lv_kernel<<<1, 256, 0, stream>>>(loop_rel1, w_loop1, lv);
    layer_kernel<<<layer_blocks, 256, 0, stream>>>(bufA, bufB, init_embed,
                                                   w_in1, w_out1, w_loop1, lv, b1, bufX);
    rgemm_kernel<<<(N_REL2 * DIM + 255) / 256, 256, 0, stream>>>(init_rel, w_rel1, r1, N_REL2);

    // ---- layer 2 ----
    gather_kernel<<<gather_blocks, 256, 0, stream>>>(bufX, r1, esrc, eet,
                                                     row_start, cnt, bufA);
    lv_kernel<<<1, 256, 0, stream>>>(loop_rel2, w_loop2, lv);
    layer_kernel<<<layer_blocks, 256, 0, stream>>>(bufA, bufB, bufX,
                                                   w_in2, w_out2, w_loop2, lv, b2, bufA);
    rgemm_kernel<<<(N_REL2 * DIM + 255) / 256, 256, 0, stream>>>(r1, w_rel2, r2, N_REL2);

    // ---- ConvE ----
    img_kernel<<<(BB * 400 + 255) / 256, 256, 0, stream>>>(bufA, r2, sub, rel,
                                                           bn0_g, bn0_b, img);
    conv_kernel<<<NFILT * 4, 256, 0, stream>>>(img, conv_w, conv_b, bn1_g, bn1_b, outT);
    hipMemsetAsync(accT, 0, (size_t)51200 * 4, stream);
    fc_kernel<<<98 * 4, 256, 0, stream>>>(outT, fc_w, accT);
    fc_epi_kernel<<<(DIM * BB + 255) / 256, 256, 0, stream>>>(accT, fc_b, bn2_g, bn2_b, hT);

    // ---- logits ----
    logits_kernel<<<layer_blocks * 2, 256, 0, stream>>>(bufA, hT, ent_bias, (float*)d_out);
}

// Round 3
// 1452.170 us; speedup vs baseline: 3.6304x; 1.8099x over previous
//
#include <hip/hip_runtime.h>
#include <math.h>

#define N_ENT   100000
#define N_REL2  1000
#define E_TOT   500000
#define E_HALF  250000
#define DIM     200
#define BB      256
#define NFILT   200
#define FLATK   39200
#define EPS_BN  1e-5f

#define NROWS   200000          // 100k in-rows + 100k out-rows
#define SCHUNK  2048
#define SNBLK   ((NROWS + SCHUNK - 1) / SCHUNK)   // 98

typedef __attribute__((ext_vector_type(8))) short bf16x8;   // 8 bf16 (4 VGPRs)
typedef __attribute__((ext_vector_type(4))) float f32x4;

__device__ __forceinline__ unsigned short f2b(float f) {
    union { float f; unsigned u; } c; c.f = f;
    unsigned u = c.u;
    u += 0x7fffu + ((u >> 16) & 1u);          // round-to-nearest-even
    return (unsigned short)(u >> 16);
}
__device__ __forceinline__ float b2f(unsigned short h) {
    union { unsigned u; float f; } c; c.u = ((unsigned)h) << 16;
    return c.f;
}
__device__ __forceinline__ float fast_tanh(float x) {
    float ax = fabsf(x);
    float e = __expf(-2.0f * ax);             // in (0,1], never overflows
    float t = (1.0f - e) / (1.0f + e);
    return copysignf(t, x);
}

// ---------------------------------------------------------------------------
// fp32 -> bf16 convert (n multiple of 4 in all uses)
// ---------------------------------------------------------------------------
__global__ void convert_kernel(const float* __restrict__ s, unsigned short* __restrict__ d,
                               int n) {
    int i = (blockIdx.x * 256 + threadIdx.x) * 4;
    if (i + 3 < n) {
        float4 v = *(const float4*)(s + i);
        ushort4 o;
        o.x = f2b(v.x); o.y = f2b(v.y); o.z = f2b(v.z); o.w = f2b(v.w);
        *(ushort4*)(d + i) = o;
    } else {
        for (; i < n; ++i) d[i] = f2b(s[i]);
    }
}

// ---------------------------------------------------------------------------
// Build WstackT[208][672] bf16: WstackT[j][seg*224+k] = Wseg[k][j] (zero-pad)
// ---------------------------------------------------------------------------
__global__ void wstack_kernel(const float* __restrict__ wIn, const float* __restrict__ wOut,
                              const float* __restrict__ wLoop, unsigned short* __restrict__ WT) {
    int g = blockIdx.x * 256 + threadIdx.x;
    if (g >= 208 * 672) return;
    int j = g / 672, t = g - j * 672;
    int seg = t / 224, k = t - seg * 224;
    float v = 0.f;
    if (j < 200 && k < 200)
        v = (seg == 0 ? wIn : seg == 1 ? wOut : wLoop)[k * 200 + j];
    WT[g] = f2b(v);
}

// ---------------------------------------------------------------------------
// CSR build: histogram -> scan -> fill. Row id = dst + (e<E_HALF ? 0 : N_ENT).
// ---------------------------------------------------------------------------
__global__ void hist_kernel(const int* __restrict__ ei, int* __restrict__ cnt) {
    int e = blockIdx.x * 256 + threadIdx.x;
    if (e >= E_TOT) return;
    int row = ei[E_TOT + e] + (e < E_HALF ? 0 : N_ENT);
    atomicAdd(&cnt[row], 1);
}

__global__ void scan1_kernel(const int* __restrict__ cnt, int* __restrict__ row_start,
                             int* __restrict__ blockSum) {
    __shared__ int tsum[256];
    const int t = threadIdx.x;
    const int base = blockIdx.x * SCHUNK + t * 8;
    int v[8];
    int s = 0;
#pragma unroll
    for (int i = 0; i < 8; ++i) {
        int idx = base + i;
        int c = (idx < NROWS) ? cnt[idx] : 0;
        v[i] = s;
        s += c;
    }
    tsum[t] = s;
    __syncthreads();
    for (int off = 1; off < 256; off <<= 1) {
        int x = (t >= off) ? tsum[t - off] : 0;
        __syncthreads();
        if (t >= off) tsum[t] += x;
        __syncthreads();
    }
    int texc = (t == 0) ? 0 : tsum[t - 1];
    if (t == 0) blockSum[blockIdx.x] = tsum[255];
#pragma unroll
    for (int i = 0; i < 8; ++i) {
        int idx = base + i;
        if (idx < NROWS) row_start[idx] = texc + v[i];
    }
}

__global__ void scan2_kernel(int* __restrict__ blockSum) {
    int s = 0;
    for (int i = 0; i < SNBLK; ++i) { int c = blockSum[i]; blockSum[i] = s; s += c; }
}

__global__ void scan3_kernel(int* __restrict__ row_start, int* __restrict__ row_cur,
                             const int* __restrict__ blockSum) {
    int i = blockIdx.x * 256 + threadIdx.x;
    if (i >= NROWS) return;
    int v = row_start[i] + blockSum[i / SCHUNK];
    row_start[i] = v;
    row_cur[i] = v;
}

__global__ void fill_kernel(const int* __restrict__ ei, const int* __restrict__ et,
                            int* __restrict__ row_cur,
                            int* __restrict__ esrc, int* __restrict__ eet) {
    int e = blockIdx.x * 256 + threadIdx.x;
    if (e >= E_TOT) return;
    int row = ei[E_TOT + e] + (e < E_HALF ? 0 : N_ENT);
    int pos = atomicAdd(&row_cur[row], 1);
    esrc[pos] = ei[e];
    eet[pos] = et[e];
}

// ---------------------------------------------------------------------------
// gather (bf16): one wave per CSR row, lanes 0..49 own 4 bf16 each; fp32 accum;
// writes degree-normalized bf16 row once. agg = [200000][200] bf16.
// ---------------------------------------------------------------------------
__global__ void gather_kernel(const unsigned short* __restrict__ x,
                              const unsigned short* __restrict__ r,
                              const int* __restrict__ esrc, const int* __restrict__ eet,
                              const int* __restrict__ row_start, const int* __restrict__ cnt,
                              unsigned short* __restrict__ agg) {
    int wid = blockIdx.x * 4 + (threadIdx.x >> 6);
    if (wid >= NROWS) return;
    int lane = threadIdx.x & 63;
    if (lane >= 50) return;
    int start = row_start[wid];
    int deg = cnt[wid];
    float a0 = 0.f, a1 = 0.f, a2 = 0.f, a3 = 0.f;
    for (int i = 0; i < deg; ++i) {
        int s = esrc[start + i];
        int t = eet[start + i];
        ushort4 xv = *(const ushort4*)(x + (size_t)s * DIM + lane * 4);
        ushort4 rv = *(const ushort4*)(r + (size_t)t * DIM + lane * 4);
        a0 += b2f(xv.x) - b2f(rv.x);
        a1 += b2f(xv.y) - b2f(rv.y);
        a2 += b2f(xv.z) - b2f(rv.z);
        a3 += b2f(xv.w) - b2f(rv.w);
    }
    float sc = 1.0f / fmaxf((float)deg, 1.0f);
    ushort4 o;
    o.x = f2b(a0 * sc); o.y = f2b(a1 * sc); o.z = f2b(a2 * sc); o.w = f2b(a3 * sc);
    *(ushort4*)(agg + (size_t)wid * DIM + lane * 4) = o;
}

// ---------------------------------------------------------------------------
// lv = loop_rel @ w_loop   (fp32, one 200-vector)
// ---------------------------------------------------------------------------
__global__ void lv_kernel(const float* __restrict__ lr, const float* __restrict__ wl,
                          float* __restrict__ lv) {
    int j = blockIdx.x * blockDim.x + threadIdx.x;
    if (j >= DIM) return;
    float acc = 0.f;
    for (int k = 0; k < DIM; ++k) acc += lr[k] * wl[k * DIM + j];
    lv[j] = acc;
}

// ---------------------------------------------------------------------------
// r_out = r_in @ w   fp32, tiny (rows=1000)
// ---------------------------------------------------------------------------
__global__ void rgemm_kernel(const float* __restrict__ r, const float* __restrict__ w,
                             float* __restrict__ out, int rows) {
    int g = blockIdx.x * 256 + threadIdx.x;
    if (g >= rows * DIM) return;
    int i = g / DIM, j = g - i * DIM;
    float acc = 0.f;
    for (int k = 0; k < DIM; ++k) acc += r[i * DIM + k] * w[k * DIM + j];
    out[g] = acc;
}

// ---------------------------------------------------------------------------
// MFMA layer: out = tanh((aggI@wIn + aggO@wOut + xin@wLoop - lv)/3 + bias), bf16.
// Block: 128 rows x 208 cols (13 N-tiles), 4 waves; wave = 2 M-tiles x 13 N-tiles.
// K: 3 segments, each 7 chunks of 32 (k>=200 zero-padded).
// A_lds/W_lds rows strided 40 bf16 (80 B): 16B-aligned b128, 2-way bank alias (free).
// ---------------------------------------------------------------------------
__global__ __launch_bounds__(256) void layer_mfma_kernel(
        const unsigned short* __restrict__ aggI, const unsigned short* __restrict__ aggO,
        const unsigned short* __restrict__ xin, const unsigned short* __restrict__ WT,
        const float* __restrict__ lv, const float* __restrict__ bias,
        unsigned short* __restrict__ out) {
    __shared__ __align__(16) unsigned short A_lds[128 * 40];
    __shared__ __align__(16) unsigned short W_lds[208 * 40];
    const int tid  = threadIdx.x;
    const int row0 = blockIdx.x * 128;
    const int wave = tid >> 6;
    const int lane = tid & 63;
    const int lr   = lane & 15;     // A-row / B-col within tile
    const int lq   = lane >> 4;     // k-quarter

    f32x4 acc[2][13];
#pragma unroll
    for (int m = 0; m < 2; ++m)
#pragma unroll
        for (int n = 0; n < 13; ++n) acc[m][n] = (f32x4){0.f, 0.f, 0.f, 0.f};

    for (int seg = 0; seg < 3; ++seg) {
        const unsigned short* Ap = (seg == 0) ? aggI : (seg == 1) ? aggO : xin;
        for (int c = 0; c < 7; ++c) {
            const int k0 = c * 32;
            __syncthreads();
            // stage A: 128 rows x 32 k  (512 x 16B units)
#pragma unroll
            for (int it = 0; it < 2; ++it) {
                int uu = tid + it * 256;
                int row = uu >> 2, kq = uu & 3;
                int grow = row0 + row;
                int k = k0 + kq * 8;
                int4 v = make_int4(0, 0, 0, 0);
                if (grow < N_ENT && k < 200)
                    v = *(const int4*)(Ap + (size_t)grow * 200 + k);
                *(int4*)(&A_lds[row * 40 + kq * 8]) = v;
            }
            // stage W^T: 208 cols x 32 k  (832 x 16B units)
            for (int uu = tid; uu < 832; uu += 256) {
                int col = uu >> 2, kq = uu & 3;
                int4 v = *(const int4*)(WT + (size_t)col * 672 + seg * 224 + k0 + kq * 8);
                *(int4*)(&W_lds[col * 40 + kq * 8]) = v;
            }
            __syncthreads();

            const unsigned short* Abase = &A_lds[(wave * 32 + lr) * 40 + lq * 8];
            bf16x8 a0 = *(const bf16x8*)(Abase);
            bf16x8 a1 = *(const bf16x8*)(Abase + 16 * 40);
#pragma unroll
            for (int n = 0; n < 13; ++n) {
                bf16x8 b = *(const bf16x8*)(&W_lds[(n * 16 + lr) * 40 + lq * 8]);
                acc[0][n] = __builtin_amdgcn_mfma_f32_16x16x32_bf16(a0, b, acc[0][n], 0, 0, 0);
                acc[1][n] = __builtin_amdgcn_mfma_f32_16x16x32_bf16(a1, b, acc[1][n], 0, 0, 0);
            }
        }
    }

#pragma unroll
    for (int m = 0; m < 2; ++m) {
        int grow_base = row0 + wave * 32 + m * 16 + lq * 4;
#pragma unroll
        for (int n = 0; n < 13; ++n) {
            int col = n * 16 + lr;
            if (col < 200) {
                float lvc = lv[col], bc = bias[col];
#pragma unroll
                for (int r = 0; r < 4; ++r) {
                    int grow = grow_base + r;
                    if (grow < N_ENT) {
                        float v = (acc[m][n][r] - lvc) * (1.0f / 3.0f) + bc;
                        out[(size_t)grow * 200 + col] = f2b(fast_tanh(v));
                    }
                }
            }
        }
    }
}

// ---------------------------------------------------------------------------
// build ConvE input images with BN0 (x is bf16 now)
// ---------------------------------------------------------------------------
__global__ void img_kernel(const unsigned short* __restrict__ x, const float* __restrict__ r,
                           const int* __restrict__ sub, const int* __restrict__ rel,
                           const float* __restrict__ bn0g, const float* __restrict__ bn0b,
                           float* __restrict__ img) {
    int g = blockIdx.x * 256 + threadIdx.x;
    if (g >= BB * 2 * DIM) return;
    int b = g / 400, l = g - b * 400;
    int d = l >> 1;
    float v = (l & 1) ? r[(size_t)rel[b] * DIM + d] : b2f(x[(size_t)sub[b] * DIM + d]);
    float s0 = bn0g[0] * rsqrtf(1.0f + EPS_BN);
    img[g] = v * s0 + bn0b[0];
}

// ---------------------------------------------------------------------------
// conv 7x7 valid + bias + BN1 + relu, output transposed [k][b]
// ---------------------------------------------------------------------------
__global__ void conv_kernel(const float* __restrict__ img, const float* __restrict__ cw,
                            const float* __restrict__ cb, const float* __restrict__ bn1g,
                            const float* __restrict__ bn1b, float* __restrict__ out_t) {
    __shared__ float im[64][401];
    __shared__ float wt[49];
    const int f  = blockIdx.x >> 2;
    const int b0 = (blockIdx.x & 3) * 64;
    const int tid = threadIdx.x;
    if (tid < 49) wt[tid] = cw[f * 49 + tid];
    for (int idx = tid; idx < 64 * 400; idx += 256) {
        int bb = idx / 400, l = idx - bb * 400;
        im[bb][l] = img[(size_t)(b0 + bb) * 400 + l];
    }
    __syncthreads();
    const float s1 = bn1g[f] * rsqrtf(1.0f + EPS_BN);
    const float t1 = bn1b[f];
    const float cbf = cb[f];
    const int b_l = tid & 63;
    const int oq  = tid >> 6;
    for (int q = 0; q < 49; ++q) {
        int p = oq * 49 + q;
        int h = p / 14, w2 = p - h * 14;
        float s = 0.f;
#pragma unroll
        for (int i = 0; i < 7; ++i)
#pragma unroll
            for (int j = 0; j < 7; ++j)
                s += im[b_l][(h + i) * 20 + (w2 + j)] * wt[i * 7 + j];
        float v = fmaxf((s + cbf) * s1 + t1, 0.f);
        out_t[(size_t)(f * 196 + p) * BB + b0 + b_l] = v;
    }
}

// ---------------------------------------------------------------------------
// fc partial GEMM: acc_t[j][b] += sum_k out_t[k][b] * fc_w[k][j]
// ---------------------------------------------------------------------------
__global__ void fc_kernel(const float* __restrict__ xt, const float* __restrict__ fw,
                          float* __restrict__ acc_t) {
    __shared__ float w[100][50];
    const int kc = blockIdx.x >> 2;
    const int j0 = (blockIdx.x & 3) * 50;
    const int b  = threadIdx.x;
    float acc[50];
#pragma unroll
    for (int c = 0; c < 50; ++c) acc[c] = 0.f;
    for (int ks = 0; ks < 4; ++ks) {
        int k0 = kc * 400 + ks * 100;
        __syncthreads();
        for (int idx = b; idx < 5000; idx += 256) {
            int kk = idx / 50, jj = idx - kk * 50;
            w[kk][jj] = fw[(size_t)(k0 + kk) * DIM + j0 + jj];
        }
        __syncthreads();
        for (int kk = 0; kk < 100; ++kk) {
            float xv = xt[(size_t)(k0 + kk) * BB + b];
#pragma unroll
            for (int c = 0; c < 50; ++c) acc[c] += xv * w[kk][c];
        }
    }
    for (int c = 0; c < 50; ++c)
        atomicAdd(&acc_t[(size_t)(j0 + c) * BB + b], acc[c]);
}

__global__ void fc_epi_kernel(const float* __restrict__ acc_t, const float* __restrict__ fcb,
                              const float* __restrict__ g2, const float* __restrict__ b2v,
                              float* __restrict__ h_t) {
    int g = blockIdx.x * 256 + threadIdx.x;
    if (g >= DIM * BB) return;
    int j = g >> 8;
    float v = (acc_t[g] + fcb[j]) * (g2[j] * rsqrtf(1.0f + EPS_BN)) + b2v[j];
    h_t[g] = fmaxf(v, 0.f);
}

// ---------------------------------------------------------------------------
// logits: out[b][n] = sigmoid( h[b]·x[n] + ent_bias[n] ), x is bf16
// ---------------------------------------------------------------------------
__global__ void logits_kernel(const unsigned short* __restrict__ x,
                              const float* __restrict__ ht,
                              const float* __restrict__ eb, float* __restrict__ out) {
    __shared__ float xs[64][9];
    __shared__ float hs[8][128];
    const int tid = threadIdx.x;
    const int e0 = (blockIdx.x >> 1) * 64;
    const int b0 = (blockIdx.x & 1) * 128;
    const int et = tid & 15;
    const int bt = tid >> 4;
    float acc[4][8];
#pragma unroll
    for (int i = 0; i < 4; ++i)
#pragma unroll
        for (int j = 0; j < 8; ++j) acc[i][j] = 0.f;

    for (int k0 = 0; k0 < DIM; k0 += 8) {
        __syncthreads();
        for (int idx = tid; idx < 512; idx += 256) {
            int ee = idx >> 3, kk = idx & 7;
            int ge = e0 + ee;
            xs[ee][kk] = (ge < N_ENT) ? b2f(x[(size_t)ge * DIM + k0 + kk]) : 0.f;
        }
        for (int idx = tid; idx < 1024; idx += 256) {
            int kk = idx >> 7, bbx = idx & 127;
            hs[kk][bbx] = ht[(size_t)(k0 + kk) * BB + b0 + bbx];
        }
        __syncthreads();
#pragma unroll
        for (int kk = 0; kk < 8; ++kk) {
            float a[4], hb[8];
#pragma unroll
            for (int i = 0; i < 4; ++i) a[i] = xs[et * 4 + i][kk];
#pragma unroll
            for (int j = 0; j < 8; ++j) hb[j] = hs[kk][bt * 8 + j];
#pragma unroll
            for (int i = 0; i < 4; ++i)
#pragma unroll
                for (int j = 0; j < 8; ++j) acc[i][j] += a[i] * hb[j];
        }
    }
#pragma unroll
    for (int i = 0; i < 4; ++i) {
        int n = e0 + et * 4 + i;
        if (n < N_ENT) {
            float bias = eb[n];
#pragma unroll
            for (int j = 0; j < 8; ++j) {
                float v = acc[i][j] + bias;
                out[(size_t)(b0 + bt * 8 + j) * N_ENT + n] = 1.0f / (1.0f + expf(-v));
            }
        }
    }
}

// ---------------------------------------------------------------------------
extern "C" void kernel_launch(void* const* d_in, const int* in_sizes, int n_in,
                              void* d_out, int out_size, void* d_ws, size_t ws_size,
                              hipStream_t stream) {
    const int*   sub        = (const int*)  d_in[0];
    const int*   rel        = (const int*)  d_in[1];
    const int*   edge_index = (const int*)  d_in[2];
    const int*   edge_type  = (const int*)  d_in[3];
    const float* init_embed = (const float*)d_in[4];
    const float* init_rel   = (const float*)d_in[5];
    const float* loop_rel1  = (const float*)d_in[6];
    const float* loop_rel2  = (const float*)d_in[7];
    const float* w_in1      = (const float*)d_in[8];
    const float* w_out1     = (const float*)d_in[9];
    const float* w_loop1    = (const float*)d_in[10];
    const float* w_rel1     = (const float*)d_in[11];
    const float* b1         = (const float*)d_in[12];
    const float* w_in2      = (const float*)d_in[13];
    const float* w_out2     = (const float*)d_in[14];
    const float* w_loop2    = (const float*)d_in[15];
    const float* w_rel2     = (const float*)d_in[16];
    const float* b2         = (const float*)d_in[17];
    const float* conv_w     = (const float*)d_in[18];
    const float* conv_b     = (const float*)d_in[19];
    const float* bn0_g      = (const float*)d_in[20];
    const float* bn0_b      = (const float*)d_in[21];
    const float* bn1_g      = (const float*)d_in[22];
    const float* bn1_b      = (const float*)d_in[23];
    const float* bn2_g      = (const float*)d_in[24];
    const float* bn2_b      = (const float*)d_in[25];
    const float* fc_w       = (const float*)d_in[26];
    const float* fc_b       = (const float*)d_in[27];
    const float* ent_bias   = (const float*)d_in[28];

    // ---- bf16 region ----
    unsigned short* aggb = (unsigned short*)d_ws;     // 40,000,000 (in-rows then out-rows)
    unsigned short* x0b  = aggb + 40000000;           // 20,000,000 (init bf16; reused as x2b)
    unsigned short* x1b  = x0b  + 20000000;           // 20,000,000
    unsigned short* r0b  = x1b  + 20000000;           //    200,000
    unsigned short* r1b  = r0b  + 200000;             //    200,000
    unsigned short* WT   = r1b  + 200000;             //    139,776 (208*672)
    // ---- fp32 region ----
    float* fbase = (float*)(WT + 139776);
    float* r1f  = fbase;                              // 200,000
    float* r2f  = r1f  + 200000;                      // 200,000
    float* lv   = r2f  + 200000;                      // 256
    float* img  = lv   + 256;                         // 102,400
    float* outT = img  + 102400;                      // 10,035,200
    float* accT = outT + 10035200;                    // 51,200
    float* hT   = accT + 51200;                       // 51,200

    // CSR arrays alias outT (last CSR read = gather2, before conv writes outT)
    int* esrc      = (int*)outT;                      // 500,000
    int* eet       = esrc + E_TOT;                    // 500,000
    int* cnt       = eet  + E_TOT;                    // 200,000
    int* row_start = cnt  + NROWS;                    // 200,000
    int* row_cur   = row_start + NROWS;               // 200,000
    int* blockSum  = row_cur + NROWS;                 // 98

    unsigned short* aggIb = aggb;
    unsigned short* aggOb = aggb + (size_t)N_ENT * DIM;
    unsigned short* x2b   = x0b;   // init bf16 dead after layer 1

    const int gather_blocks = (NROWS + 3) / 4;
    const int layer_blocks  = (N_ENT + 127) / 128;    // 782
    const int wstack_blocks = (208 * 672 + 255) / 256;

    // ---- converts + CSR build ----
    convert_kernel<<<(N_ENT * DIM + 1023) / 1024, 256, 0, stream>>>(init_embed, x0b, N_ENT * DIM);
    convert_kernel<<<(N_REL2 * DIM + 1023) / 1024, 256, 0, stream>>>(init_rel, r0b, N_REL2 * DIM);
    hipMemsetAsync(cnt, 0, (size_t)NROWS * 4, stream);
    hist_kernel<<<(E_TOT + 255) / 256, 256, 0, stream>>>(edge_index, cnt);
    scan1_kernel<<<SNBLK, 256, 0, stream>>>(cnt, row_start, blockSum);
    scan2_kernel<<<1, 1, 0, stream>>>(blockSum);
    scan3_kernel<<<(NROWS + 255) / 256, 256, 0, stream>>>(row_start, row_cur, blockSum);
    fill_kernel<<<(E_TOT + 255) / 256, 256, 0, stream>>>(edge_index, edge_type, row_cur,
                                                         esrc, eet);

    // ---- layer 1 ----
    wstack_kernel<<<wstack_blocks, 256, 0, stream>>>(w_in1, w_out1, w_loop1, WT);
    gather_kernel<<<gather_blocks, 256, 0, stream>>>(x0b, r0b, esrc, eet, row_start, cnt, aggb);
    lv_kernel<<<1, 256, 0, stream>>>(loop_rel1, w_loop1, lv);
    layer_mfma_kernel<<<layer_blocks, 256, 0, stream>>>(aggIb, aggOb, x0b, WT, lv, b1, x1b);
    rgemm_kernel<<<(N_REL2 * DIM + 255) / 256, 256, 0, stream>>>(init_rel, w_rel1, r1f, N_REL2);
    convert_kernel<<<(N_REL2 * DIM + 1023) / 1024, 256, 0, stream>>>(r1f, r1b, N_REL2 * DIM);

    // ---- layer 2 ----
    wstack_kernel<<<wstack_blocks, 256, 0, stream>>>(w_in2, w_out2, w_loop2, WT);
    gather_kernel<<<gather_blocks, 256, 0, stream>>>(x1b, r1b, esrc, eet, row_start, cnt, aggb);
    lv_kernel<<<1, 256, 0, stream>>>(loop_rel2, w_loop2, lv);
    layer_mfma_kernel<<<layer_blocks, 256, 0, stream>>>(aggIb, aggOb, x1b, WT, lv, b2, x2b);
    rgemm_kernel<<<(N_REL2 * DIM + 255) / 256, 256, 0, stream>>>(r1f, w_rel2, r2f, N_REL2);

    // ---- ConvE ----
    img_kernel<<<(BB * 400 + 255) / 256, 256, 0, stream>>>(x2b, r2f, sub, rel,
                                                           bn0_g, bn0_b, img);
    conv_kernel<<<NFILT * 4, 256, 0, stream>>>(img, conv_w, conv_b, bn1_g, bn1_b, outT);
    hipMemsetAsync(accT, 0, (size_t)51200 * 4, stream);
    fc_kernel<<<98 * 4, 256, 0, stream>>>(outT, fc_w, accT);
    fc_epi_kernel<<<(DIM * BB + 255) / 256, 256, 0, stream>>>(accT, fc_b, bn2_g, bn2_b, hT);

    // ---- logits ----
    logits_kernel<<<((N_ENT + 63) / 64) * 2, 256, 0, stream>>>(x2b, hT, ent_bias, (float*)d_out);
}

// Round 4
// 1145.842 us; speedup vs baseline: 4.6010x; 1.2673x over previous
//
#include <hip/hip_runtime.h>
#include <math.h>

#define N_ENT   100000
#define N_REL2  1000
#define E_TOT   500000
#define E_HALF  250000
#define DIM     200
#define BB      256
#define NFILT   200
#define FLATK   39200
#define EPS_BN  1e-5f

#define NROWS   200000          // 100k in-rows + 100k out-rows
#define SCHUNK  2048
#define SNBLK   ((NROWS + SCHUNK - 1) / SCHUNK)   // 98

typedef __attribute__((ext_vector_type(8))) short bf16x8;   // 8 bf16 (4 VGPRs)
typedef __attribute__((ext_vector_type(4))) float f32x4;

__device__ __forceinline__ unsigned short f2b(float f) {
    union { float f; unsigned u; } c; c.f = f;
    unsigned u = c.u;
    u += 0x7fffu + ((u >> 16) & 1u);          // round-to-nearest-even
    return (unsigned short)(u >> 16);
}
__device__ __forceinline__ float b2f(unsigned short h) {
    union { unsigned u; float f; } c; c.u = ((unsigned)h) << 16;
    return c.f;
}
__device__ __forceinline__ float fast_tanh(float x) {
    float ax = fabsf(x);
    float e = __expf(-2.0f * ax);             // in (0,1], never overflows
    float t = (1.0f - e) / (1.0f + e);
    return copysignf(t, x);
}

// ---------------------------------------------------------------------------
// fp32 -> bf16 convert
// ---------------------------------------------------------------------------
__global__ void convert_kernel(const float* __restrict__ s, unsigned short* __restrict__ d,
                               int n) {
    int i = (blockIdx.x * 256 + threadIdx.x) * 4;
    if (i + 3 < n) {
        float4 v = *(const float4*)(s + i);
        ushort4 o;
        o.x = f2b(v.x); o.y = f2b(v.y); o.z = f2b(v.z); o.w = f2b(v.w);
        *(ushort4*)(d + i) = o;
    } else {
        for (; i < n; ++i) d[i] = f2b(s[i]);
    }
}

// ---------------------------------------------------------------------------
// Build WstackT[208][672] bf16: WstackT[j][seg*224+k] = Wseg[k][j] (zero-pad)
// ---------------------------------------------------------------------------
__global__ void wstack_kernel(const float* __restrict__ wIn, const float* __restrict__ wOut,
                              const float* __restrict__ wLoop, unsigned short* __restrict__ WT) {
    int g = blockIdx.x * 256 + threadIdx.x;
    if (g >= 208 * 672) return;
    int j = g / 672, t = g - j * 672;
    int seg = t / 224, k = t - seg * 224;
    float v = 0.f;
    if (j < 200 && k < 200)
        v = (seg == 0 ? wIn : seg == 1 ? wOut : wLoop)[k * 200 + j];
    WT[g] = f2b(v);
}

// ---------------------------------------------------------------------------
// CSR build
// ---------------------------------------------------------------------------
__global__ void hist_kernel(const int* __restrict__ ei, int* __restrict__ cnt) {
    int e = blockIdx.x * 256 + threadIdx.x;
    if (e >= E_TOT) return;
    int row = ei[E_TOT + e] + (e < E_HALF ? 0 : N_ENT);
    atomicAdd(&cnt[row], 1);
}

__global__ void scan1_kernel(const int* __restrict__ cnt, int* __restrict__ row_start,
                             int* __restrict__ blockSum) {
    __shared__ int tsum[256];
    const int t = threadIdx.x;
    const int base = blockIdx.x * SCHUNK + t * 8;
    int v[8];
    int s = 0;
#pragma unroll
    for (int i = 0; i < 8; ++i) {
        int idx = base + i;
        int c = (idx < NROWS) ? cnt[idx] : 0;
        v[i] = s;
        s += c;
    }
    tsum[t] = s;
    __syncthreads();
    for (int off = 1; off < 256; off <<= 1) {
        int x = (t >= off) ? tsum[t - off] : 0;
        __syncthreads();
        if (t >= off) tsum[t] += x;
        __syncthreads();
    }
    int texc = (t == 0) ? 0 : tsum[t - 1];
    if (t == 0) blockSum[blockIdx.x] = tsum[255];
#pragma unroll
    for (int i = 0; i < 8; ++i) {
        int idx = base + i;
        if (idx < NROWS) row_start[idx] = texc + v[i];
    }
}

__global__ void scan2_kernel(int* __restrict__ blockSum) {
    int s = 0;
    for (int i = 0; i < SNBLK; ++i) { int c = blockSum[i]; blockSum[i] = s; s += c; }
}

__global__ void scan3_kernel(int* __restrict__ row_start, int* __restrict__ row_cur,
                             const int* __restrict__ blockSum) {
    int i = blockIdx.x * 256 + threadIdx.x;
    if (i >= NROWS) return;
    int v = row_start[i] + blockSum[i / SCHUNK];
    row_start[i] = v;
    row_cur[i] = v;
}

__global__ void fill_kernel(const int* __restrict__ ei, const int* __restrict__ et,
                            int* __restrict__ row_cur,
                            int* __restrict__ esrc, int* __restrict__ eet) {
    int e = blockIdx.x * 256 + threadIdx.x;
    if (e >= E_TOT) return;
    int row = ei[E_TOT + e] + (e < E_HALF ? 0 : N_ENT);
    int pos = atomicAdd(&row_cur[row], 1);
    esrc[pos] = ei[e];
    eet[pos] = et[e];
}

// ---------------------------------------------------------------------------
// gather (bf16): one wave per CSR row, lanes 0..49 own 4 bf16 each; fp32 accum
// ---------------------------------------------------------------------------
__global__ void gather_kernel(const unsigned short* __restrict__ x,
                              const unsigned short* __restrict__ r,
                              const int* __restrict__ esrc, const int* __restrict__ eet,
                              const int* __restrict__ row_start, const int* __restrict__ cnt,
                              unsigned short* __restrict__ agg) {
    int wid = blockIdx.x * 4 + (threadIdx.x >> 6);
    if (wid >= NROWS) return;
    int lane = threadIdx.x & 63;
    if (lane >= 50) return;
    int start = row_start[wid];
    int deg = cnt[wid];
    float a0 = 0.f, a1 = 0.f, a2 = 0.f, a3 = 0.f;
    for (int i = 0; i < deg; ++i) {
        int s = esrc[start + i];
        int t = eet[start + i];
        ushort4 xv = *(const ushort4*)(x + (size_t)s * DIM + lane * 4);
        ushort4 rv = *(const ushort4*)(r + (size_t)t * DIM + lane * 4);
        a0 += b2f(xv.x) - b2f(rv.x);
        a1 += b2f(xv.y) - b2f(rv.y);
        a2 += b2f(xv.z) - b2f(rv.z);
        a3 += b2f(xv.w) - b2f(rv.w);
    }
    float sc = 1.0f / fmaxf((float)deg, 1.0f);
    ushort4 o;
    o.x = f2b(a0 * sc); o.y = f2b(a1 * sc); o.z = f2b(a2 * sc); o.w = f2b(a3 * sc);
    *(ushort4*)(agg + (size_t)wid * DIM + lane * 4) = o;
}

// ---------------------------------------------------------------------------
// lv = loop_rel @ w_loop   (fp32, one 200-vector)
// ---------------------------------------------------------------------------
__global__ void lv_kernel(const float* __restrict__ lr, const float* __restrict__ wl,
                          float* __restrict__ lv) {
    int j = blockIdx.x * blockDim.x + threadIdx.x;
    if (j >= DIM) return;
    float acc = 0.f;
    for (int k = 0; k < DIM; ++k) acc += lr[k] * wl[k * DIM + j];
    lv[j] = acc;
}

// ---------------------------------------------------------------------------
// r_out = r_in @ w   fp32, tiny (rows=1000)
// ---------------------------------------------------------------------------
__global__ void rgemm_kernel(const float* __restrict__ r, const float* __restrict__ w,
                             float* __restrict__ out, int rows) {
    int g = blockIdx.x * 256 + threadIdx.x;
    if (g >= rows * DIM) return;
    int i = g / DIM, j = g - i * DIM;
    float acc = 0.f;
    for (int k = 0; k < DIM; ++k) acc += r[i * DIM + k] * w[k * DIM + j];
    out[g] = acc;
}

// ---------------------------------------------------------------------------
// MFMA layer, zero-LDS / zero-barrier: A rows are wave-exclusive -> direct
// global->VGPR bf16x8 loads; W fragments read straight from L2-resident WT.
// Over-reads at k>=200 hit zero-padded W columns; M-edge masked at write.
// ---------------------------------------------------------------------------
__global__ __launch_bounds__(256) void layer_mfma_kernel(
        const unsigned short* __restrict__ aggI, const unsigned short* __restrict__ aggO,
        const unsigned short* __restrict__ xin, const unsigned short* __restrict__ WT,
        const float* __restrict__ lv, const float* __restrict__ bias,
        unsigned short* __restrict__ out) {
    const int tid  = threadIdx.x;
    const int row0 = blockIdx.x * 128;
    const int wave = tid >> 6;
    const int lane = tid & 63;
    const int lr   = lane & 15;
    const int lq   = lane >> 4;
    const int arow = row0 + wave * 32 + lr;

    f32x4 acc[2][13];
#pragma unroll
    for (int m = 0; m < 2; ++m)
#pragma unroll
        for (int n = 0; n < 13; ++n) acc[m][n] = (f32x4){0.f, 0.f, 0.f, 0.f};

    for (int seg = 0; seg < 3; ++seg) {
        const unsigned short* Ap = (seg == 0) ? aggI : (seg == 1) ? aggO : xin;
        const unsigned short* Wp = WT + seg * 224;
#pragma unroll
        for (int c = 0; c < 7; ++c) {
            const int k = c * 32 + lq * 8;
            bf16x8 a0 = *(const bf16x8*)(Ap + (size_t)arow * 200 + k);
            bf16x8 a1 = *(const bf16x8*)(Ap + (size_t)(arow + 16) * 200 + k);
#pragma unroll
            for (int n = 0; n < 13; ++n) {
                bf16x8 b = *(const bf16x8*)(Wp + (size_t)(n * 16 + lr) * 672 + k);
                acc[0][n] = __builtin_amdgcn_mfma_f32_16x16x32_bf16(a0, b, acc[0][n], 0, 0, 0);
                acc[1][n] = __builtin_amdgcn_mfma_f32_16x16x32_bf16(a1, b, acc[1][n], 0, 0, 0);
            }
        }
    }

#pragma unroll
    for (int m = 0; m < 2; ++m) {
        int grow_base = row0 + wave * 32 + m * 16 + lq * 4;
#pragma unroll
        for (int n = 0; n < 13; ++n) {
            int col = n * 16 + lr;
            if (col < 200) {
                float lvc = lv[col], bc = bias[col];
#pragma unroll
                for (int r = 0; r < 4; ++r) {
                    int grow = grow_base + r;
                    if (grow < N_ENT) {
                        float v = (acc[m][n][r] - lvc) * (1.0f / 3.0f) + bc;
                        out[(size_t)grow * 200 + col] = f2b(fast_tanh(v));
                    }
                }
            }
        }
    }
}

// ---------------------------------------------------------------------------
// build ConvE input images with BN0 (bf16 out)
// ---------------------------------------------------------------------------
__global__ void img_kernel(const unsigned short* __restrict__ x, const float* __restrict__ r,
                           const int* __restrict__ sub, const int* __restrict__ rel,
                           const float* __restrict__ bn0g, const float* __restrict__ bn0b,
                           unsigned short* __restrict__ img) {
    int g = blockIdx.x * 256 + threadIdx.x;
    if (g >= BB * 2 * DIM) return;
    int b = g / 400, l = g - b * 400;
    int d = l >> 1;
    float v = (l & 1) ? r[(size_t)rel[b] * DIM + d] : b2f(x[(size_t)sub[b] * DIM + d]);
    float s0 = bn0g[0] * rsqrtf(1.0f + EPS_BN);
    img[g] = f2b(v * s0 + bn0b[0]);
}

// ---------------------------------------------------------------------------
// im2col: IM[b*196+p][64], k = i*7+j (49 real, 64 padded with zeros)
// ---------------------------------------------------------------------------
__global__ void im2col_kernel(const unsigned short* __restrict__ img,
                              unsigned short* __restrict__ IM) {
    int g = blockIdx.x * 256 + threadIdx.x;
    if (g >= FLATK / 200 * 256 * 64 * 200 / FLATK * FLATK) {}   // no-op
    if (g >= 50176 * 64) return;
    int row = g >> 6, k = g & 63;
    int b = row / 196, p = row - b * 196;
    int h = p / 14, w = p - h * 14;
    unsigned short v = 0;
    if (k < 49) {
        int i = k / 7, j = k - i * 7;
        v = img[b * 400 + (h + i) * 20 + (w + j)];
    }
    IM[g] = v;
}

// CWT[208][64] bf16: CWT[f][k] = conv_w[f][k], zero-padded
__global__ void cwt_kernel(const float* __restrict__ cw, unsigned short* __restrict__ CWT) {
    int g = blockIdx.x * 256 + threadIdx.x;
    if (g >= 208 * 64) return;
    int f = g >> 6, k = g & 63;
    CWT[g] = (f < 200 && k < 49) ? f2b(cw[f * 49 + k]) : 0;
}

// ---------------------------------------------------------------------------
// conv as MFMA: [50176 x 64] @ [64 x 200(pad 208)], zero-LDS/zero-barrier.
// Epilogue: +conv_b, BN1, relu, write CO_T[f*196+p][b] bf16 (fc-friendly).
// ---------------------------------------------------------------------------
__global__ __launch_bounds__(256) void conv_mfma_kernel(
        const unsigned short* __restrict__ IM, const unsigned short* __restrict__ CWT,
        const float* __restrict__ cb, const float* __restrict__ bn1g,
        const float* __restrict__ bn1b, unsigned short* __restrict__ CO_T) {
    const int tid  = threadIdx.x;
    const int row0 = blockIdx.x * 128;
    const int wave = tid >> 6;
    const int lane = tid & 63;
    const int lr   = lane & 15;
    const int lq   = lane >> 4;
    const int arow = row0 + wave * 32 + lr;

    f32x4 acc[2][13];
#pragma unroll
    for (int m = 0; m < 2; ++m)
#pragma unroll
        for (int n = 0; n < 13; ++n) acc[m][n] = (f32x4){0.f, 0.f, 0.f, 0.f};

#pragma unroll
    for (int c = 0; c < 2; ++c) {
        const int k = c * 32 + lq * 8;
        bf16x8 a0 = *(const bf16x8*)(IM + (size_t)arow * 64 + k);
        bf16x8 a1 = *(const bf16x8*)(IM + (size_t)(arow + 16) * 64 + k);
#pragma unroll
        for (int n = 0; n < 13; ++n) {
            bf16x8 b = *(const bf16x8*)(CWT + (size_t)(n * 16 + lr) * 64 + k);
            acc[0][n] = __builtin_amdgcn_mfma_f32_16x16x32_bf16(a0, b, acc[0][n], 0, 0, 0);
            acc[1][n] = __builtin_amdgcn_mfma_f32_16x16x32_bf16(a1, b, acc[1][n], 0, 0, 0);
        }
    }

#pragma unroll
    for (int m = 0; m < 2; ++m) {
        int grow_base = row0 + wave * 32 + m * 16 + lq * 4;
#pragma unroll
        for (int n = 0; n < 13; ++n) {
            int col = n * 16 + lr;          // filter
            if (col < 200) {
                float s1 = bn1g[col] * rsqrtf(1.0f + EPS_BN);
                float t1 = bn1b[col];
                float cbf = cb[col];
#pragma unroll
                for (int r = 0; r < 4; ++r) {
                    int grow = grow_base + r;          // b*196+p, always < 50176
                    int b = grow / 196, p = grow - b * 196;
                    float v = fmaxf((acc[m][n][r] + cbf) * s1 + t1, 0.f);
                    CO_T[(size_t)(col * 196 + p) * BB + b] = f2b(v);
                }
            }
        }
    }
}

// ---------------------------------------------------------------------------
// fc partial GEMM: acc_t[j][b] += sum_k CO_T[k][b] * fc_w[k][j]  (CO_T bf16)
// ---------------------------------------------------------------------------
__global__ void fc_kernel(const unsigned short* __restrict__ xt, const float* __restrict__ fw,
                          float* __restrict__ acc_t) {
    __shared__ float w[100][50];
    const int kc = blockIdx.x >> 2;
    const int j0 = (blockIdx.x & 3) * 50;
    const int b  = threadIdx.x;
    float acc[50];
#pragma unroll
    for (int c = 0; c < 50; ++c) acc[c] = 0.f;
    for (int ks = 0; ks < 4; ++ks) {
        int k0 = kc * 400 + ks * 100;
        __syncthreads();
        for (int idx = b; idx < 5000; idx += 256) {
            int kk = idx / 50, jj = idx - kk * 50;
            w[kk][jj] = fw[(size_t)(k0 + kk) * DIM + j0 + jj];
        }
        __syncthreads();
        for (int kk = 0; kk < 100; ++kk) {
            float xv = b2f(xt[(size_t)(k0 + kk) * BB + b]);
#pragma unroll
            for (int c = 0; c < 50; ++c) acc[c] += xv * w[kk][c];
        }
    }
    for (int c = 0; c < 50; ++c)
        atomicAdd(&acc_t[(size_t)(j0 + c) * BB + b], acc[c]);
}

// hb16[b][k=224] = relu((acc+fc_b)*bn2s+bn2b) bf16, zero-padded k>=200
__global__ void fc_epi_kernel(const float* __restrict__ acc_t, const float* __restrict__ fcb,
                              const float* __restrict__ g2, const float* __restrict__ b2v,
                              unsigned short* __restrict__ hb) {
    int g = blockIdx.x * 256 + threadIdx.x;
    if (g >= BB * 224) return;
    int b = g / 224, j = g - b * 224;
    unsigned short o = 0;
    if (j < 200) {
        float v = (acc_t[j * BB + b] + fcb[j]) * (g2[j] * rsqrtf(1.0f + EPS_BN)) + b2v[j];
        o = f2b(fmaxf(v, 0.f));
    }
    hb[g] = o;
}

// ---------------------------------------------------------------------------
// logits MFMA: D[b][ent] = sigmoid(h[b]·x[ent] + eb[ent]).
// M=256 batch (2 m-blocks), N=208 ents per block (481 n-blocks), K=224.
// A = hb16 [256][224] (L2), B = x2b rows (block-exclusive), zero-LDS.
// ---------------------------------------------------------------------------
__global__ __launch_bounds__(256) void logits_mfma_kernel(
        const unsigned short* __restrict__ x, const unsigned short* __restrict__ hb,
        const float* __restrict__ eb, float* __restrict__ out) {
    const int tid  = threadIdx.x;
    const int nb   = blockIdx.x >> 1;
    const int mb   = blockIdx.x & 1;
    const int ent0 = nb * 208;
    const int wave = tid >> 6;
    const int lane = tid & 63;
    const int lr   = lane & 15;
    const int lq   = lane >> 4;
    const int brow = mb * 128 + wave * 32 + lr;

    f32x4 acc[2][13];
#pragma unroll
    for (int m = 0; m < 2; ++m)
#pragma unroll
        for (int n = 0; n < 13; ++n) acc[m][n] = (f32x4){0.f, 0.f, 0.f, 0.f};

#pragma unroll
    for (int c = 0; c < 7; ++c) {
        const int k = c * 32 + lq * 8;
        bf16x8 a0 = *(const bf16x8*)(hb + (size_t)brow * 224 + k);
        bf16x8 a1 = *(const bf16x8*)(hb + (size_t)(brow + 16) * 224 + k);
#pragma unroll
        for (int n = 0; n < 13; ++n) {
            bf16x8 b = *(const bf16x8*)(x + (size_t)(ent0 + n * 16 + lr) * 200 + k);
            acc[0][n] = __builtin_amdgcn_mfma_f32_16x16x32_bf16(a0, b, acc[0][n], 0, 0, 0);
            acc[1][n] = __builtin_amdgcn_mfma_f32_16x16x32_bf16(a1, b, acc[1][n], 0, 0, 0);
        }
    }

#pragma unroll
    for (int m = 0; m < 2; ++m) {
        int b_base = mb * 128 + wave * 32 + m * 16 + lq * 4;
#pragma unroll
        for (int n = 0; n < 13; ++n) {
            int ent = ent0 + n * 16 + lr;
            if (ent < N_ENT) {
                float bias = eb[ent];
#pragma unroll
                for (int r = 0; r < 4; ++r) {
                    float v = acc[m][n][r] + bias;
                    out[(size_t)(b_base + r) * N_ENT + ent] = 1.0f / (1.0f + __expf(-v));
                }
            }
        }
    }
}

// ---------------------------------------------------------------------------
extern "C" void kernel_launch(void* const* d_in, const int* in_sizes, int n_in,
                              void* d_out, int out_size, void* d_ws, size_t ws_size,
                              hipStream_t stream) {
    const int*   sub        = (const int*)  d_in[0];
    const int*   rel        = (const int*)  d_in[1];
    const int*   edge_index = (const int*)  d_in[2];
    const int*   edge_type  = (const int*)  d_in[3];
    const float* init_embed = (const float*)d_in[4];
    const float* init_rel   = (const float*)d_in[5];
    const float* loop_rel1  = (const float*)d_in[6];
    const float* loop_rel2  = (const float*)d_in[7];
    const float* w_in1      = (const float*)d_in[8];
    const float* w_out1     = (const float*)d_in[9];
    const float* w_loop1    = (const float*)d_in[10];
    const float* w_rel1     = (const float*)d_in[11];
    const float* b1         = (const float*)d_in[12];
    const float* w_in2      = (const float*)d_in[13];
    const float* w_out2     = (const float*)d_in[14];
    const float* w_loop2    = (const float*)d_in[15];
    const float* w_rel2     = (const float*)d_in[16];
    const float* b2         = (const float*)d_in[17];
    const float* conv_w     = (const float*)d_in[18];
    const float* conv_b     = (const float*)d_in[19];
    const float* bn0_g      = (const float*)d_in[20];
    const float* bn0_b      = (const float*)d_in[21];
    const float* bn1_g      = (const float*)d_in[22];
    const float* bn1_b      = (const float*)d_in[23];
    const float* bn2_g      = (const float*)d_in[24];
    const float* bn2_b      = (const float*)d_in[25];
    const float* fc_w       = (const float*)d_in[26];
    const float* fc_b       = (const float*)d_in[27];
    const float* ent_bias   = (const float*)d_in[28];

    // ---- bf16 region ----
    unsigned short* aggb = (unsigned short*)d_ws;     // 40,000,000
    unsigned short* x0b  = aggb + 40000000;           // 20,000,000 (init; reused as x2b)
    unsigned short* x1b  = x0b  + 20000000;           // 20,000,000
    unsigned short* r0b  = x1b  + 20000000;           //    200,000
    unsigned short* r1b  = r0b  + 200000;             //    200,000
    unsigned short* WT   = r1b  + 200000;             //    139,776
    unsigned short* img  = WT   + 139776;             //    102,400
    unsigned short* IM   = img  + 102400;             //  3,211,264 (50176*64)
    unsigned short* CWT  = IM   + 3211264;            //     13,312
    unsigned short* CO_T = CWT  + 13312;              // 10,035,200 (39200*256)
    unsigned short* hb16 = CO_T + 10035200;           //     57,344 (256*224)
    // ---- fp32 region ----
    float* fbase = (float*)(hb16 + 57344);
    float* r1f  = fbase;                              // 200,000
    float* r2f  = r1f  + 200000;                      // 200,000
    float* lv   = r2f  + 200000;                      // 256
    float* accT = lv   + 256;                         // 51,200

    // CSR ints alias CO_T (last CSR read = gather2, before conv writes CO_T)
    int* esrc      = (int*)CO_T;                      // 500,000
    int* eet       = esrc + E_TOT;                    // 500,000
    int* cnt       = eet  + E_TOT;                    // 200,000
    int* row_start = cnt  + NROWS;                    // 200,000
    int* row_cur   = row_start + NROWS;               // 200,000
    int* blockSum  = row_cur + NROWS;                 // 98

    unsigned short* aggIb = aggb;
    unsigned short* aggOb = aggb + (size_t)N_ENT * DIM;
    unsigned short* x2b   = x0b;

    const int gather_blocks = (NROWS + 3) / 4;
    const int layer_blocks  = (N_ENT + 127) / 128;    // 782
    const int wstack_blocks = (208 * 672 + 255) / 256;

    // ---- converts + CSR build ----
    convert_kernel<<<(N_ENT * DIM + 1023) / 1024, 256, 0, stream>>>(init_embed, x0b, N_ENT * DIM);
    convert_kernel<<<(N_REL2 * DIM + 1023) / 1024, 256, 0, stream>>>(init_rel, r0b, N_REL2 * DIM);
    hipMemsetAsync(cnt, 0, (size_t)NROWS * 4, stream);
    hist_kernel<<<(E_TOT + 255) / 256, 256, 0, stream>>>(edge_index, cnt);
    scan1_kernel<<<SNBLK, 256, 0, stream>>>(cnt, row_start, blockSum);
    scan2_kernel<<<1, 1, 0, stream>>>(blockSum);
    scan3_kernel<<<(NROWS + 255) / 256, 256, 0, stream>>>(row_start, row_cur, blockSum);
    fill_kernel<<<(E_TOT + 255) / 256, 256, 0, stream>>>(edge_index, edge_type, row_cur,
                                                         esrc, eet);

    // ---- layer 1 ----
    wstack_kernel<<<wstack_blocks, 256, 0, stream>>>(w_in1, w_out1, w_loop1, WT);
    gather_kernel<<<gather_blocks, 256, 0, stream>>>(x0b, r0b, esrc, eet, row_start, cnt, aggb);
    lv_kernel<<<1, 256, 0, stream>>>(loop_rel1, w_loop1, lv);
    layer_mfma_kernel<<<layer_blocks, 256, 0, stream>>>(aggIb, aggOb, x0b, WT, lv, b1, x1b);
    rgemm_kernel<<<(N_REL2 * DIM + 255) / 256, 256, 0, stream>>>(init_rel, w_rel1, r1f, N_REL2);
    convert_kernel<<<(N_REL2 * DIM + 1023) / 1024, 256, 0, stream>>>(r1f, r1b, N_REL2 * DIM);

    // ---- layer 2 ----
    wstack_kernel<<<wstack_blocks, 256, 0, stream>>>(w_in2, w_out2, w_loop2, WT);
    gather_kernel<<<gather_blocks, 256, 0, stream>>>(x1b, r1b, esrc, eet, row_start, cnt, aggb);
    lv_kernel<<<1, 256, 0, stream>>>(loop_rel2, w_loop2, lv);
    layer_mfma_kernel<<<layer_blocks, 256, 0, stream>>>(aggIb, aggOb, x1b, WT, lv, b2, x2b);
    rgemm_kernel<<<(N_REL2 * DIM + 255) / 256, 256, 0, stream>>>(r1f, w_rel2, r2f, N_REL2);

    // ---- ConvE ----
    img_kernel<<<(BB * 400 + 255) / 256, 256, 0, stream>>>(x2b, r2f, sub, rel,
                                                           bn0_g, bn0_b, img);
    im2col_kernel<<<(50176 * 64 + 255) / 256, 256, 0, stream>>>(img, IM);
    cwt_kernel<<<(208 * 64 + 255) / 256, 256, 0, stream>>>(conv_w, CWT);
    conv_mfma_kernel<<<50176 / 128, 256, 0, stream>>>(IM, CWT, conv_b, bn1_g, bn1_b, CO_T);
    hipMemsetAsync(accT, 0, (size_t)51200 * 4, stream);
    fc_kernel<<<98 * 4, 256, 0, stream>>>(CO_T, fc_w, accT);
    fc_epi_kernel<<<(BB * 224 + 255) / 256, 256, 0, stream>>>(accT, fc_b, bn2_g, bn2_b, hb16);

    // ---- logits ----
    logits_mfma_kernel<<<481 * 2, 256, 0, stream>>>(x2b, hb16, ent_bias, (float*)d_out);
}

// Round 5
// 868.908 us; speedup vs baseline: 6.0674x; 1.3187x over previous
//
#include <hip/hip_runtime.h>
#include <math.h>

#define N_ENT   100000
#define N_REL2  1000
#define E_TOT   500000
#define E_HALF  250000
#define DIM     200
#define BB      256
#define NFILT   200
#define FLATK   39200
#define EPS_BN  1e-5f

#define NROWS   200000          // 100k in-rows + 100k out-rows
#define SCHUNK  2048
#define SNBLK   ((NROWS + SCHUNK - 1) / SCHUNK)   // 98

typedef __attribute__((ext_vector_type(8))) short bf16x8;   // 8 bf16 (4 VGPRs)
typedef __attribute__((ext_vector_type(4))) float f32x4;

__device__ __forceinline__ unsigned short f2b(float f) {
    union { float f; unsigned u; } c; c.f = f;
    unsigned u = c.u;
    u += 0x7fffu + ((u >> 16) & 1u);          // round-to-nearest-even
    return (unsigned short)(u >> 16);
}
__device__ __forceinline__ float b2f(unsigned short h) {
    union { unsigned u; float f; } c; c.u = ((unsigned)h) << 16;
    return c.f;
}
__device__ __forceinline__ float fast_tanh(float x) {
    float ax = fabsf(x);
    float e = __expf(-2.0f * ax);             // in (0,1], never overflows
    float t = (1.0f - e) / (1.0f + e);
    return copysignf(t, x);
}

// ---------------------------------------------------------------------------
// fp32 -> bf16 convert
// ---------------------------------------------------------------------------
__global__ void convert_kernel(const float* __restrict__ s, unsigned short* __restrict__ d,
                               int n) {
    int i = (blockIdx.x * 256 + threadIdx.x) * 4;
    if (i + 3 < n) {
        float4 v = *(const float4*)(s + i);
        ushort4 o;
        o.x = f2b(v.x); o.y = f2b(v.y); o.z = f2b(v.z); o.w = f2b(v.w);
        *(ushort4*)(d + i) = o;
    } else {
        for (; i < n; ++i) d[i] = f2b(s[i]);
    }
}

// ---------------------------------------------------------------------------
// Build WstackT[224][672] bf16: WstackT[j][seg*224+k] = Wseg[k][j] (zero-pad)
// cols 200..223 and k 200..223 are zero (N/K padding for the MFMA tiles).
// ---------------------------------------------------------------------------
__global__ void wstack_kernel(const float* __restrict__ wIn, const float* __restrict__ wOut,
                              const float* __restrict__ wLoop, unsigned short* __restrict__ WT) {
    int g = blockIdx.x * 256 + threadIdx.x;
    if (g >= 224 * 672) return;
    int j = g / 672, t = g - j * 672;
    int seg = t / 224, k = t - seg * 224;
    float v = 0.f;
    if (j < 200 && k < 200)
        v = (seg == 0 ? wIn : seg == 1 ? wOut : wLoop)[k * 200 + j];
    WT[g] = f2b(v);
}

// ---------------------------------------------------------------------------
// CSR build
// ---------------------------------------------------------------------------
__global__ void hist_kernel(const int* __restrict__ ei, int* __restrict__ cnt) {
    int e = blockIdx.x * 256 + threadIdx.x;
    if (e >= E_TOT) return;
    int row = ei[E_TOT + e] + (e < E_HALF ? 0 : N_ENT);
    atomicAdd(&cnt[row], 1);
}

__global__ void scan1_kernel(const int* __restrict__ cnt, int* __restrict__ row_start,
                             int* __restrict__ blockSum) {
    __shared__ int tsum[256];
    const int t = threadIdx.x;
    const int base = blockIdx.x * SCHUNK + t * 8;
    int v[8];
    int s = 0;
#pragma unroll
    for (int i = 0; i < 8; ++i) {
        int idx = base + i;
        int c = (idx < NROWS) ? cnt[idx] : 0;
        v[i] = s;
        s += c;
    }
    tsum[t] = s;
    __syncthreads();
    for (int off = 1; off < 256; off <<= 1) {
        int x = (t >= off) ? tsum[t - off] : 0;
        __syncthreads();
        if (t >= off) tsum[t] += x;
        __syncthreads();
    }
    int texc = (t == 0) ? 0 : tsum[t - 1];
    if (t == 0) blockSum[blockIdx.x] = tsum[255];
#pragma unroll
    for (int i = 0; i < 8; ++i) {
        int idx = base + i;
        if (idx < NROWS) row_start[idx] = texc + v[i];
    }
}

__global__ void scan2_kernel(int* __restrict__ blockSum) {
    int s = 0;
    for (int i = 0; i < SNBLK; ++i) { int c = blockSum[i]; blockSum[i] = s; s += c; }
}

__global__ void scan3_kernel(int* __restrict__ row_start, int* __restrict__ row_cur,
                             const int* __restrict__ blockSum) {
    int i = blockIdx.x * 256 + threadIdx.x;
    if (i >= NROWS) return;
    int v = row_start[i] + blockSum[i / SCHUNK];
    row_start[i] = v;
    row_cur[i] = v;
}

__global__ void fill_kernel(const int* __restrict__ ei, const int* __restrict__ et,
                            int* __restrict__ row_cur,
                            int* __restrict__ esrc, int* __restrict__ eet) {
    int e = blockIdx.x * 256 + threadIdx.x;
    if (e >= E_TOT) return;
    int row = ei[E_TOT + e] + (e < E_HALF ? 0 : N_ENT);
    int pos = atomicAdd(&row_cur[row], 1);
    esrc[pos] = ei[e];
    eet[pos] = et[e];
}

// ---------------------------------------------------------------------------
// gather (bf16): one wave per CSR row, lanes 0..49 own 4 bf16 each; fp32 accum
// ---------------------------------------------------------------------------
__global__ void gather_kernel(const unsigned short* __restrict__ x,
                              const unsigned short* __restrict__ r,
                              const int* __restrict__ esrc, const int* __restrict__ eet,
                              const int* __restrict__ row_start, const int* __restrict__ cnt,
                              unsigned short* __restrict__ agg) {
    int wid = blockIdx.x * 4 + (threadIdx.x >> 6);
    if (wid >= NROWS) return;
    int lane = threadIdx.x & 63;
    if (lane >= 50) return;
    int start = row_start[wid];
    int deg = cnt[wid];
    float a0 = 0.f, a1 = 0.f, a2 = 0.f, a3 = 0.f;
    for (int i = 0; i < deg; ++i) {
        int s = esrc[start + i];
        int t = eet[start + i];
        ushort4 xv = *(const ushort4*)(x + (size_t)s * DIM + lane * 4);
        ushort4 rv = *(const ushort4*)(r + (size_t)t * DIM + lane * 4);
        a0 += b2f(xv.x) - b2f(rv.x);
        a1 += b2f(xv.y) - b2f(rv.y);
        a2 += b2f(xv.z) - b2f(rv.z);
        a3 += b2f(xv.w) - b2f(rv.w);
    }
    float sc = 1.0f / fmaxf((float)deg, 1.0f);
    ushort4 o;
    o.x = f2b(a0 * sc); o.y = f2b(a1 * sc); o.z = f2b(a2 * sc); o.w = f2b(a3 * sc);
    *(ushort4*)(agg + (size_t)wid * DIM + lane * 4) = o;
}

// ---------------------------------------------------------------------------
// lv = loop_rel @ w_loop   (fp32, one 200-vector)
// ---------------------------------------------------------------------------
__global__ void lv_kernel(const float* __restrict__ lr, const float* __restrict__ wl,
                          float* __restrict__ lv) {
    int j = blockIdx.x * blockDim.x + threadIdx.x;
    if (j >= DIM) return;
    float acc = 0.f;
    for (int k = 0; k < DIM; ++k) acc += lr[k] * wl[k * DIM + j];
    lv[j] = acc;
}

// ---------------------------------------------------------------------------
// r_out = r_in @ w   fp32, tiny (rows=1000)
// ---------------------------------------------------------------------------
__global__ void rgemm_kernel(const float* __restrict__ r, const float* __restrict__ w,
                             float* __restrict__ out, int rows) {
    int g = blockIdx.x * 256 + threadIdx.x;
    if (g >= rows * DIM) return;
    int i = g / DIM, j = g - i * DIM;
    float acc = 0.f;
    for (int k = 0; k < DIM; ++k) acc += r[i * DIM + k] * w[k * DIM + j];
    out[g] = acc;
}

// ---------------------------------------------------------------------------
// MFMA layer v3: per-seg W staged in LDS (224x224 bf16 = 98KB, 3 barriers
// total), A direct-from-global with 3-slot register prefetch issued 2 chunks
// ahead (all indices static after full unroll). 512 thr = 8 waves (4M x 2N),
// block tile 256 rows x 224 cols, wave tile 64 x 112 -> 4 MFMAs per B-frag.
// ---------------------------------------------------------------------------
#define LOAD_A(g, buf) do {                                                     \
    const unsigned short* Ap_ = Aseg[(g) / 7];                                  \
    const unsigned short* base_ = Ap_ + (size_t)arow * 200 + ((g) % 7) * 32 + lq * 8; \
    buf[0] = *(const bf16x8*)(base_);                                           \
    buf[1] = *(const bf16x8*)(base_ + 16 * 200);                                \
    buf[2] = *(const bf16x8*)(base_ + 32 * 200);                                \
    buf[3] = *(const bf16x8*)(base_ + 48 * 200);                                \
} while (0)

__global__ __launch_bounds__(512, 2) void layer_mfma_kernel(
        const unsigned short* __restrict__ aggI, const unsigned short* __restrict__ aggO,
        const unsigned short* __restrict__ xin, const unsigned short* __restrict__ WT,
        const float* __restrict__ lv, const float* __restrict__ bias,
        unsigned short* __restrict__ out) {
    extern __shared__ unsigned short Wl[];        // [224 cols][224 k] = 100,352 B
    const int tid  = threadIdx.x;
    const int wave = tid >> 6;
    const int wm   = wave >> 1;          // 0..3 : 64-row group
    const int wn   = wave & 1;           // 0..1 : 112-col group
    const int lane = tid & 63;
    const int lr   = lane & 15;
    const int lq   = lane >> 4;
    const int row0 = blockIdx.x * 256;
    const int arow = row0 + wm * 64 + lr;

    const unsigned short* const Aseg[3] = { aggI, aggO, xin };

    f32x4 acc[4][7];
#pragma unroll
    for (int m = 0; m < 4; ++m)
#pragma unroll
        for (int n = 0; n < 7; ++n) acc[m][n] = (f32x4){0.f, 0.f, 0.f, 0.f};

    bf16x8 apf[3][4];                     // rotating A prefetch, depth 2
    LOAD_A(0, apf[0]);
    LOAD_A(1, apf[1]);

#pragma unroll
    for (int seg = 0; seg < 3; ++seg) {
        if (seg) __syncthreads();         // waves done reading previous Wl
        // stage W_seg: 224 cols x 224 k, 16B units (28 per col)
        for (int u = tid; u < 6272; u += 512) {
            int col = u / 28, kq = u - col * 28;
            *(int4*)(&Wl[col * 224 + kq * 8]) =
                *(const int4*)(WT + (size_t)col * 672 + seg * 224 + kq * 8);
        }
        __syncthreads();
#pragma unroll
        for (int c = 0; c < 7; ++c) {
            const int g = seg * 7 + c;
            if (g + 2 < 21) LOAD_A(g + 2, apf[(g + 2) % 3]);
#pragma unroll
            for (int n = 0; n < 7; ++n) {
                bf16x8 b = *(const bf16x8*)(&Wl[(wn * 112 + n * 16 + lr) * 224 + c * 32 + lq * 8]);
                acc[0][n] = __builtin_amdgcn_mfma_f32_16x16x32_bf16(apf[g % 3][0], b, acc[0][n], 0, 0, 0);
                acc[1][n] = __builtin_amdgcn_mfma_f32_16x16x32_bf16(apf[g % 3][1], b, acc[1][n], 0, 0, 0);
                acc[2][n] = __builtin_amdgcn_mfma_f32_16x16x32_bf16(apf[g % 3][2], b, acc[2][n], 0, 0, 0);
                acc[3][n] = __builtin_amdgcn_mfma_f32_16x16x32_bf16(apf[g % 3][3], b, acc[3][n], 0, 0, 0);
            }
        }
    }

#pragma unroll
    for (int m = 0; m < 4; ++m) {
        int row_base = row0 + wm * 64 + m * 16 + lq * 4;
#pragma unroll
        for (int n = 0; n < 7; ++n) {
            int col = wn * 112 + n * 16 + lr;
            if (col < 200) {
                float lvc = lv[col], bc = bias[col];
#pragma unroll
                for (int r = 0; r < 4; ++r) {
                    int row = row_base + r;
                    if (row < N_ENT) {
                        float v = (acc[m][n][r] - lvc) * (1.0f / 3.0f) + bc;
                        out[(size_t)row * 200 + col] = f2b(fast_tanh(v));
                    }
                }
            }
        }
    }
}

// ---------------------------------------------------------------------------
// build ConvE input images with BN0 (bf16 out)
// ---------------------------------------------------------------------------
__global__ void img_kernel(const unsigned short* __restrict__ x, const float* __restrict__ r,
                           const int* __restrict__ sub, const int* __restrict__ rel,
                           const float* __restrict__ bn0g, const float* __restrict__ bn0b,
                           unsigned short* __restrict__ img) {
    int g = blockIdx.x * 256 + threadIdx.x;
    if (g >= BB * 2 * DIM) return;
    int b = g / 400, l = g - b * 400;
    int d = l >> 1;
    float v = (l & 1) ? r[(size_t)rel[b] * DIM + d] : b2f(x[(size_t)sub[b] * DIM + d]);
    float s0 = bn0g[0] * rsqrtf(1.0f + EPS_BN);
    img[g] = f2b(v * s0 + bn0b[0]);
}

// ---------------------------------------------------------------------------
// im2col: IM[b*196+p][64], k = i*7+j (49 real, 64 padded with zeros)
// ---------------------------------------------------------------------------
__global__ void im2col_kernel(const unsigned short* __restrict__ img,
                              unsigned short* __restrict__ IM) {
    int g = blockIdx.x * 256 + threadIdx.x;
    if (g >= 50176 * 64) return;
    int row = g >> 6, k = g & 63;
    int b = row / 196, p = row - b * 196;
    int h = p / 14, w = p - h * 14;
    unsigned short v = 0;
    if (k < 49) {
        int i = k / 7, j = k - i * 7;
        v = img[b * 400 + (h + i) * 20 + (w + j)];
    }
    IM[g] = v;
}

// CWT[208][64] bf16: CWT[f][k] = conv_w[f][k], zero-padded
__global__ void cwt_kernel(const float* __restrict__ cw, unsigned short* __restrict__ CWT) {
    int g = blockIdx.x * 256 + threadIdx.x;
    if (g >= 208 * 64) return;
    int f = g >> 6, k = g & 63;
    CWT[g] = (f < 200 && k < 49) ? f2b(cw[f * 49 + k]) : 0;
}

// ---------------------------------------------------------------------------
// conv as MFMA: [50176 x 64] @ [64 x 200(pad 208)], zero-LDS/zero-barrier.
// Epilogue: +conv_b, BN1, relu, write CO_T[f*196+p][b] bf16 (fc-friendly).
// ---------------------------------------------------------------------------
__global__ __launch_bounds__(256) void conv_mfma_kernel(
        const unsigned short* __restrict__ IM, const unsigned short* __restrict__ CWT,
        const float* __restrict__ cb, const float* __restrict__ bn1g,
        const float* __restrict__ bn1b, unsigned short* __restrict__ CO_T) {
    const int tid  = threadIdx.x;
    const int row0 = blockIdx.x * 128;
    const int wave = tid >> 6;
    const int lane = tid & 63;
    const int lr   = lane & 15;
    const int lq   = lane >> 4;
    const int arow = row0 + wave * 32 + lr;

    f32x4 acc[2][13];
#pragma unroll
    for (int m = 0; m < 2; ++m)
#pragma unroll
        for (int n = 0; n < 13; ++n) acc[m][n] = (f32x4){0.f, 0.f, 0.f, 0.f};

#pragma unroll
    for (int c = 0; c < 2; ++c) {
        const int k = c * 32 + lq * 8;
        bf16x8 a0 = *(const bf16x8*)(IM + (size_t)arow * 64 + k);
        bf16x8 a1 = *(const bf16x8*)(IM + (size_t)(arow + 16) * 64 + k);
#pragma unroll
        for (int n = 0; n < 13; ++n) {
            bf16x8 b = *(const bf16x8*)(CWT + (size_t)(n * 16 + lr) * 64 + k);
            acc[0][n] = __builtin_amdgcn_mfma_f32_16x16x32_bf16(a0, b, acc[0][n], 0, 0, 0);
            acc[1][n] = __builtin_amdgcn_mfma_f32_16x16x32_bf16(a1, b, acc[1][n], 0, 0, 0);
        }
    }

#pragma unroll
    for (int m = 0; m < 2; ++m) {
        int grow_base = row0 + wave * 32 + m * 16 + lq * 4;
#pragma unroll
        for (int n = 0; n < 13; ++n) {
            int col = n * 16 + lr;          // filter
            if (col < 200) {
                float s1 = bn1g[col] * rsqrtf(1.0f + EPS_BN);
                float t1 = bn1b[col];
                float cbf = cb[col];
#pragma unroll
                for (int r = 0; r < 4; ++r) {
                    int grow = grow_base + r;          // b*196+p, always < 50176
                    int b = grow / 196, p = grow - b * 196;
                    float v = fmaxf((acc[m][n][r] + cbf) * s1 + t1, 0.f);
                    CO_T[(size_t)(col * 196 + p) * BB + b] = f2b(v);
                }
            }
        }
    }
}

// ---------------------------------------------------------------------------
// fc partial GEMM: acc_t[j][b] += sum_k CO_T[k][b] * fc_w[k][j]  (CO_T bf16)
// ---------------------------------------------------------------------------
__global__ void fc_kernel(const unsigned short* __restrict__ xt, const float* __restrict__ fw,
                          float* __restrict__ acc_t) {
    __shared__ float w[100][50];
    const int kc = blockIdx.x >> 2;
    const int j0 = (blockIdx.x & 3) * 50;
    const int b  = threadIdx.x;
    float acc[50];
#pragma unroll
    for (int c = 0; c < 50; ++c) acc[c] = 0.f;
    for (int ks = 0; ks < 4; ++ks) {
        int k0 = kc * 400 + ks * 100;
        __syncthreads();
        for (int idx = b; idx < 5000; idx += 256) {
            int kk = idx / 50, jj = idx - kk * 50;
            w[kk][jj] = fw[(size_t)(k0 + kk) * DIM + j0 + jj];
        }
        __syncthreads();
        for (int kk = 0; kk < 100; ++kk) {
            float xv = b2f(xt[(size_t)(k0 + kk) * BB + b]);
#pragma unroll
            for (int c = 0; c < 50; ++c) acc[c] += xv * w[kk][c];
        }
    }
    for (int c = 0; c < 50; ++c)
        atomicAdd(&acc_t[(size_t)(j0 + c) * BB + b], acc[c]);
}

// hb16[b][k=224] = relu((acc+fc_b)*bn2s+bn2b) bf16, zero-padded k>=200
__global__ void fc_epi_kernel(const float* __restrict__ acc_t, const float* __restrict__ fcb,
                              const float* __restrict__ g2, const float* __restrict__ b2v,
                              unsigned short* __restrict__ hb) {
    int g = blockIdx.x * 256 + threadIdx.x;
    if (g >= BB * 224) return;
    int b = g / 224, j = g - b * 224;
    unsigned short o = 0;
    if (j < 200) {
        float v = (acc_t[j * BB + b] + fcb[j]) * (g2[j] * rsqrtf(1.0f + EPS_BN)) + b2v[j];
        o = f2b(fmaxf(v, 0.f));
    }
    hb[g] = o;
}

// ---------------------------------------------------------------------------
// logits MFMA: D[b][ent] = sigmoid(h[b]·x[ent] + eb[ent]).
// ---------------------------------------------------------------------------
__global__ __launch_bounds__(256) void logits_mfma_kernel(
        const unsigned short* __restrict__ x, const unsigned short* __restrict__ hb,
        const float* __restrict__ eb, float* __restrict__ out) {
    const int tid  = threadIdx.x;
    const int nb   = blockIdx.x >> 1;
    const int mb   = blockIdx.x & 1;
    const int ent0 = nb * 208;
    const int wave = tid >> 6;
    const int lane = tid & 63;
    const int lr   = lane & 15;
    const int lq   = lane >> 4;
    const int brow = mb * 128 + wave * 32 + lr;

    f32x4 acc[2][13];
#pragma unroll
    for (int m = 0; m < 2; ++m)
#pragma unroll
        for (int n = 0; n < 13; ++n) acc[m][n] = (f32x4){0.f, 0.f, 0.f, 0.f};

#pragma unroll
    for (int c = 0; c < 7; ++c) {
        const int k = c * 32 + lq * 8;
        bf16x8 a0 = *(const bf16x8*)(hb + (size_t)brow * 224 + k);
        bf16x8 a1 = *(const bf16x8*)(hb + (size_t)(brow + 16) * 224 + k);
#pragma unroll
        for (int n = 0; n < 13; ++n) {
            bf16x8 b = *(const bf16x8*)(x + (size_t)(ent0 + n * 16 + lr) * 200 + k);
            acc[0][n] = __builtin_amdgcn_mfma_f32_16x16x32_bf16(a0, b, acc[0][n], 0, 0, 0);
            acc[1][n] = __builtin_amdgcn_mfma_f32_16x16x32_bf16(a1, b, acc[1][n], 0, 0, 0);
        }
    }

#pragma unroll
    for (int m = 0; m < 2; ++m) {
        int b_base = mb * 128 + wave * 32 + m * 16 + lq * 4;
#pragma unroll
        for (int n = 0; n < 13; ++n) {
            int ent = ent0 + n * 16 + lr;
            if (ent < N_ENT) {
                float bias = eb[ent];
#pragma unroll
                for (int r = 0; r < 4; ++r) {
                    float v = acc[m][n][r] + bias;
                    out[(size_t)(b_base + r) * N_ENT + ent] = 1.0f / (1.0f + __expf(-v));
                }
            }
        }
    }
}

// ---------------------------------------------------------------------------
extern "C" void kernel_launch(void* const* d_in, const int* in_sizes, int n_in,
                              void* d_out, int out_size, void* d_ws, size_t ws_size,
                              hipStream_t stream) {
    const int*   sub        = (const int*)  d_in[0];
    const int*   rel        = (const int*)  d_in[1];
    const int*   edge_index = (const int*)  d_in[2];
    const int*   edge_type  = (const int*)  d_in[3];
    const float* init_embed = (const float*)d_in[4];
    const float* init_rel   = (const float*)d_in[5];
    const float* loop_rel1  = (const float*)d_in[6];
    const float* loop_rel2  = (const float*)d_in[7];
    const float* w_in1      = (const float*)d_in[8];
    const float* w_out1     = (const float*)d_in[9];
    const float* w_loop1    = (const float*)d_in[10];
    const float* w_rel1     = (const float*)d_in[11];
    const float* b1         = (const float*)d_in[12];
    const float* w_in2      = (const float*)d_in[13];
    const float* w_out2     = (const float*)d_in[14];
    const float* w_loop2    = (const float*)d_in[15];
    const float* w_rel2     = (const float*)d_in[16];
    const float* b2         = (const float*)d_in[17];
    const float* conv_w     = (const float*)d_in[18];
    const float* conv_b     = (const float*)d_in[19];
    const float* bn0_g      = (const float*)d_in[20];
    const float* bn0_b      = (const float*)d_in[21];
    const float* bn1_g      = (const float*)d_in[22];
    const float* bn1_b      = (const float*)d_in[23];
    const float* bn2_g      = (const float*)d_in[24];
    const float* bn2_b      = (const float*)d_in[25];
    const float* fc_w       = (const float*)d_in[26];
    const float* fc_b       = (const float*)d_in[27];
    const float* ent_bias   = (const float*)d_in[28];

    // ---- bf16 region ----
    unsigned short* aggb = (unsigned short*)d_ws;     // 40,000,000
    unsigned short* x0b  = aggb + 40000000;           // 20,000,000 (init; reused as x2b)
    unsigned short* x1b  = x0b  + 20000000;           // 20,000,000
    unsigned short* r0b  = x1b  + 20000000;           //    200,000
    unsigned short* r1b  = r0b  + 200000;             //    200,000
    unsigned short* WT   = r1b  + 200000;             //    150,528 (224*672)
    unsigned short* img  = WT   + 150528;             //    102,400
    unsigned short* IM   = img  + 102400;             //  3,211,264 (50176*64)
    unsigned short* CWT  = IM   + 3211264;            //     13,312
    unsigned short* CO_T = CWT  + 13312;              // 10,035,200 (39200*256)
    unsigned short* hb16 = CO_T + 10035200;           //     57,344 (256*224)
    // ---- fp32 region ----
    float* fbase = (float*)(hb16 + 57344);
    float* r1f  = fbase;                              // 200,000
    float* r2f  = r1f  + 200000;                      // 200,000
    float* lv   = r2f  + 200000;                      // 256
    float* accT = lv   + 256;                         // 51,200

    // CSR ints alias CO_T (last CSR read = gather2, before conv writes CO_T)
    int* esrc      = (int*)CO_T;                      // 500,000
    int* eet       = esrc + E_TOT;                    // 500,000
    int* cnt       = eet  + E_TOT;                    // 200,000
    int* row_start = cnt  + NROWS;                    // 200,000
    int* row_cur   = row_start + NROWS;               // 200,000
    int* blockSum  = row_cur + NROWS;                 // 98

    unsigned short* aggIb = aggb;
    unsigned short* aggOb = aggb + (size_t)N_ENT * DIM;
    unsigned short* x2b   = x0b;

    const int gather_blocks = (NROWS + 3) / 4;
    const int layer_blocks  = (N_ENT + 255) / 256;    // 391 (512-thread blocks)
    const int wstack_blocks = (224 * 672 + 255) / 256;
    const size_t layer_lds  = 224 * 224 * sizeof(unsigned short);   // 100,352 B

    // ---- converts + CSR build ----
    convert_kernel<<<(N_ENT * DIM + 1023) / 1024, 256, 0, stream>>>(init_embed, x0b, N_ENT * DIM);
    convert_kernel<<<(N_REL2 * DIM + 1023) / 1024, 256, 0, stream>>>(init_rel, r0b, N_REL2 * DIM);
    hipMemsetAsync(cnt, 0, (size_t)NROWS * 4, stream);
    hist_kernel<<<(E_TOT + 255) / 256, 256, 0, stream>>>(edge_index, cnt);
    scan1_kernel<<<SNBLK, 256, 0, stream>>>(cnt, row_start, blockSum);
    scan2_kernel<<<1, 1, 0, stream>>>(blockSum);
    scan3_kernel<<<(NROWS + 255) / 256, 256, 0, stream>>>(row_start, row_cur, blockSum);
    fill_kernel<<<(E_TOT + 255) / 256, 256, 0, stream>>>(edge_index, edge_type, row_cur,
                                                         esrc, eet);

    // ---- layer 1 ----
    wstack_kernel<<<wstack_blocks, 256, 0, stream>>>(w_in1, w_out1, w_loop1, WT);
    gather_kernel<<<gather_blocks, 256, 0, stream>>>(x0b, r0b, esrc, eet, row_start, cnt, aggb);
    lv_kernel<<<1, 256, 0, stream>>>(loop_rel1, w_loop1, lv);
    layer_mfma_kernel<<<layer_blocks, 512, layer_lds, stream>>>(aggIb, aggOb, x0b, WT, lv, b1, x1b);
    rgemm_kernel<<<(N_REL2 * DIM + 255) / 256, 256, 0, stream>>>(init_rel, w_rel1, r1f, N_REL2);
    convert_kernel<<<(N_REL2 * DIM + 1023) / 1024, 256, 0, stream>>>(r1f, r1b, N_REL2 * DIM);

    // ---- layer 2 ----
    wstack_kernel<<<wstack_blocks, 256, 0, stream>>>(w_in2, w_out2, w_loop2, WT);
    gather_kernel<<<gather_blocks, 256, 0, stream>>>(x1b, r1b, esrc, eet, row_start, cnt, aggb);
    lv_kernel<<<1, 256, 0, stream>>>(loop_rel2, w_loop2, lv);
    layer_mfma_kernel<<<layer_blocks, 512, layer_lds, stream>>>(aggIb, aggOb, x1b, WT, lv, b2, x2b);
    rgemm_kernel<<<(N_REL2 * DIM + 255) / 256, 256, 0, stream>>>(r1f, w_rel2, r2f, N_REL2);

    // ---- ConvE ----
    img_kernel<<<(BB * 400 + 255) / 256, 256, 0, stream>>>(x2b, r2f, sub, rel,
                                                           bn0_g, bn0_b, img);
    im2col_kernel<<<(50176 * 64 + 255) / 256, 256, 0, stream>>>(img, IM);
    cwt_kernel<<<(208 * 64 + 255) / 256, 256, 0, stream>>>(conv_w, CWT);
    conv_mfma_kernel<<<50176 / 128, 256, 0, stream>>>(IM, CWT, conv_b, bn1_g, bn1_b, CO_T);
    hipMemsetAsync(accT, 0, (size_t)51200 * 4, stream);
    fc_kernel<<<98 * 4, 256, 0, stream>>>(CO_T, fc_w, accT);
    fc_epi_kernel<<<(BB * 224 + 255) / 256, 256, 0, stream>>>(accT, fc_b, bn2_g, bn2_b, hb16);

    // ---- logits ----
    logits_mfma_kernel<<<481 * 2, 256, 0, stream>>>(x2b, hb16, ent_bias, (float*)d_out);
}

// Round 6
// 771.235 us; speedup vs baseline: 6.8358x; 1.1266x over previous
//
#include <hip/hip_runtime.h>
#include <math.h>

#define N_ENT   100000
#define N_REL2  1000
#define E_TOT   500000
#define E_HALF  250000
#define DIM     200
#define BB      256
#define NFILT   200
#define FLATK   39200
#define EPS_BN  1e-5f

#define NROWS   200000          // 100k in-rows + 100k out-rows
#define SCHUNK  2048
#define SNBLK   ((NROWS + SCHUNK - 1) / SCHUNK)   // 98

typedef __attribute__((ext_vector_type(8))) short bf16x8;   // 8 bf16 (4 VGPRs)
typedef __attribute__((ext_vector_type(4))) float f32x4;

__device__ __forceinline__ unsigned short f2b(float f) {
    union { float f; unsigned u; } c; c.f = f;
    unsigned u = c.u;
    u += 0x7fffu + ((u >> 16) & 1u);          // round-to-nearest-even
    return (unsigned short)(u >> 16);
}
__device__ __forceinline__ float b2f(unsigned short h) {
    union { unsigned u; float f; } c; c.u = ((unsigned)h) << 16;
    return c.f;
}
__device__ __forceinline__ float fast_tanh(float x) {
    float ax = fabsf(x);
    float e = __expf(-2.0f * ax);             // in (0,1], never overflows
    float t = (1.0f - e) / (1.0f + e);
    return copysignf(t, x);
}

// ---------------------------------------------------------------------------
// fp32 -> bf16 convert
// ---------------------------------------------------------------------------
__global__ void convert_kernel(const float* __restrict__ s, unsigned short* __restrict__ d,
                               int n) {
    int i = (blockIdx.x * 256 + threadIdx.x) * 4;
    if (i + 3 < n) {
        float4 v = *(const float4*)(s + i);
        ushort4 o;
        o.x = f2b(v.x); o.y = f2b(v.y); o.z = f2b(v.z); o.w = f2b(v.w);
        *(ushort4*)(d + i) = o;
    } else {
        for (; i < n; ++i) d[i] = f2b(s[i]);
    }
}

// ---------------------------------------------------------------------------
// Build WstackT[224][672] bf16: WstackT[j][seg*224+k] = Wseg[k][j] (zero-pad)
// ---------------------------------------------------------------------------
__global__ void wstack_kernel(const float* __restrict__ wIn, const float* __restrict__ wOut,
                              const float* __restrict__ wLoop, unsigned short* __restrict__ WT) {
    int g = blockIdx.x * 256 + threadIdx.x;
    if (g >= 224 * 672) return;
    int j = g / 672, t = g - j * 672;
    int seg = t / 224, k = t - seg * 224;
    float v = 0.f;
    if (j < 200 && k < 200)
        v = (seg == 0 ? wIn : seg == 1 ? wOut : wLoop)[k * 200 + j];
    WT[g] = f2b(v);
}

// ---------------------------------------------------------------------------
// CSR build
// ---------------------------------------------------------------------------
__global__ void hist_kernel(const int* __restrict__ ei, int* __restrict__ cnt) {
    int e = blockIdx.x * 256 + threadIdx.x;
    if (e >= E_TOT) return;
    int row = ei[E_TOT + e] + (e < E_HALF ? 0 : N_ENT);
    atomicAdd(&cnt[row], 1);
}

__global__ void scan1_kernel(const int* __restrict__ cnt, int* __restrict__ row_start,
                             int* __restrict__ blockSum) {
    __shared__ int tsum[256];
    const int t = threadIdx.x;
    const int base = blockIdx.x * SCHUNK + t * 8;
    int v[8];
    int s = 0;
#pragma unroll
    for (int i = 0; i < 8; ++i) {
        int idx = base + i;
        int c = (idx < NROWS) ? cnt[idx] : 0;
        v[i] = s;
        s += c;
    }
    tsum[t] = s;
    __syncthreads();
    for (int off = 1; off < 256; off <<= 1) {
        int x = (t >= off) ? tsum[t - off] : 0;
        __syncthreads();
        if (t >= off) tsum[t] += x;
        __syncthreads();
    }
    int texc = (t == 0) ? 0 : tsum[t - 1];
    if (t == 0) blockSum[blockIdx.x] = tsum[255];
#pragma unroll
    for (int i = 0; i < 8; ++i) {
        int idx = base + i;
        if (idx < NROWS) row_start[idx] = texc + v[i];
    }
}

__global__ void scan2_kernel(int* __restrict__ blockSum) {
    int s = 0;
    for (int i = 0; i < SNBLK; ++i) { int c = blockSum[i]; blockSum[i] = s; s += c; }
}

__global__ void scan3_kernel(int* __restrict__ row_start, int* __restrict__ row_cur,
                             const int* __restrict__ blockSum) {
    int i = blockIdx.x * 256 + threadIdx.x;
    if (i >= NROWS) return;
    int v = row_start[i] + blockSum[i / SCHUNK];
    row_start[i] = v;
    row_cur[i] = v;
}

__global__ void fill_kernel(const int* __restrict__ ei, const int* __restrict__ et,
                            int* __restrict__ row_cur, int2* __restrict__ epair) {
    int e = blockIdx.x * 256 + threadIdx.x;
    if (e >= E_TOT) return;
    int row = ei[E_TOT + e] + (e < E_HALF ? 0 : N_ENT);
    int pos = atomicAdd(&row_cur[row], 1);
    epair[pos] = make_int2(ei[e], et[e]);
}

// ---------------------------------------------------------------------------
// gather (bf16): one wave per CSR row, lanes 0..49 own 4 bf16 each; fp32 accum;
// degree loop unrolled x2 with dual accumulators to break the latency chain.
// ---------------------------------------------------------------------------
__global__ void gather_kernel(const unsigned short* __restrict__ x,
                              const unsigned short* __restrict__ r,
                              const int2* __restrict__ epair,
                              const int* __restrict__ row_start, const int* __restrict__ cnt,
                              unsigned short* __restrict__ agg) {
    int wid = blockIdx.x * 4 + (threadIdx.x >> 6);
    if (wid >= NROWS) return;
    int lane = threadIdx.x & 63;
    if (lane >= 50) return;
    int start = row_start[wid];
    int deg = cnt[wid];
    float a0 = 0.f, a1 = 0.f, a2 = 0.f, a3 = 0.f;
    float c0 = 0.f, c1 = 0.f, c2 = 0.f, c3 = 0.f;
    int i = 0;
    for (; i + 2 <= deg; i += 2) {
        int2 e0 = epair[start + i];
        int2 e1 = epair[start + i + 1];
        ushort4 xv0 = *(const ushort4*)(x + (size_t)e0.x * DIM + lane * 4);
        ushort4 rv0 = *(const ushort4*)(r + (size_t)e0.y * DIM + lane * 4);
        ushort4 xv1 = *(const ushort4*)(x + (size_t)e1.x * DIM + lane * 4);
        ushort4 rv1 = *(const ushort4*)(r + (size_t)e1.y * DIM + lane * 4);
        a0 += b2f(xv0.x) - b2f(rv0.x);
        a1 += b2f(xv0.y) - b2f(rv0.y);
        a2 += b2f(xv0.z) - b2f(rv0.z);
        a3 += b2f(xv0.w) - b2f(rv0.w);
        c0 += b2f(xv1.x) - b2f(rv1.x);
        c1 += b2f(xv1.y) - b2f(rv1.y);
        c2 += b2f(xv1.z) - b2f(rv1.z);
        c3 += b2f(xv1.w) - b2f(rv1.w);
    }
    if (i < deg) {
        int2 e = epair[start + i];
        ushort4 xv = *(const ushort4*)(x + (size_t)e.x * DIM + lane * 4);
        ushort4 rv = *(const ushort4*)(r + (size_t)e.y * DIM + lane * 4);
        a0 += b2f(xv.x) - b2f(rv.x);
        a1 += b2f(xv.y) - b2f(rv.y);
        a2 += b2f(xv.z) - b2f(rv.z);
        a3 += b2f(xv.w) - b2f(rv.w);
    }
    float sc = 1.0f / fmaxf((float)deg, 1.0f);
    ushort4 o;
    o.x = f2b((a0 + c0) * sc);
    o.y = f2b((a1 + c1) * sc);
    o.z = f2b((a2 + c2) * sc);
    o.w = f2b((a3 + c3) * sc);
    *(ushort4*)(agg + (size_t)wid * DIM + lane * 4) = o;
}

// ---------------------------------------------------------------------------
// lv = loop_rel @ w_loop   (fp32, one 200-vector)
// ---------------------------------------------------------------------------
__global__ void lv_kernel(const float* __restrict__ lr, const float* __restrict__ wl,
                          float* __restrict__ lv) {
    int j = blockIdx.x * blockDim.x + threadIdx.x;
    if (j >= DIM) return;
    float acc = 0.f;
    for (int k = 0; k < DIM; ++k) acc += lr[k] * wl[k * DIM + j];
    lv[j] = acc;
}

// ---------------------------------------------------------------------------
// r_out = r_in @ w   fp32, tiny (rows=1000)
// ---------------------------------------------------------------------------
__global__ void rgemm_kernel(const float* __restrict__ r, const float* __restrict__ w,
                             float* __restrict__ out, int rows) {
    int g = blockIdx.x * 256 + threadIdx.x;
    if (g >= rows * DIM) return;
    int i = g / DIM, j = g - i * DIM;
    float acc = 0.f;
    for (int k = 0; k < DIM; ++k) acc += r[i * DIM + k] * w[k * DIM + j];
    out[g] = acc;
}

// ---------------------------------------------------------------------------
// MFMA layer v4 (occupancy-first): 256 thr = 4 waves (all M), block tile
// 128 rows x 112 cols (col-half by block), LDS = one K-half of one W-seg
// [112][136] = 30.5 KB -> 4 blocks/CU (16 waves). 6 stage phases per block
// (3 segs x {128k, 96k}). A: rotating register prefetch depth 2, statically
// indexed via full unroll. Bijective XCD swizzle pairs the two col-halves
// of a row-block on one XCD (shared A rows -> L2 hits).
// ---------------------------------------------------------------------------
#define LOAD_A2(g, buf) do {                                                    \
    const unsigned short* Ap_ = Aseg[(g) / 7];                                  \
    const unsigned short* base_ = Ap_ + (size_t)arow * 200 + ((g) % 7) * 32 + lq * 8; \
    buf[0] = *(const bf16x8*)(base_);                                           \
    buf[1] = *(const bf16x8*)(base_ + 16 * 200);                                \
} while (0)

__global__ __launch_bounds__(256, 4) void layer_mfma_kernel(
        const unsigned short* __restrict__ aggI, const unsigned short* __restrict__ aggO,
        const unsigned short* __restrict__ xin, const unsigned short* __restrict__ WT,
        const float* __restrict__ lv, const float* __restrict__ bias,
        unsigned short* __restrict__ out, int nwg) {
    __shared__ unsigned short Wl[112 * 136];          // 30,464 B
    // bijective XCD swizzle (m204): logical id L contiguous within an XCD
    const int bid = blockIdx.x;
    const int q = nwg >> 3, rr = nwg & 7;
    const int xcd = bid & 7, idx = bid >> 3;
    const int L = (xcd < rr ? xcd * (q + 1) : rr * (q + 1) + (xcd - rr) * q) + idx;
    const int rowblk  = L >> 1;
    const int colbase = (L & 1) * 112;

    const int tid  = threadIdx.x;
    const int wm   = tid >> 6;
    const int lane = tid & 63;
    const int lr   = lane & 15;
    const int lq   = lane >> 4;
    const int row0 = rowblk * 128;
    const int arow = row0 + wm * 32 + lr;

    const unsigned short* const Aseg[3] = { aggI, aggO, xin };

    f32x4 acc[2][7];
#pragma unroll
    for (int m = 0; m < 2; ++m)
#pragma unroll
        for (int n = 0; n < 7; ++n) acc[m][n] = (f32x4){0.f, 0.f, 0.f, 0.f};

    bf16x8 apf[3][2];                     // rotating A prefetch, depth 2
    LOAD_A2(0, apf[0]);
    LOAD_A2(1, apf[1]);

#pragma unroll
    for (int seg = 0; seg < 3; ++seg) {
#pragma unroll
        for (int ph = 0; ph < 2; ++ph) {
            if (seg + ph) __syncthreads();     // all waves done reading old Wl
            if (ph == 0) {
                // stage k 0..127: 112 cols x 16 int4 = 1792 units (7/thread)
#pragma unroll
                for (int it = 0; it < 7; ++it) {
                    int u = tid + it * 256;
                    int col = u >> 4, kq = u & 15;
                    *(int4*)(&Wl[col * 136 + kq * 8]) =
                        *(const int4*)(WT + (size_t)(colbase + col) * 672 + seg * 224 + kq * 8);
                }
            } else {
                // stage k 128..223: 112 cols x 12 int4 = 1344 units
                for (int u = tid; u < 1344; u += 256) {
                    int col = u / 12, kq = u - col * 12;
                    *(int4*)(&Wl[col * 136 + kq * 8]) =
                        *(const int4*)(WT + (size_t)(colbase + col) * 672 + seg * 224 + 128 + kq * 8);
                }
            }
            __syncthreads();
            const int NC = (ph == 0) ? 4 : 3;
#pragma unroll
            for (int cc = 0; cc < NC; ++cc) {
                const int g = seg * 7 + (ph ? 4 : 0) + cc;     // literal after unroll
                if (g + 2 < 21) LOAD_A2(g + 2, apf[(g + 2) % 3]);
#pragma unroll
                for (int n = 0; n < 7; ++n) {
                    bf16x8 b = *(const bf16x8*)(&Wl[(n * 16 + lr) * 136 + cc * 32 + lq * 8]);
                    acc[0][n] = __builtin_amdgcn_mfma_f32_16x16x32_bf16(apf[g % 3][0], b, acc[0][n], 0, 0, 0);
                    acc[1][n] = __builtin_amdgcn_mfma_f32_16x16x32_bf16(apf[g % 3][1], b, acc[1][n], 0, 0, 0);
                }
            }
        }
    }

#pragma unroll
    for (int m = 0; m < 2; ++m) {
        int rbase = row0 + wm * 32 + m * 16 + lq * 4;
#pragma unroll
        for (int n = 0; n < 7; ++n) {
            int col = colbase + n * 16 + lr;
            if (col < 200) {
                float lvc = lv[col], bc = bias[col];
#pragma unroll
                for (int r2 = 0; r2 < 4; ++r2) {
                    int row = rbase + r2;
                    if (row < N_ENT) {
                        float v = (acc[m][n][r2] - lvc) * (1.0f / 3.0f) + bc;
                        out[(size_t)row * 200 + col] = f2b(fast_tanh(v));
                    }
                }
            }
        }
    }
}

// ---------------------------------------------------------------------------
// build ConvE input images with BN0 (bf16 out)
// ---------------------------------------------------------------------------
__global__ void img_kernel(const unsigned short* __restrict__ x, const float* __restrict__ r,
                           const int* __restrict__ sub, const int* __restrict__ rel,
                           const float* __restrict__ bn0g, const float* __restrict__ bn0b,
                           unsigned short* __restrict__ img) {
    int g = blockIdx.x * 256 + threadIdx.x;
    if (g >= BB * 2 * DIM) return;
    int b = g / 400, l = g - b * 400;
    int d = l >> 1;
    float v = (l & 1) ? r[(size_t)rel[b] * DIM + d] : b2f(x[(size_t)sub[b] * DIM + d]);
    float s0 = bn0g[0] * rsqrtf(1.0f + EPS_BN);
    img[g] = f2b(v * s0 + bn0b[0]);
}

// ---------------------------------------------------------------------------
// im2col: IM[b*196+p][64], k = i*7+j (49 real, 64 padded with zeros)
// ---------------------------------------------------------------------------
__global__ void im2col_kernel(const unsigned short* __restrict__ img,
                              unsigned short* __restrict__ IM) {
    int g = blockIdx.x * 256 + threadIdx.x;
    if (g >= 50176 * 64) return;
    int row = g >> 6, k = g & 63;
    int b = row / 196, p = row - b * 196;
    int h = p / 14, w = p - h * 14;
    unsigned short v = 0;
    if (k < 49) {
        int i = k / 7, j = k - i * 7;
        v = img[b * 400 + (h + i) * 20 + (w + j)];
    }
    IM[g] = v;
}

// CWT[208][64] bf16: CWT[f][k] = conv_w[f][k], zero-padded
__global__ void cwt_kernel(const float* __restrict__ cw, unsigned short* __restrict__ CWT) {
    int g = blockIdx.x * 256 + threadIdx.x;
    if (g >= 208 * 64) return;
    int f = g >> 6, k = g & 63;
    CWT[g] = (f < 200 && k < 49) ? f2b(cw[f * 49 + k]) : 0;
}

// ---------------------------------------------------------------------------
// conv as MFMA: [50176 x 64] @ [64 x 200(pad 208)], zero-LDS/zero-barrier.
// Epilogue: +conv_b, BN1, relu, write CO_T[f*196+p][b] bf16 (fc-friendly).
// ---------------------------------------------------------------------------
__global__ __launch_bounds__(256) void conv_mfma_kernel(
        const unsigned short* __restrict__ IM, const unsigned short* __restrict__ CWT,
        const float* __restrict__ cb, const float* __restrict__ bn1g,
        const float* __restrict__ bn1b, unsigned short* __restrict__ CO_T) {
    const int tid  = threadIdx.x;
    const int row0 = blockIdx.x * 128;
    const int wave = tid >> 6;
    const int lane = tid & 63;
    const int lr   = lane & 15;
    const int lq   = lane >> 4;
    const int arow = row0 + wave * 32 + lr;

    f32x4 acc[2][13];
#pragma unroll
    for (int m = 0; m < 2; ++m)
#pragma unroll
        for (int n = 0; n < 13; ++n) acc[m][n] = (f32x4){0.f, 0.f, 0.f, 0.f};

#pragma unroll
    for (int c = 0; c < 2; ++c) {
        const int k = c * 32 + lq * 8;
        bf16x8 a0 = *(const bf16x8*)(IM + (size_t)arow * 64 + k);
        bf16x8 a1 = *(const bf16x8*)(IM + (size_t)(arow + 16) * 64 + k);
#pragma unroll
        for (int n = 0; n < 13; ++n) {
            bf16x8 b = *(const bf16x8*)(CWT + (size_t)(n * 16 + lr) * 64 + k);
            acc[0][n] = __builtin_amdgcn_mfma_f32_16x16x32_bf16(a0, b, acc[0][n], 0, 0, 0);
            acc[1][n] = __builtin_amdgcn_mfma_f32_16x16x32_bf16(a1, b, acc[1][n], 0, 0, 0);
        }
    }

#pragma unroll
    for (int m = 0; m < 2; ++m) {
        int grow_base = row0 + wave * 32 + m * 16 + lq * 4;
#pragma unroll
        for (int n = 0; n < 13; ++n) {
            int col = n * 16 + lr;          // filter
            if (col < 200) {
                float s1 = bn1g[col] * rsqrtf(1.0f + EPS_BN);
                float t1 = bn1b[col];
                float cbf = cb[col];
#pragma unroll
                for (int r = 0; r < 4; ++r) {
                    int grow = grow_base + r;          // b*196+p, always < 50176
                    int b = grow / 196, p = grow - b * 196;
                    float v = fmaxf((acc[m][n][r] + cbf) * s1 + t1, 0.f);
                    CO_T[(size_t)(col * 196 + p) * BB + b] = f2b(v);
                }
            }
        }
    }
}

// ---------------------------------------------------------------------------
// fc partial GEMM: acc_t[j][b] += sum_k CO_T[k][b] * fc_w[k][j]  (CO_T bf16)
// ---------------------------------------------------------------------------
__global__ void fc_kernel(const unsigned short* __restrict__ xt, const float* __restrict__ fw,
                          float* __restrict__ acc_t) {
    __shared__ float w[100][50];
    const int kc = blockIdx.x >> 2;
    const int j0 = (blockIdx.x & 3) * 50;
    const int b  = threadIdx.x;
    float acc[50];
#pragma unroll
    for (int c = 0; c < 50; ++c) acc[c] = 0.f;
    for (int ks = 0; ks < 4; ++ks) {
        int k0 = kc * 400 + ks * 100;
        __syncthreads();
        for (int idx = b; idx < 5000; idx += 256) {
            int kk = idx / 50, jj = idx - kk * 50;
            w[kk][jj] = fw[(size_t)(k0 + kk) * DIM + j0 + jj];
        }
        __syncthreads();
        for (int kk = 0; kk < 100; ++kk) {
            float xv = b2f(xt[(size_t)(k0 + kk) * BB + b]);
#pragma unroll
            for (int c = 0; c < 50; ++c) acc[c] += xv * w[kk][c];
        }
    }
    for (int c = 0; c < 50; ++c)
        atomicAdd(&acc_t[(size_t)(j0 + c) * BB + b], acc[c]);
}

// hb16[b][k=224] = relu((acc+fc_b)*bn2s+bn2b) bf16, zero-padded k>=200
__global__ void fc_epi_kernel(const float* __restrict__ acc_t, const float* __restrict__ fcb,
                              const float* __restrict__ g2, const float* __restrict__ b2v,
                              unsigned short* __restrict__ hb) {
    int g = blockIdx.x * 256 + threadIdx.x;
    if (g >= BB * 224) return;
    int b = g / 224, j = g - b * 224;
    unsigned short o = 0;
    if (j < 200) {
        float v = (acc_t[j * BB + b] + fcb[j]) * (g2[j] * rsqrtf(1.0f + EPS_BN)) + b2v[j];
        o = f2b(fmaxf(v, 0.f));
    }
    hb[g] = o;
}

// ---------------------------------------------------------------------------
// logits MFMA: D[b][ent] = sigmoid(h[b]·x[ent] + eb[ent]).
// ---------------------------------------------------------------------------
__global__ __launch_bounds__(256) void logits_mfma_kernel(
        const unsigned short* __restrict__ x, const unsigned short* __restrict__ hb,
        const float* __restrict__ eb, float* __restrict__ out) {
    const int tid  = threadIdx.x;
    const int nb   = blockIdx.x >> 1;
    const int mb   = blockIdx.x & 1;
    const int ent0 = nb * 208;
    const int wave = tid >> 6;
    const int lane = tid & 63;
    const int lr   = lane & 15;
    const int lq   = lane >> 4;
    const int brow = mb * 128 + wave * 32 + lr;

    f32x4 acc[2][13];
#pragma unroll
    for (int m = 0; m < 2; ++m)
#pragma unroll
        for (int n = 0; n < 13; ++n) acc[m][n] = (f32x4){0.f, 0.f, 0.f, 0.f};

#pragma unroll
    for (int c = 0; c < 7; ++c) {
        const int k = c * 32 + lq * 8;
        bf16x8 a0 = *(const bf16x8*)(hb + (size_t)brow * 224 + k);
        bf16x8 a1 = *(const bf16x8*)(hb + (size_t)(brow + 16) * 224 + k);
#pragma unroll
        for (int n = 0; n < 13; ++n) {
            bf16x8 b = *(const bf16x8*)(x + (size_t)(ent0 + n * 16 + lr) * 200 + k);
            acc[0][n] = __builtin_amdgcn_mfma_f32_16x16x32_bf16(a0, b, acc[0][n], 0, 0, 0);
            acc[1][n] = __builtin_amdgcn_mfma_f32_16x16x32_bf16(a1, b, acc[1][n], 0, 0, 0);
        }
    }

#pragma unroll
    for (int m = 0; m < 2; ++m) {
        int b_base = mb * 128 + wave * 32 + m * 16 + lq * 4;
#pragma unroll
        for (int n = 0; n < 13; ++n) {
            int ent = ent0 + n * 16 + lr;
            if (ent < N_ENT) {
                float bias = eb[ent];
#pragma unroll
                for (int r = 0; r < 4; ++r) {
                    float v = acc[m][n][r] + bias;
                    out[(size_t)(b_base + r) * N_ENT + ent] = 1.0f / (1.0f + __expf(-v));
                }
            }
        }
    }
}

// ---------------------------------------------------------------------------
extern "C" void kernel_launch(void* const* d_in, const int* in_sizes, int n_in,
                              void* d_out, int out_size, void* d_ws, size_t ws_size,
                              hipStream_t stream) {
    const int*   sub        = (const int*)  d_in[0];
    const int*   rel        = (const int*)  d_in[1];
    const int*   edge_index = (const int*)  d_in[2];
    const int*   edge_type  = (const int*)  d_in[3];
    const float* init_embed = (const float*)d_in[4];
    const float* init_rel   = (const float*)d_in[5];
    const float* loop_rel1  = (const float*)d_in[6];
    const float* loop_rel2  = (const float*)d_in[7];
    const float* w_in1      = (const float*)d_in[8];
    const float* w_out1     = (const float*)d_in[9];
    const float* w_loop1    = (const float*)d_in[10];
    const float* w_rel1     = (const float*)d_in[11];
    const float* b1         = (const float*)d_in[12];
    const float* w_in2      = (const float*)d_in[13];
    const float* w_out2     = (const float*)d_in[14];
    const float* w_loop2    = (const float*)d_in[15];
    const float* w_rel2     = (const float*)d_in[16];
    const float* b2         = (const float*)d_in[17];
    const float* conv_w     = (const float*)d_in[18];
    const float* conv_b     = (const float*)d_in[19];
    const float* bn0_g      = (const float*)d_in[20];
    const float* bn0_b      = (const float*)d_in[21];
    const float* bn1_g      = (const float*)d_in[22];
    const float* bn1_b      = (const float*)d_in[23];
    const float* bn2_g      = (const float*)d_in[24];
    const float* bn2_b      = (const float*)d_in[25];
    const float* fc_w       = (const float*)d_in[26];
    const float* fc_b       = (const float*)d_in[27];
    const float* ent_bias   = (const float*)d_in[28];

    // ---- bf16 region ----
    unsigned short* aggb = (unsigned short*)d_ws;     // 40,000,000
    unsigned short* x0b  = aggb + 40000000;           // 20,000,000 (init; reused as x2b)
    unsigned short* x1b  = x0b  + 20000000;           // 20,000,000
    unsigned short* r0b  = x1b  + 20000000;           //    200,000
    unsigned short* r1b  = r0b  + 200000;             //    200,000
    unsigned short* WT   = r1b  + 200000;             //    150,528 (224*672)
    unsigned short* img  = WT   + 150528;             //    102,400
    unsigned short* IM   = img  + 102400;             //  3,211,264 (50176*64)
    unsigned short* CWT  = IM   + 3211264;            //     13,312
    unsigned short* CO_T = CWT  + 13312;              // 10,035,200 (39200*256)
    unsigned short* hb16 = CO_T + 10035200;           //     57,344 (256*224)
    // ---- fp32 region ----
    float* fbase = (float*)(hb16 + 57344);
    float* r1f  = fbase;                              // 200,000
    float* r2f  = r1f  + 200000;                      // 200,000
    float* lv   = r2f  + 200000;                      // 256
    float* accT = lv   + 256;                         // 51,200

    // CSR ints alias CO_T (last CSR read = gather2, before conv writes CO_T)
    int2* epair    = (int2*)CO_T;                     // 500,000 int2 (8B-aligned)
    int* cnt       = (int*)(epair + E_TOT);           // 200,000
    int* row_start = cnt  + NROWS;                    // 200,000
    int* row_cur   = row_start + NROWS;               // 200,000
    int* blockSum  = row_cur + NROWS;                 // 98

    unsigned short* aggIb = aggb;
    unsigned short* aggOb = aggb + (size_t)N_ENT * DIM;
    unsigned short* x2b   = x0b;

    const int gather_blocks = (NROWS + 3) / 4;
    const int layer_nwg     = ((N_ENT + 127) / 128) * 2;   // 782 row-blocks x 2 col-halves
    const int wstack_blocks = (224 * 672 + 255) / 256;

    // ---- converts + CSR build ----
    convert_kernel<<<(N_ENT * DIM + 1023) / 1024, 256, 0, stream>>>(init_embed, x0b, N_ENT * DIM);
    convert_kernel<<<(N_REL2 * DIM + 1023) / 1024, 256, 0, stream>>>(init_rel, r0b, N_REL2 * DIM);
    hipMemsetAsync(cnt, 0, (size_t)NROWS * 4, stream);
    hist_kernel<<<(E_TOT + 255) / 256, 256, 0, stream>>>(edge_index, cnt);
    scan1_kernel<<<SNBLK, 256, 0, stream>>>(cnt, row_start, blockSum);
    scan2_kernel<<<1, 1, 0, stream>>>(blockSum);
    scan3_kernel<<<(NROWS + 255) / 256, 256, 0, stream>>>(row_start, row_cur, blockSum);
    fill_kernel<<<(E_TOT + 255) / 256, 256, 0, stream>>>(edge_index, edge_type, row_cur, epair);

    // ---- layer 1 ----
    wstack_kernel<<<wstack_blocks, 256, 0, stream>>>(w_in1, w_out1, w_loop1, WT);
    gather_kernel<<<gather_blocks, 256, 0, stream>>>(x0b, r0b, epair, row_start, cnt, aggb);
    lv_kernel<<<1, 256, 0, stream>>>(loop_rel1, w_loop1, lv);
    layer_mfma_kernel<<<layer_nwg, 256, 0, stream>>>(aggIb, aggOb, x0b, WT, lv, b1, x1b, layer_nwg);
    rgemm_kernel<<<(N_REL2 * DIM + 255) / 256, 256, 0, stream>>>(init_rel, w_rel1, r1f, N_REL2);
    convert_kernel<<<(N_REL2 * DIM + 1023) / 1024, 256, 0, stream>>>(r1f, r1b, N_REL2 * DIM);

    // ---- layer 2 ----
    wstack_kernel<<<wstack_blocks, 256, 0, stream>>>(w_in2, w_out2, w_loop2, WT);
    gather_kernel<<<gather_blocks, 256, 0, stream>>>(x1b, r1b, epair, row_start, cnt, aggb);
    lv_kernel<<<1, 256, 0, stream>>>(loop_rel2, w_loop2, lv);
    layer_mfma_kernel<<<layer_nwg, 256, 0, stream>>>(aggIb, aggOb, x1b, WT, lv, b2, x2b, layer_nwg);
    rgemm_kernel<<<(N_REL2 * DIM + 255) / 256, 256, 0, stream>>>(r1f, w_rel2, r2f, N_REL2);

    // ---- ConvE ----
    img_kernel<<<(BB * 400 + 255) / 256, 256, 0, stream>>>(x2b, r2f, sub, rel,
                                                           bn0_g, bn0_b, img);
    im2col_kernel<<<(50176 * 64 + 255) / 256, 256, 0, stream>>>(img, IM);
    cwt_kernel<<<(208 * 64 + 255) / 256, 256, 0, stream>>>(conv_w, CWT);
    conv_mfma_kernel<<<50176 / 128, 256, 0, stream>>>(IM, CWT, conv_b, bn1_g, bn1_b, CO_T);
    hipMemsetAsync(accT, 0, (size_t)51200 * 4, stream);
    fc_kernel<<<98 * 4, 256, 0, stream>>>(CO_T, fc_w, accT);
    fc_epi_kernel<<<(BB * 224 + 255) / 256, 256, 0, stream>>>(accT, fc_b, bn2_g, bn2_b, hb16);

    // ---- logits ----
    logits_mfma_kernel<<<481 * 2, 256, 0, stream>>>(x2b, hb16, ent_bias, (float*)d_out);
}

// Round 7
// 643.124 us; speedup vs baseline: 8.1975x; 1.1992x over previous
//
#include <hip/hip_runtime.h>
#include <math.h>

#define N_ENT   100000
#define N_REL2  1000
#define E_TOT   500000
#define E_HALF  250000
#define DIM     200
#define BB      256
#define NFILT   200
#define FLATK   39200
#define EPS_BN  1e-5f

#define NROWS   200000          // 100k in-rows + 100k out-rows
#define SCHUNK  2048
#define SNBLK   ((NROWS + SCHUNK - 1) / SCHUNK)   // 98

#define FC_KC   175             // fc split-K chunks (39200 = 175 * 224)
#define FC_KLEN 224             // 7 mfma k-steps

typedef __attribute__((ext_vector_type(8))) short bf16x8;   // 8 bf16 (4 VGPRs)
typedef __attribute__((ext_vector_type(4))) float f32x4;

__device__ __forceinline__ unsigned short f2b(float f) {
    union { float f; unsigned u; } c; c.f = f;
    unsigned u = c.u;
    u += 0x7fffu + ((u >> 16) & 1u);          // round-to-nearest-even
    return (unsigned short)(u >> 16);
}
__device__ __forceinline__ float b2f(unsigned short h) {
    union { unsigned u; float f; } c; c.u = ((unsigned)h) << 16;
    return c.f;
}
__device__ __forceinline__ float fast_tanh(float x) {
    float ax = fabsf(x);
    float e = __expf(-2.0f * ax);             // in (0,1], never overflows
    float t = (1.0f - e) / (1.0f + e);
    return copysignf(t, x);
}

// ---------------------------------------------------------------------------
// fp32 -> bf16 convert
// ---------------------------------------------------------------------------
__global__ void convert_kernel(const float* __restrict__ s, unsigned short* __restrict__ d,
                               int n) {
    int i = (blockIdx.x * 256 + threadIdx.x) * 4;
    if (i + 3 < n) {
        float4 v = *(const float4*)(s + i);
        ushort4 o;
        o.x = f2b(v.x); o.y = f2b(v.y); o.z = f2b(v.z); o.w = f2b(v.w);
        *(ushort4*)(d + i) = o;
    } else {
        for (; i < n; ++i) d[i] = f2b(s[i]);
    }
}

// ---------------------------------------------------------------------------
// Build WstackT[224][672] bf16: WstackT[j][seg*224+k] = Wseg[k][j] (zero-pad)
// ---------------------------------------------------------------------------
__global__ void wstack_kernel(const float* __restrict__ wIn, const float* __restrict__ wOut,
                              const float* __restrict__ wLoop, unsigned short* __restrict__ WT) {
    int g = blockIdx.x * 256 + threadIdx.x;
    if (g >= 224 * 672) return;
    int j = g / 672, t = g - j * 672;
    int seg = t / 224, k = t - seg * 224;
    float v = 0.f;
    if (j < 200 && k < 200)
        v = (seg == 0 ? wIn : seg == 1 ? wOut : wLoop)[k * 200 + j];
    WT[g] = f2b(v);
}

// ---------------------------------------------------------------------------
// fc weight transpose: FWT[j][k] = fc_w[k][j], bf16, j padded to 208.
// LDS 32x32 tile keeps both sides coalesced. 1225 k-tiles x 7 j-tiles.
// ---------------------------------------------------------------------------
__global__ void fwt_kernel(const float* __restrict__ fw, unsigned short* __restrict__ FWT) {
    __shared__ float t[32][33];
    const int bid = blockIdx.x;
    const int kt = bid % 1225, jt = bid / 1225;
    const int tid = threadIdx.x;
#pragma unroll
    for (int it = 0; it < 4; ++it) {
        int idx = tid + it * 256;
        int kk = idx >> 5, jj = idx & 31;
        int j = jt * 32 + jj;
        t[kk][jj] = (j < 200) ? fw[(size_t)(kt * 32 + kk) * 200 + j] : 0.f;
    }
    __syncthreads();
#pragma unroll
    for (int it = 0; it < 4; ++it) {
        int idx = tid + it * 256;
        int jj = idx >> 5, kk = idx & 31;
        int j = jt * 32 + jj;
        if (j < 208)
            FWT[(size_t)j * FLATK + kt * 32 + kk] = f2b(t[kk][jj]);
    }
}

// ---------------------------------------------------------------------------
// CSR build
// ---------------------------------------------------------------------------
__global__ void hist_kernel(const int* __restrict__ ei, int* __restrict__ cnt) {
    int e = blockIdx.x * 256 + threadIdx.x;
    if (e >= E_TOT) return;
    int row = ei[E_TOT + e] + (e < E_HALF ? 0 : N_ENT);
    atomicAdd(&cnt[row], 1);
}

__global__ void scan1_kernel(const int* __restrict__ cnt, int* __restrict__ row_start,
                             int* __restrict__ blockSum) {
    __shared__ int tsum[256];
    const int t = threadIdx.x;
    const int base = blockIdx.x * SCHUNK + t * 8;
    int v[8];
    int s = 0;
#pragma unroll
    for (int i = 0; i < 8; ++i) {
        int idx = base + i;
        int c = (idx < NROWS) ? cnt[idx] : 0;
        v[i] = s;
        s += c;
    }
    tsum[t] = s;
    __syncthreads();
    for (int off = 1; off < 256; off <<= 1) {
        int x = (t >= off) ? tsum[t - off] : 0;
        __syncthreads();
        if (t >= off) tsum[t] += x;
        __syncthreads();
    }
    int texc = (t == 0) ? 0 : tsum[t - 1];
    if (t == 0) blockSum[blockIdx.x] = tsum[255];
#pragma unroll
    for (int i = 0; i < 8; ++i) {
        int idx = base + i;
        if (idx < NROWS) row_start[idx] = texc + v[i];
    }
}

__global__ void scan2_kernel(int* __restrict__ blockSum) {
    int s = 0;
    for (int i = 0; i < SNBLK; ++i) { int c = blockSum[i]; blockSum[i] = s; s += c; }
}

__global__ void scan3_kernel(int* __restrict__ row_start, int* __restrict__ row_cur,
                             const int* __restrict__ blockSum) {
    int i = blockIdx.x * 256 + threadIdx.x;
    if (i >= NROWS) return;
    int v = row_start[i] + blockSum[i / SCHUNK];
    row_start[i] = v;
    row_cur[i] = v;
}

__global__ void fill_kernel(const int* __restrict__ ei, const int* __restrict__ et,
                            int* __restrict__ row_cur, int2* __restrict__ epair) {
    int e = blockIdx.x * 256 + threadIdx.x;
    if (e >= E_TOT) return;
    int row = ei[E_TOT + e] + (e < E_HALF ? 0 : N_ENT);
    int pos = atomicAdd(&row_cur[row], 1);
    epair[pos] = make_int2(ei[e], et[e]);
}

// ---------------------------------------------------------------------------
// gather (bf16): one wave per CSR row, lanes 0..49 own 4 bf16 each; fp32 accum;
// degree loop unrolled x2 with dual accumulators to break the latency chain.
// ---------------------------------------------------------------------------
__global__ void gather_kernel(const unsigned short* __restrict__ x,
                              const unsigned short* __restrict__ r,
                              const int2* __restrict__ epair,
                              const int* __restrict__ row_start, const int* __restrict__ cnt,
                              unsigned short* __restrict__ agg) {
    int wid = blockIdx.x * 4 + (threadIdx.x >> 6);
    if (wid >= NROWS) return;
    int lane = threadIdx.x & 63;
    if (lane >= 50) return;
    int start = row_start[wid];
    int deg = cnt[wid];
    float a0 = 0.f, a1 = 0.f, a2 = 0.f, a3 = 0.f;
    float c0 = 0.f, c1 = 0.f, c2 = 0.f, c3 = 0.f;
    int i = 0;
    for (; i + 2 <= deg; i += 2) {
        int2 e0 = epair[start + i];
        int2 e1 = epair[start + i + 1];
        ushort4 xv0 = *(const ushort4*)(x + (size_t)e0.x * DIM + lane * 4);
        ushort4 rv0 = *(const ushort4*)(r + (size_t)e0.y * DIM + lane * 4);
        ushort4 xv1 = *(const ushort4*)(x + (size_t)e1.x * DIM + lane * 4);
        ushort4 rv1 = *(const ushort4*)(r + (size_t)e1.y * DIM + lane * 4);
        a0 += b2f(xv0.x) - b2f(rv0.x);
        a1 += b2f(xv0.y) - b2f(rv0.y);
        a2 += b2f(xv0.z) - b2f(rv0.z);
        a3 += b2f(xv0.w) - b2f(rv0.w);
        c0 += b2f(xv1.x) - b2f(rv1.x);
        c1 += b2f(xv1.y) - b2f(rv1.y);
        c2 += b2f(xv1.z) - b2f(rv1.z);
        c3 += b2f(xv1.w) - b2f(rv1.w);
    }
    if (i < deg) {
        int2 e = epair[start + i];
        ushort4 xv = *(const ushort4*)(x + (size_t)e.x * DIM + lane * 4);
        ushort4 rv = *(const ushort4*)(r + (size_t)e.y * DIM + lane * 4);
        a0 += b2f(xv.x) - b2f(rv.x);
        a1 += b2f(xv.y) - b2f(rv.y);
        a2 += b2f(xv.z) - b2f(rv.z);
        a3 += b2f(xv.w) - b2f(rv.w);
    }
    float sc = 1.0f / fmaxf((float)deg, 1.0f);
    ushort4 o;
    o.x = f2b((a0 + c0) * sc);
    o.y = f2b((a1 + c1) * sc);
    o.z = f2b((a2 + c2) * sc);
    o.w = f2b((a3 + c3) * sc);
    *(ushort4*)(agg + (size_t)wid * DIM + lane * 4) = o;
}

// ---------------------------------------------------------------------------
// lv = loop_rel @ w_loop   (fp32, one 200-vector)
// ---------------------------------------------------------------------------
__global__ void lv_kernel(const float* __restrict__ lr, const float* __restrict__ wl,
                          float* __restrict__ lv) {
    int j = blockIdx.x * blockDim.x + threadIdx.x;
    if (j >= DIM) return;
    float acc = 0.f;
    for (int k = 0; k < DIM; ++k) acc += lr[k] * wl[k * DIM + j];
    lv[j] = acc;
}

// ---------------------------------------------------------------------------
// r_out = r_in @ w   fp32, tiny (rows=1000)
// ---------------------------------------------------------------------------
__global__ void rgemm_kernel(const float* __restrict__ r, const float* __restrict__ w,
                             float* __restrict__ out, int rows) {
    int g = blockIdx.x * 256 + threadIdx.x;
    if (g >= rows * DIM) return;
    int i = g / DIM, j = g - i * DIM;
    float acc = 0.f;
    for (int k = 0; k < DIM; ++k) acc += r[i * DIM + k] * w[k * DIM + j];
    out[g] = acc;
}

// ---------------------------------------------------------------------------
// MFMA layer v4 (occupancy-first): 256 thr = 4 waves (all M), block tile
// 128 rows x 112 cols, LDS [112][136] = 30.5 KB -> 4 blocks/CU.
// ---------------------------------------------------------------------------
#define LOAD_A2(g, buf) do {                                                    \
    const unsigned short* Ap_ = Aseg[(g) / 7];                                  \
    const unsigned short* base_ = Ap_ + (size_t)arow * 200 + ((g) % 7) * 32 + lq * 8; \
    buf[0] = *(const bf16x8*)(base_);                                           \
    buf[1] = *(const bf16x8*)(base_ + 16 * 200);                                \
} while (0)

__global__ __launch_bounds__(256, 4) void layer_mfma_kernel(
        const unsigned short* __restrict__ aggI, const unsigned short* __restrict__ aggO,
        const unsigned short* __restrict__ xin, const unsigned short* __restrict__ WT,
        const float* __restrict__ lv, const float* __restrict__ bias,
        unsigned short* __restrict__ out, int nwg) {
    __shared__ unsigned short Wl[112 * 136];          // 30,464 B
    const int bid = blockIdx.x;
    const int q = nwg >> 3, rr = nwg & 7;
    const int xcd = bid & 7, idx = bid >> 3;
    const int L = (xcd < rr ? xcd * (q + 1) : rr * (q + 1) + (xcd - rr) * q) + idx;
    const int rowblk  = L >> 1;
    const int colbase = (L & 1) * 112;

    const int tid  = threadIdx.x;
    const int wm   = tid >> 6;
    const int lane = tid & 63;
    const int lr   = lane & 15;
    const int lq   = lane >> 4;
    const int row0 = rowblk * 128;
    const int arow = row0 + wm * 32 + lr;

    const unsigned short* const Aseg[3] = { aggI, aggO, xin };

    f32x4 acc[2][7];
#pragma unroll
    for (int m = 0; m < 2; ++m)
#pragma unroll
        for (int n = 0; n < 7; ++n) acc[m][n] = (f32x4){0.f, 0.f, 0.f, 0.f};

    bf16x8 apf[3][2];                     // rotating A prefetch, depth 2
    LOAD_A2(0, apf[0]);
    LOAD_A2(1, apf[1]);

#pragma unroll
    for (int seg = 0; seg < 3; ++seg) {
#pragma unroll
        for (int ph = 0; ph < 2; ++ph) {
            if (seg + ph) __syncthreads();
            if (ph == 0) {
#pragma unroll
                for (int it = 0; it < 7; ++it) {
                    int u = tid + it * 256;
                    int col = u >> 4, kq = u & 15;
                    *(int4*)(&Wl[col * 136 + kq * 8]) =
                        *(const int4*)(WT + (size_t)(colbase + col) * 672 + seg * 224 + kq * 8);
                }
            } else {
                for (int u = tid; u < 1344; u += 256) {
                    int col = u / 12, kq = u - col * 12;
                    *(int4*)(&Wl[col * 136 + kq * 8]) =
                        *(const int4*)(WT + (size_t)(colbase + col) * 672 + seg * 224 + 128 + kq * 8);
                }
            }
            __syncthreads();
            const int NC = (ph == 0) ? 4 : 3;
#pragma unroll
            for (int cc = 0; cc < NC; ++cc) {
                const int g = seg * 7 + (ph ? 4 : 0) + cc;
                if (g + 2 < 21) LOAD_A2(g + 2, apf[(g + 2) % 3]);
#pragma unroll
                for (int n = 0; n < 7; ++n) {
                    bf16x8 b = *(const bf16x8*)(&Wl[(n * 16 + lr) * 136 + cc * 32 + lq * 8]);
                    acc[0][n] = __builtin_amdgcn_mfma_f32_16x16x32_bf16(apf[g % 3][0], b, acc[0][n], 0, 0, 0);
                    acc[1][n] = __builtin_amdgcn_mfma_f32_16x16x32_bf16(apf[g % 3][1], b, acc[1][n], 0, 0, 0);
                }
            }
        }
    }

#pragma unroll
    for (int m = 0; m < 2; ++m) {
        int rbase = row0 + wm * 32 + m * 16 + lq * 4;
#pragma unroll
        for (int n = 0; n < 7; ++n) {
            int col = colbase + n * 16 + lr;
            if (col < 200) {
                float lvc = lv[col], bc = bias[col];
#pragma unroll
                for (int r2 = 0; r2 < 4; ++r2) {
                    int row = rbase + r2;
                    if (row < N_ENT) {
                        float v = (acc[m][n][r2] - lvc) * (1.0f / 3.0f) + bc;
                        out[(size_t)row * 200 + col] = f2b(fast_tanh(v));
                    }
                }
            }
        }
    }
}

// ---------------------------------------------------------------------------
// build ConvE input images with BN0 (bf16 out)
// ---------------------------------------------------------------------------
__global__ void img_kernel(const unsigned short* __restrict__ x, const float* __restrict__ r,
                           const int* __restrict__ sub, const int* __restrict__ rel,
                           const float* __restrict__ bn0g, const float* __restrict__ bn0b,
                           unsigned short* __restrict__ img) {
    int g = blockIdx.x * 256 + threadIdx.x;
    if (g >= BB * 2 * DIM) return;
    int b = g / 400, l = g - b * 400;
    int d = l >> 1;
    float v = (l & 1) ? r[(size_t)rel[b] * DIM + d] : b2f(x[(size_t)sub[b] * DIM + d]);
    float s0 = bn0g[0] * rsqrtf(1.0f + EPS_BN);
    img[g] = f2b(v * s0 + bn0b[0]);
}

// ---------------------------------------------------------------------------
// im2col: IM[b*196+p][64], k = i*7+j (49 real, 64 padded with zeros)
// ---------------------------------------------------------------------------
__global__ void im2col_kernel(const unsigned short* __restrict__ img,
                              unsigned short* __restrict__ IM) {
    int g = blockIdx.x * 256 + threadIdx.x;
    if (g >= 50176 * 64) return;
    int row = g >> 6, k = g & 63;
    int b = row / 196, p = row - b * 196;
    int h = p / 14, w = p - h * 14;
    unsigned short v = 0;
    if (k < 49) {
        int i = k / 7, j = k - i * 7;
        v = img[b * 400 + (h + i) * 20 + (w + j)];
    }
    IM[g] = v;
}

// CWT[208][64] bf16: CWT[f][k] = conv_w[f][k], zero-padded
__global__ void cwt_kernel(const float* __restrict__ cw, unsigned short* __restrict__ CWT) {
    int g = blockIdx.x * 256 + threadIdx.x;
    if (g >= 208 * 64) return;
    int f = g >> 6, k = g & 63;
    CWT[g] = (f < 200 && k < 49) ? f2b(cw[f * 49 + k]) : 0;
}

// ---------------------------------------------------------------------------
// conv as MFMA: [50176 x 64] @ [64 x 200(pad 208)], zero-LDS/zero-barrier.
// Epilogue: +conv_b, BN1, relu, write CO_B[b][f*196+p] bf16 (fc A-layout).
// ---------------------------------------------------------------------------
__global__ __launch_bounds__(256) void conv_mfma_kernel(
        const unsigned short* __restrict__ IM, const unsigned short* __restrict__ CWT,
        const float* __restrict__ cb, const float* __restrict__ bn1g,
        const float* __restrict__ bn1b, unsigned short* __restrict__ CO_B) {
    const int tid  = threadIdx.x;
    const int row0 = blockIdx.x * 128;
    const int wave = tid >> 6;
    const int lane = tid & 63;
    const int lr   = lane & 15;
    const int lq   = lane >> 4;
    const int arow = row0 + wave * 32 + lr;

    f32x4 acc[2][13];
#pragma unroll
    for (int m = 0; m < 2; ++m)
#pragma unroll
        for (int n = 0; n < 13; ++n) acc[m][n] = (f32x4){0.f, 0.f, 0.f, 0.f};

#pragma unroll
    for (int c = 0; c < 2; ++c) {
        const int k = c * 32 + lq * 8;
        bf16x8 a0 = *(const bf16x8*)(IM + (size_t)arow * 64 + k);
        bf16x8 a1 = *(const bf16x8*)(IM + (size_t)(arow + 16) * 64 + k);
#pragma unroll
        for (int n = 0; n < 13; ++n) {
            bf16x8 b = *(const bf16x8*)(CWT + (size_t)(n * 16 + lr) * 64 + k);
            acc[0][n] = __builtin_amdgcn_mfma_f32_16x16x32_bf16(a0, b, acc[0][n], 0, 0, 0);
            acc[1][n] = __builtin_amdgcn_mfma_f32_16x16x32_bf16(a1, b, acc[1][n], 0, 0, 0);
        }
    }

#pragma unroll
    for (int m = 0; m < 2; ++m) {
        int grow_base = row0 + wave * 32 + m * 16 + lq * 4;
#pragma unroll
        for (int n = 0; n < 13; ++n) {
            int col = n * 16 + lr;          // filter
            if (col < 200) {
                float s1 = bn1g[col] * rsqrtf(1.0f + EPS_BN);
                float t1 = bn1b[col];
                float cbf = cb[col];
#pragma unroll
                for (int r = 0; r < 4; ++r) {
                    int grow = grow_base + r;          // b*196+p, always < 50176
                    int b = grow / 196, p = grow - b * 196;
                    float v = fmaxf((acc[m][n][r] + cbf) * s1 + t1, 0.f);
                    CO_B[(size_t)b * FLATK + col * 196 + p] = f2b(v);
                }
            }
        }
    }
}

// ---------------------------------------------------------------------------
// fc as MFMA split-K: [256 x 39200] @ [39200 x 208], 175 k-chunks x 4 m-blocks.
// Each block: 4 waves, wave = 16 batch rows x 208 cols, K-chunk = 224.
// Deterministic fp32 partials (one slab per k-chunk), reduced afterwards.
// ---------------------------------------------------------------------------
__global__ __launch_bounds__(256) void fc_mfma_kernel(
        const unsigned short* __restrict__ CO_B, const unsigned short* __restrict__ FWT,
        float* __restrict__ partials) {
    const int tid  = threadIdx.x;
    const int kc   = blockIdx.x >> 2;
    const int mb   = blockIdx.x & 3;
    const int wave = tid >> 6;
    const int lane = tid & 63;
    const int lr   = lane & 15;
    const int lq   = lane >> 4;
    const int m0   = mb * 64 + wave * 16;

    f32x4 acc[13];
#pragma unroll
    for (int n = 0; n < 13; ++n) acc[n] = (f32x4){0.f, 0.f, 0.f, 0.f};

#pragma unroll
    for (int s = 0; s < 7; ++s) {
        const int k = kc * FC_KLEN + s * 32 + lq * 8;
        bf16x8 a = *(const bf16x8*)(CO_B + (size_t)(m0 + lr) * FLATK + k);
#pragma unroll
        for (int n = 0; n < 13; ++n) {
            bf16x8 b = *(const bf16x8*)(FWT + (size_t)(n * 16 + lr) * FLATK + k);
            acc[n] = __builtin_amdgcn_mfma_f32_16x16x32_bf16(a, b, acc[n], 0, 0, 0);
        }
    }

    float* slab = partials + (size_t)kc * (BB * 208);
#pragma unroll
    for (int n = 0; n < 13; ++n) {
        int col = n * 16 + lr;
#pragma unroll
        for (int r = 0; r < 4; ++r) {
            int row = m0 + lq * 4 + r;
            slab[(size_t)row * 208 + col] = acc[n][r];
        }
    }
}

// hb16[b][j=224] = relu((sum_kc partial + fc_b)*bn2s+bn2b) bf16, pad j>=200
__global__ void fc_reduce_kernel(const float* __restrict__ partials,
                                 const float* __restrict__ fcb,
                                 const float* __restrict__ g2, const float* __restrict__ b2v,
                                 unsigned short* __restrict__ hb) {
    int g = blockIdx.x * 256 + threadIdx.x;
    if (g >= BB * 224) return;
    int b = g / 224, j = g - b * 224;
    unsigned short o = 0;
    if (j < 200) {
        float s = 0.f;
        const float* p = partials + (size_t)b * 208 + j;
#pragma unroll 5
        for (int c = 0; c < FC_KC; ++c)
            s += p[(size_t)c * (BB * 208)];
        float v = (s + fcb[j]) * (g2[j] * rsqrtf(1.0f + EPS_BN)) + b2v[j];
        o = f2b(fmaxf(v, 0.f));
    }
    hb[g] = o;
}

// ---------------------------------------------------------------------------
// logits MFMA: D[b][ent] = sigmoid(h[b]·x[ent] + eb[ent]).
// ---------------------------------------------------------------------------
__global__ __launch_bounds__(256) void logits_mfma_kernel(
        const unsigned short* __restrict__ x, const unsigned short* __restrict__ hb,
        const float* __restrict__ eb, float* __restrict__ out) {
    const int tid  = threadIdx.x;
    const int nb   = blockIdx.x >> 1;
    const int mb   = blockIdx.x & 1;
    const int ent0 = nb * 208;
    const int wave = tid >> 6;
    const int lane = tid & 63;
    const int lr   = lane & 15;
    const int lq   = lane >> 4;
    const int brow = mb * 128 + wave * 32 + lr;

    f32x4 acc[2][13];
#pragma unroll
    for (int m = 0; m < 2; ++m)
#pragma unroll
        for (int n = 0; n < 13; ++n) acc[m][n] = (f32x4){0.f, 0.f, 0.f, 0.f};

#pragma unroll
    for (int c = 0; c < 7; ++c) {
        const int k = c * 32 + lq * 8;
        bf16x8 a0 = *(const bf16x8*)(hb + (size_t)brow * 224 + k);
        bf16x8 a1 = *(const bf16x8*)(hb + (size_t)(brow + 16) * 224 + k);
#pragma unroll
        for (int n = 0; n < 13; ++n) {
            bf16x8 b = *(const bf16x8*)(x + (size_t)(ent0 + n * 16 + lr) * 200 + k);
            acc[0][n] = __builtin_amdgcn_mfma_f32_16x16x32_bf16(a0, b, acc[0][n], 0, 0, 0);
            acc[1][n] = __builtin_amdgcn_mfma_f32_16x16x32_bf16(a1, b, acc[1][n], 0, 0, 0);
        }
    }

#pragma unroll
    for (int m = 0; m < 2; ++m) {
        int b_base = mb * 128 + wave * 32 + m * 16 + lq * 4;
#pragma unroll
        for (int n = 0; n < 13; ++n) {
            int ent = ent0 + n * 16 + lr;
            if (ent < N_ENT) {
                float bias = eb[ent];
#pragma unroll
                for (int r = 0; r < 4; ++r) {
                    float v = acc[m][n][r] + bias;
                    out[(size_t)(b_base + r) * N_ENT + ent] = 1.0f / (1.0f + __expf(-v));
                }
            }
        }
    }
}

// ---------------------------------------------------------------------------
extern "C" void kernel_launch(void* const* d_in, const int* in_sizes, int n_in,
                              void* d_out, int out_size, void* d_ws, size_t ws_size,
                              hipStream_t stream) {
    const int*   sub        = (const int*)  d_in[0];
    const int*   rel        = (const int*)  d_in[1];
    const int*   edge_index = (const int*)  d_in[2];
    const int*   edge_type  = (const int*)  d_in[3];
    const float* init_embed = (const float*)d_in[4];
    const float* init_rel   = (const float*)d_in[5];
    const float* loop_rel1  = (const float*)d_in[6];
    const float* loop_rel2  = (const float*)d_in[7];
    const float* w_in1      = (const float*)d_in[8];
    const float* w_out1     = (const float*)d_in[9];
    const float* w_loop1    = (const float*)d_in[10];
    const float* w_rel1     = (const float*)d_in[11];
    const float* b1         = (const float*)d_in[12];
    const float* w_in2      = (const float*)d_in[13];
    const float* w_out2     = (const float*)d_in[14];
    const float* w_loop2    = (const float*)d_in[15];
    const float* w_rel2     = (const float*)d_in[16];
    const float* b2         = (const float*)d_in[17];
    const float* conv_w     = (const float*)d_in[18];
    const float* conv_b     = (const float*)d_in[19];
    const float* bn0_g      = (const float*)d_in[20];
    const float* bn0_b      = (const float*)d_in[21];
    const float* bn1_g      = (const float*)d_in[22];
    const float* bn1_b      = (const float*)d_in[23];
    const float* bn2_g      = (const float*)d_in[24];
    const float* bn2_b      = (const float*)d_in[25];
    const float* fc_w       = (const float*)d_in[26];
    const float* fc_b       = (const float*)d_in[27];
    const float* ent_bias   = (const float*)d_in[28];

    // ---- bf16 region ----
    unsigned short* aggb = (unsigned short*)d_ws;     // 40,000,000
    unsigned short* x0b  = aggb + 40000000;           // 20,000,000 (init; reused as x2b)
    unsigned short* x1b  = x0b  + 20000000;           // 20,000,000
    unsigned short* r0b  = x1b  + 20000000;           //    200,000
    unsigned short* r1b  = r0b  + 200000;             //    200,000
    unsigned short* WT   = r1b  + 200000;             //    150,528 (224*672)
    unsigned short* img  = WT   + 150528;             //    102,400
    unsigned short* IM   = img  + 102400;             //  3,211,264 (50176*64)
    unsigned short* CWT  = IM   + 3211264;            //     13,312
    unsigned short* CO_B = CWT  + 13312;              // 10,035,200 (256*39200)
    unsigned short* hb16 = CO_B + 10035200;           //     57,344 (256*224)
    unsigned short* FWT  = hb16 + 57344;              //  8,153,600 (208*39200)
    // ---- fp32 region ----
    float* fbase = (float*)(FWT + 8153600);
    float* r1f      = fbase;                          // 200,000
    float* r2f      = r1f  + 200000;                  // 200,000
    float* lv       = r2f  + 200000;                  // 256
    float* partials = lv   + 256;                     // 9,318,400 (175*256*208)

    // CSR ints alias CO_B (last CSR read = gather2, before conv writes CO_B)
    int2* epair    = (int2*)CO_B;                     // 500,000 int2
    int* cnt       = (int*)(epair + E_TOT);           // 200,000
    int* row_start = cnt  + NROWS;                    // 200,000
    int* row_cur   = row_start + NROWS;               // 200,000
    int* blockSum  = row_cur + NROWS;                 // 98

    unsigned short* aggIb = aggb;
    unsigned short* aggOb = aggb + (size_t)N_ENT * DIM;
    unsigned short* x2b   = x0b;

    const int gather_blocks = (NROWS + 3) / 4;
    const int layer_nwg     = ((N_ENT + 127) / 128) * 2;   // 1564
    const int wstack_blocks = (224 * 672 + 255) / 256;

    // ---- converts + CSR build ----
    convert_kernel<<<(N_ENT * DIM + 1023) / 1024, 256, 0, stream>>>(init_embed, x0b, N_ENT * DIM);
    convert_kernel<<<(N_REL2 * DIM + 1023) / 1024, 256, 0, stream>>>(init_rel, r0b, N_REL2 * DIM);
    hipMemsetAsync(cnt, 0, (size_t)NROWS * 4, stream);
    hist_kernel<<<(E_TOT + 255) / 256, 256, 0, stream>>>(edge_index, cnt);
    scan1_kernel<<<SNBLK, 256, 0, stream>>>(cnt, row_start, blockSum);
    scan2_kernel<<<1, 1, 0, stream>>>(blockSum);
    scan3_kernel<<<(NROWS + 255) / 256, 256, 0, stream>>>(row_start, row_cur, blockSum);
    fill_kernel<<<(E_TOT + 255) / 256, 256, 0, stream>>>(edge_index, edge_type, row_cur, epair);

    // ---- layer 1 ----
    wstack_kernel<<<wstack_blocks, 256, 0, stream>>>(w_in1, w_out1, w_loop1, WT);
    gather_kernel<<<gather_blocks, 256, 0, stream>>>(x0b, r0b, epair, row_start, cnt, aggb);
    lv_kernel<<<1, 256, 0, stream>>>(loop_rel1, w_loop1, lv);
    layer_mfma_kernel<<<layer_nwg, 256, 0, stream>>>(aggIb, aggOb, x0b, WT, lv, b1, x1b, layer_nwg);
    rgemm_kernel<<<(N_REL2 * DIM + 255) / 256, 256, 0, stream>>>(init_rel, w_rel1, r1f, N_REL2);
    convert_kernel<<<(N_REL2 * DIM + 1023) / 1024, 256, 0, stream>>>(r1f, r1b, N_REL2 * DIM);

    // ---- layer 2 ----
    wstack_kernel<<<wstack_blocks, 256, 0, stream>>>(w_in2, w_out2, w_loop2, WT);
    gather_kernel<<<gather_blocks, 256, 0, stream>>>(x1b, r1b, epair, row_start, cnt, aggb);
    lv_kernel<<<1, 256, 0, stream>>>(loop_rel2, w_loop2, lv);
    layer_mfma_kernel<<<layer_nwg, 256, 0, stream>>>(aggIb, aggOb, x1b, WT, lv, b2, x2b, layer_nwg);
    rgemm_kernel<<<(N_REL2 * DIM + 255) / 256, 256, 0, stream>>>(r1f, w_rel2, r2f, N_REL2);

    // ---- ConvE ----
    img_kernel<<<(BB * 400 + 255) / 256, 256, 0, stream>>>(x2b, r2f, sub, rel,
                                                           bn0_g, bn0_b, img);
    im2col_kernel<<<(50176 * 64 + 255) / 256, 256, 0, stream>>>(img, IM);
    cwt_kernel<<<(208 * 64 + 255) / 256, 256, 0, stream>>>(conv_w, CWT);
    conv_mfma_kernel<<<50176 / 128, 256, 0, stream>>>(IM, CWT, conv_b, bn1_g, bn1_b, CO_B);
    fwt_kernel<<<1225 * 7, 256, 0, stream>>>(fc_w, FWT);
    fc_mfma_kernel<<<FC_KC * 4, 256, 0, stream>>>(CO_B, FWT, partials);
    fc_reduce_kernel<<<(BB * 224 + 255) / 256, 256, 0, stream>>>(partials, fc_b, bn2_g, bn2_b, hb16);

    // ---- logits ----
    logits_mfma_kernel<<<481 * 2, 256, 0, stream>>>(x2b, hb16, ent_bias, (float*)d_out);
}

// Round 8
// 598.355 us; speedup vs baseline: 8.8108x; 1.0748x over previous
//
#include <hip/hip_runtime.h>
#include <math.h>

#define N_ENT   100000
#define N_REL2  1000
#define E_TOT   500000
#define E_HALF  250000
#define DIM     200
#define BB      256
#define NFILT   200
#define FLATK   39200
#define EPS_BN  1e-5f

#define NROWS   200000          // 100k in-rows + 100k out-rows
#define SCHUNK  2048
#define SNBLK   ((NROWS + SCHUNK - 1) / SCHUNK)   // 98

#define FC_KC   175             // fc split-K chunks (39200 = 175 * 224)
#define FC_KLEN 224             // 7 mfma k-steps

typedef __attribute__((ext_vector_type(8))) short bf16x8;   // 8 bf16 (4 VGPRs)
typedef __attribute__((ext_vector_type(4))) float f32x4;

__device__ __forceinline__ unsigned short f2b(float f) {
    union { float f; unsigned u; } c; c.f = f;
    unsigned u = c.u;
    u += 0x7fffu + ((u >> 16) & 1u);          // round-to-nearest-even
    return (unsigned short)(u >> 16);
}
__device__ __forceinline__ float b2f(unsigned short h) {
    union { unsigned u; float f; } c; c.u = ((unsigned)h) << 16;
    return c.f;
}
__device__ __forceinline__ float fast_tanh(float x) {
    float ax = fabsf(x);
    float e = __expf(-2.0f * ax);             // in (0,1], never overflows
    float t = (1.0f - e) / (1.0f + e);
    return copysignf(t, x);
}

// ---------------------------------------------------------------------------
// fp32 -> bf16 convert
// ---------------------------------------------------------------------------
__global__ void convert_kernel(const float* __restrict__ s, unsigned short* __restrict__ d,
                               int n) {
    int i = (blockIdx.x * 256 + threadIdx.x) * 4;
    if (i + 3 < n) {
        float4 v = *(const float4*)(s + i);
        ushort4 o;
        o.x = f2b(v.x); o.y = f2b(v.y); o.z = f2b(v.z); o.w = f2b(v.w);
        *(ushort4*)(d + i) = o;
    } else {
        for (; i < n; ++i) d[i] = f2b(s[i]);
    }
}

// ---------------------------------------------------------------------------
// Build WstackT[224][672] bf16: WstackT[j][seg*224+k] = Wseg[k][j] (zero-pad)
// ---------------------------------------------------------------------------
__global__ void wstack_kernel(const float* __restrict__ wIn, const float* __restrict__ wOut,
                              const float* __restrict__ wLoop, unsigned short* __restrict__ WT) {
    int g = blockIdx.x * 256 + threadIdx.x;
    if (g >= 224 * 672) return;
    int j = g / 672, t = g - j * 672;
    int seg = t / 224, k = t - seg * 224;
    float v = 0.f;
    if (j < 200 && k < 200)
        v = (seg == 0 ? wIn : seg == 1 ? wOut : wLoop)[k * 200 + j];
    WT[g] = f2b(v);
}

// ---------------------------------------------------------------------------
// fc weight transpose: FWT[j][k] = fc_w[k][j], bf16, j padded to 208.
// ---------------------------------------------------------------------------
__global__ void fwt_kernel(const float* __restrict__ fw, unsigned short* __restrict__ FWT) {
    __shared__ float t[32][33];
    const int bid = blockIdx.x;
    const int kt = bid % 1225, jt = bid / 1225;
    const int tid = threadIdx.x;
#pragma unroll
    for (int it = 0; it < 4; ++it) {
        int idx = tid + it * 256;
        int kk = idx >> 5, jj = idx & 31;
        int j = jt * 32 + jj;
        t[kk][jj] = (j < 200) ? fw[(size_t)(kt * 32 + kk) * 200 + j] : 0.f;
    }
    __syncthreads();
#pragma unroll
    for (int it = 0; it < 4; ++it) {
        int idx = tid + it * 256;
        int jj = idx >> 5, kk = idx & 31;
        int j = jt * 32 + jj;
        if (j < 208)
            FWT[(size_t)j * FLATK + kt * 32 + kk] = f2b(t[kk][jj]);
    }
}

// ---------------------------------------------------------------------------
// CSR build
// ---------------------------------------------------------------------------
__global__ void hist_kernel(const int* __restrict__ ei, int* __restrict__ cnt) {
    int e = blockIdx.x * 256 + threadIdx.x;
    if (e >= E_TOT) return;
    int row = ei[E_TOT + e] + (e < E_HALF ? 0 : N_ENT);
    atomicAdd(&cnt[row], 1);
}

__global__ void scan1_kernel(const int* __restrict__ cnt, int* __restrict__ row_start,
                             int* __restrict__ blockSum) {
    __shared__ int tsum[256];
    const int t = threadIdx.x;
    const int base = blockIdx.x * SCHUNK + t * 8;
    int v[8];
    int s = 0;
#pragma unroll
    for (int i = 0; i < 8; ++i) {
        int idx = base + i;
        int c = (idx < NROWS) ? cnt[idx] : 0;
        v[i] = s;
        s += c;
    }
    tsum[t] = s;
    __syncthreads();
    for (int off = 1; off < 256; off <<= 1) {
        int x = (t >= off) ? tsum[t - off] : 0;
        __syncthreads();
        if (t >= off) tsum[t] += x;
        __syncthreads();
    }
    int texc = (t == 0) ? 0 : tsum[t - 1];
    if (t == 0) blockSum[blockIdx.x] = tsum[255];
#pragma unroll
    for (int i = 0; i < 8; ++i) {
        int idx = base + i;
        if (idx < NROWS) row_start[idx] = texc + v[i];
    }
}

__global__ void scan2_kernel(int* __restrict__ blockSum) {
    int s = 0;
    for (int i = 0; i < SNBLK; ++i) { int c = blockSum[i]; blockSum[i] = s; s += c; }
}

__global__ void scan3_kernel(int* __restrict__ row_start, int* __restrict__ row_cur,
                             const int* __restrict__ blockSum) {
    int i = blockIdx.x * 256 + threadIdx.x;
    if (i >= NROWS) return;
    int v = row_start[i] + blockSum[i / SCHUNK];
    row_start[i] = v;
    row_cur[i] = v;
}

__global__ void fill_kernel(const int* __restrict__ ei, const int* __restrict__ et,
                            int* __restrict__ row_cur, int2* __restrict__ epair) {
    int e = blockIdx.x * 256 + threadIdx.x;
    if (e >= E_TOT) return;
    int row = ei[E_TOT + e] + (e < E_HALF ? 0 : N_ENT);
    int pos = atomicAdd(&row_cur[row], 1);
    epair[pos] = make_int2(ei[e], et[e]);
}

// ---------------------------------------------------------------------------
// gather (bf16): one wave per CSR row, lanes 0..49 own 4 bf16 each; fp32 accum;
// degree loop unrolled x2 with dual accumulators to break the latency chain.
// ---------------------------------------------------------------------------
__global__ void gather_kernel(const unsigned short* __restrict__ x,
                              const unsigned short* __restrict__ r,
                              const int2* __restrict__ epair,
                              const int* __restrict__ row_start, const int* __restrict__ cnt,
                              unsigned short* __restrict__ agg) {
    int wid = blockIdx.x * 4 + (threadIdx.x >> 6);
    if (wid >= NROWS) return;
    int lane = threadIdx.x & 63;
    if (lane >= 50) return;
    int start = row_start[wid];
    int deg = cnt[wid];
    float a0 = 0.f, a1 = 0.f, a2 = 0.f, a3 = 0.f;
    float c0 = 0.f, c1 = 0.f, c2 = 0.f, c3 = 0.f;
    int i = 0;
    for (; i + 2 <= deg; i += 2) {
        int2 e0 = epair[start + i];
        int2 e1 = epair[start + i + 1];
        ushort4 xv0 = *(const ushort4*)(x + (size_t)e0.x * DIM + lane * 4);
        ushort4 rv0 = *(const ushort4*)(r + (size_t)e0.y * DIM + lane * 4);
        ushort4 xv1 = *(const ushort4*)(x + (size_t)e1.x * DIM + lane * 4);
        ushort4 rv1 = *(const ushort4*)(r + (size_t)e1.y * DIM + lane * 4);
        a0 += b2f(xv0.x) - b2f(rv0.x);
        a1 += b2f(xv0.y) - b2f(rv0.y);
        a2 += b2f(xv0.z) - b2f(rv0.z);
        a3 += b2f(xv0.w) - b2f(rv0.w);
        c0 += b2f(xv1.x) - b2f(rv1.x);
        c1 += b2f(xv1.y) - b2f(rv1.y);
        c2 += b2f(xv1.z) - b2f(rv1.z);
        c3 += b2f(xv1.w) - b2f(rv1.w);
    }
    if (i < deg) {
        int2 e = epair[start + i];
        ushort4 xv = *(const ushort4*)(x + (size_t)e.x * DIM + lane * 4);
        ushort4 rv = *(const ushort4*)(r + (size_t)e.y * DIM + lane * 4);
        a0 += b2f(xv.x) - b2f(rv.x);
        a1 += b2f(xv.y) - b2f(rv.y);
        a2 += b2f(xv.z) - b2f(rv.z);
        a3 += b2f(xv.w) - b2f(rv.w);
    }
    float sc = 1.0f / fmaxf((float)deg, 1.0f);
    ushort4 o;
    o.x = f2b((a0 + c0) * sc);
    o.y = f2b((a1 + c1) * sc);
    o.z = f2b((a2 + c2) * sc);
    o.w = f2b((a3 + c3) * sc);
    *(ushort4*)(agg + (size_t)wid * DIM + lane * 4) = o;
}

// ---------------------------------------------------------------------------
// lv = loop_rel @ w_loop   (fp32, one 200-vector)
// ---------------------------------------------------------------------------
__global__ void lv_kernel(const float* __restrict__ lr, const float* __restrict__ wl,
                          float* __restrict__ lv) {
    int j = blockIdx.x * blockDim.x + threadIdx.x;
    if (j >= DIM) return;
    float acc = 0.f;
    for (int k = 0; k < DIM; ++k) acc += lr[k] * wl[k * DIM + j];
    lv[j] = acc;
}

// ---------------------------------------------------------------------------
// r_out = r_in @ w   fp32, tiny (rows=1000)
// ---------------------------------------------------------------------------
__global__ void rgemm_kernel(const float* __restrict__ r, const float* __restrict__ w,
                             float* __restrict__ out, int rows) {
    int g = blockIdx.x * 256 + threadIdx.x;
    if (g >= rows * DIM) return;
    int i = g / DIM, j = g - i * DIM;
    float acc = 0.f;
    for (int k = 0; k < DIM; ++k) acc += r[i * DIM + k] * w[k * DIM + j];
    out[g] = acc;
}

// ---------------------------------------------------------------------------
// MFMA layer v4 (occupancy-first): 256 thr = 4 waves (all M), block tile
// 128 rows x 112 cols, LDS [112][136] = 30.5 KB -> 4 blocks/CU.
// ---------------------------------------------------------------------------
#define LOAD_A2(g, buf) do {                                                    \
    const unsigned short* Ap_ = Aseg[(g) / 7];                                  \
    const unsigned short* base_ = Ap_ + (size_t)arow * 200 + ((g) % 7) * 32 + lq * 8; \
    buf[0] = *(const bf16x8*)(base_);                                           \
    buf[1] = *(const bf16x8*)(base_ + 16 * 200);                                \
} while (0)

__global__ __launch_bounds__(256, 4) void layer_mfma_kernel(
        const unsigned short* __restrict__ aggI, const unsigned short* __restrict__ aggO,
        const unsigned short* __restrict__ xin, const unsigned short* __restrict__ WT,
        const float* __restrict__ lv, const float* __restrict__ bias,
        unsigned short* __restrict__ out, int nwg) {
    __shared__ unsigned short Wl[112 * 136];          // 30,464 B
    const int bid = blockIdx.x;
    const int q = nwg >> 3, rr = nwg & 7;
    const int xcd = bid & 7, idx = bid >> 3;
    const int L = (xcd < rr ? xcd * (q + 1) : rr * (q + 1) + (xcd - rr) * q) + idx;
    const int rowblk  = L >> 1;
    const int colbase = (L & 1) * 112;

    const int tid  = threadIdx.x;
    const int wm   = tid >> 6;
    const int lane = tid & 63;
    const int lr   = lane & 15;
    const int lq   = lane >> 4;
    const int row0 = rowblk * 128;
    const int arow = row0 + wm * 32 + lr;

    const unsigned short* const Aseg[3] = { aggI, aggO, xin };

    f32x4 acc[2][7];
#pragma unroll
    for (int m = 0; m < 2; ++m)
#pragma unroll
        for (int n = 0; n < 7; ++n) acc[m][n] = (f32x4){0.f, 0.f, 0.f, 0.f};

    bf16x8 apf[3][2];                     // rotating A prefetch, depth 2
    LOAD_A2(0, apf[0]);
    LOAD_A2(1, apf[1]);

#pragma unroll
    for (int seg = 0; seg < 3; ++seg) {
#pragma unroll
        for (int ph = 0; ph < 2; ++ph) {
            if (seg + ph) __syncthreads();
            if (ph == 0) {
#pragma unroll
                for (int it = 0; it < 7; ++it) {
                    int u = tid + it * 256;
                    int col = u >> 4, kq = u & 15;
                    *(int4*)(&Wl[col * 136 + kq * 8]) =
                        *(const int4*)(WT + (size_t)(colbase + col) * 672 + seg * 224 + kq * 8);
                }
            } else {
                for (int u = tid; u < 1344; u += 256) {
                    int col = u / 12, kq = u - col * 12;
                    *(int4*)(&Wl[col * 136 + kq * 8]) =
                        *(const int4*)(WT + (size_t)(colbase + col) * 672 + seg * 224 + 128 + kq * 8);
                }
            }
            __syncthreads();
            const int NC = (ph == 0) ? 4 : 3;
#pragma unroll
            for (int cc = 0; cc < NC; ++cc) {
                const int g = seg * 7 + (ph ? 4 : 0) + cc;
                if (g + 2 < 21) LOAD_A2(g + 2, apf[(g + 2) % 3]);
#pragma unroll
                for (int n = 0; n < 7; ++n) {
                    bf16x8 b = *(const bf16x8*)(&Wl[(n * 16 + lr) * 136 + cc * 32 + lq * 8]);
                    acc[0][n] = __builtin_amdgcn_mfma_f32_16x16x32_bf16(apf[g % 3][0], b, acc[0][n], 0, 0, 0);
                    acc[1][n] = __builtin_amdgcn_mfma_f32_16x16x32_bf16(apf[g % 3][1], b, acc[1][n], 0, 0, 0);
                }
            }
        }
    }

#pragma unroll
    for (int m = 0; m < 2; ++m) {
        int rbase = row0 + wm * 32 + m * 16 + lq * 4;
#pragma unroll
        for (int n = 0; n < 7; ++n) {
            int col = colbase + n * 16 + lr;
            if (col < 200) {
                float lvc = lv[col], bc = bias[col];
#pragma unroll
                for (int r2 = 0; r2 < 4; ++r2) {
                    int row = rbase + r2;
                    if (row < N_ENT) {
                        float v = (acc[m][n][r2] - lvc) * (1.0f / 3.0f) + bc;
                        out[(size_t)row * 200 + col] = f2b(fast_tanh(v));
                    }
                }
            }
        }
    }
}

// ---------------------------------------------------------------------------
// build ConvE input images with BN0 (bf16 out)
// ---------------------------------------------------------------------------
__global__ void img_kernel(const unsigned short* __restrict__ x, const float* __restrict__ r,
                           const int* __restrict__ sub, const int* __restrict__ rel,
                           const float* __restrict__ bn0g, const float* __restrict__ bn0b,
                           unsigned short* __restrict__ img) {
    int g = blockIdx.x * 256 + threadIdx.x;
    if (g >= BB * 2 * DIM) return;
    int b = g / 400, l = g - b * 400;
    int d = l >> 1;
    float v = (l & 1) ? r[(size_t)rel[b] * DIM + d] : b2f(x[(size_t)sub[b] * DIM + d]);
    float s0 = bn0g[0] * rsqrtf(1.0f + EPS_BN);
    img[g] = f2b(v * s0 + bn0b[0]);
}

// ---------------------------------------------------------------------------
// im2col: IM[b*196+p][64], k = i*7+j (49 real, 64 padded with zeros)
// ---------------------------------------------------------------------------
__global__ void im2col_kernel(const unsigned short* __restrict__ img,
                              unsigned short* __restrict__ IM) {
    int g = blockIdx.x * 256 + threadIdx.x;
    if (g >= 50176 * 64) return;
    int row = g >> 6, k = g & 63;
    int b = row / 196, p = row - b * 196;
    int h = p / 14, w = p - h * 14;
    unsigned short v = 0;
    if (k < 49) {
        int i = k / 7, j = k - i * 7;
        v = img[b * 400 + (h + i) * 20 + (w + j)];
    }
    IM[g] = v;
}

// CWT[208][64] bf16: CWT[f][k] = conv_w[f][k], zero-padded
__global__ void cwt_kernel(const float* __restrict__ cw, unsigned short* __restrict__ CWT) {
    int g = blockIdx.x * 256 + threadIdx.x;
    if (g >= 208 * 64) return;
    int f = g >> 6, k = g & 63;
    CWT[g] = (f < 200 && k < 49) ? f2b(cw[f * 49 + k]) : 0;
}

// ---------------------------------------------------------------------------
// conv as MFMA: [50176 x 64] @ [64 x 200(pad 208)], zero-LDS/zero-barrier.
// Epilogue: +conv_b, BN1, relu, write CO_B[b][f*196+p] bf16 (fc A-layout).
// ---------------------------------------------------------------------------
__global__ __launch_bounds__(256) void conv_mfma_kernel(
        const unsigned short* __restrict__ IM, const unsigned short* __restrict__ CWT,
        const float* __restrict__ cb, const float* __restrict__ bn1g,
        const float* __restrict__ bn1b, unsigned short* __restrict__ CO_B) {
    const int tid  = threadIdx.x;
    const int row0 = blockIdx.x * 128;
    const int wave = tid >> 6;
    const int lane = tid & 63;
    const int lr   = lane & 15;
    const int lq   = lane >> 4;
    const int arow = row0 + wave * 32 + lr;

    f32x4 acc[2][13];
#pragma unroll
    for (int m = 0; m < 2; ++m)
#pragma unroll
        for (int n = 0; n < 13; ++n) acc[m][n] = (f32x4){0.f, 0.f, 0.f, 0.f};

#pragma unroll
    for (int c = 0; c < 2; ++c) {
        const int k = c * 32 + lq * 8;
        bf16x8 a0 = *(const bf16x8*)(IM + (size_t)arow * 64 + k);
        bf16x8 a1 = *(const bf16x8*)(IM + (size_t)(arow + 16) * 64 + k);
#pragma unroll
        for (int n = 0; n < 13; ++n) {
            bf16x8 b = *(const bf16x8*)(CWT + (size_t)(n * 16 + lr) * 64 + k);
            acc[0][n] = __builtin_amdgcn_mfma_f32_16x16x32_bf16(a0, b, acc[0][n], 0, 0, 0);
            acc[1][n] = __builtin_amdgcn_mfma_f32_16x16x32_bf16(a1, b, acc[1][n], 0, 0, 0);
        }
    }

#pragma unroll
    for (int m = 0; m < 2; ++m) {
        int grow_base = row0 + wave * 32 + m * 16 + lq * 4;
#pragma unroll
        for (int n = 0; n < 13; ++n) {
            int col = n * 16 + lr;          // filter
            if (col < 200) {
                float s1 = bn1g[col] * rsqrtf(1.0f + EPS_BN);
                float t1 = bn1b[col];
                float cbf = cb[col];
#pragma unroll
                for (int r = 0; r < 4; ++r) {
                    int grow = grow_base + r;          // b*196+p, always < 50176
                    int b = grow / 196, p = grow - b * 196;
                    float v = fmaxf((acc[m][n][r] + cbf) * s1 + t1, 0.f);
                    CO_B[(size_t)b * FLATK + col * 196 + p] = f2b(v);
                }
            }
        }
    }
}

// ---------------------------------------------------------------------------
// fc as MFMA split-K: [256 x 39200] @ [39200 x 208], 175 k-chunks x 4 m-blocks.
// ---------------------------------------------------------------------------
__global__ __launch_bounds__(256) void fc_mfma_kernel(
        const unsigned short* __restrict__ CO_B, const unsigned short* __restrict__ FWT,
        float* __restrict__ partials) {
    const int tid  = threadIdx.x;
    const int kc   = blockIdx.x >> 2;
    const int mb   = blockIdx.x & 3;
    const int wave = tid >> 6;
    const int lane = tid & 63;
    const int lr   = lane & 15;
    const int lq   = lane >> 4;
    const int m0   = mb * 64 + wave * 16;

    f32x4 acc[13];
#pragma unroll
    for (int n = 0; n < 13; ++n) acc[n] = (f32x4){0.f, 0.f, 0.f, 0.f};

#pragma unroll
    for (int s = 0; s < 7; ++s) {
        const int k = kc * FC_KLEN + s * 32 + lq * 8;
        bf16x8 a = *(const bf16x8*)(CO_B + (size_t)(m0 + lr) * FLATK + k);
#pragma unroll
        for (int n = 0; n < 13; ++n) {
            bf16x8 b = *(const bf16x8*)(FWT + (size_t)(n * 16 + lr) * FLATK + k);
            acc[n] = __builtin_amdgcn_mfma_f32_16x16x32_bf16(a, b, acc[n], 0, 0, 0);
        }
    }

    float* slab = partials + (size_t)kc * (BB * 208);
#pragma unroll
    for (int n = 0; n < 13; ++n) {
        int col = n * 16 + lr;
#pragma unroll
        for (int r = 0; r < 4; ++r) {
            int row = m0 + lq * 4 + r;
            slab[(size_t)row * 208 + col] = acc[n][r];
        }
    }
}

// hb16[b][j=224] = relu((sum_kc partial + fc_b)*bn2s+bn2b) bf16, pad j>=200
__global__ void fc_reduce_kernel(const float* __restrict__ partials,
                                 const float* __restrict__ fcb,
                                 const float* __restrict__ g2, const float* __restrict__ b2v,
                                 unsigned short* __restrict__ hb) {
    int g = blockIdx.x * 256 + threadIdx.x;
    if (g >= BB * 224) return;
    int b = g / 224, j = g - b * 224;
    unsigned short o = 0;
    if (j < 200) {
        float s = 0.f;
        const float* p = partials + (size_t)b * 208 + j;
#pragma unroll 5
        for (int c = 0; c < FC_KC; ++c)
            s += p[(size_t)c * (BB * 208)];
        float v = (s + fcb[j]) * (g2[j] * rsqrtf(1.0f + EPS_BN)) + b2v[j];
        o = f2b(fmaxf(v, 0.f));
    }
    hb[g] = o;
}

// ---------------------------------------------------------------------------
// logits MFMA v2: D[b][ent] = sigmoid(h[b]·x[ent] + eb[ent]).
// 893 blocks x 512 thr (8 waves = 2 batch-halves x 4 row-groups).
// Block tile: 256 batch x 112 ents; x-slice staged in LDS [112][136]
// (30.5 KB, coalesced contiguous reads), A=hb via rotating reg prefetch.
// ---------------------------------------------------------------------------
#define LOAD_HB(g, buf) do {                                                    \
    const unsigned short* base_ = hb + (size_t)brow * 224 + (g) * 32 + lq * 8;  \
    buf[0] = *(const bf16x8*)(base_);                                           \
    buf[1] = *(const bf16x8*)(base_ + 16 * 224);                                \
} while (0)

__global__ __launch_bounds__(512, 2) void logits_mfma_kernel(
        const unsigned short* __restrict__ x, const unsigned short* __restrict__ hb,
        const float* __restrict__ eb, float* __restrict__ out, int nwg) {
    __shared__ unsigned short Xl[112 * 136];          // 30,464 B
    const int bid = blockIdx.x;
    const int q = nwg >> 3, rr = nwg & 7;
    const int xcd = bid & 7, idx = bid >> 3;
    const int nb = (xcd < rr ? xcd * (q + 1) : rr * (q + 1) + (xcd - rr) * q) + idx;
    const int ent0 = nb * 112;

    const int tid  = threadIdx.x;
    const int wave = tid >> 6;
    const int mh   = wave >> 2;          // batch half (0/1)
    const int wm   = wave & 3;           // 32-row group
    const int lane = tid & 63;
    const int lr   = lane & 15;
    const int lq   = lane >> 4;
    const int brow = mh * 128 + wm * 32 + lr;

    f32x4 acc[2][7];
#pragma unroll
    for (int m = 0; m < 2; ++m)
#pragma unroll
        for (int n = 0; n < 7; ++n) acc[m][n] = (f32x4){0.f, 0.f, 0.f, 0.f};

    bf16x8 apf[3][2];                     // rotating A prefetch, depth 2
    LOAD_HB(0, apf[0]);
    LOAD_HB(1, apf[1]);

#pragma unroll
    for (int ph = 0; ph < 2; ++ph) {
        if (ph) __syncthreads();
        if (ph == 0) {
            // stage k 0..127: 112 rows x 16 int4 units (contiguous per row)
#pragma unroll
            for (int it = 0; it < 4; ++it) {
                int u = tid + it * 512;
                if (u < 1792) {
                    int row = u >> 4, c = u & 15;
                    int ent = ent0 + row;
                    int4 v = make_int4(0, 0, 0, 0);
                    if (ent < N_ENT)
                        v = *(const int4*)(x + (size_t)ent * 200 + c * 8);
                    *(int4*)(&Xl[row * 136 + c * 8]) = v;
                }
            }
        } else {
            // stage k 128..223: units 16..27 (real to unit 24, then zeros)
            for (int u = tid; u < 1344; u += 512) {
                int row = u / 12, c = u - row * 12;
                int gu = 16 + c;
                int ent = ent0 + row;
                int4 v = make_int4(0, 0, 0, 0);
                if (ent < N_ENT && gu < 25)
                    v = *(const int4*)(x + (size_t)ent * 200 + gu * 8);
                *(int4*)(&Xl[row * 136 + c * 8]) = v;
            }
        }
        __syncthreads();
        const int NC = (ph == 0) ? 4 : 3;
#pragma unroll
        for (int cc = 0; cc < NC; ++cc) {
            const int g = (ph ? 4 : 0) + cc;
            if (g + 2 < 7) LOAD_HB(g + 2, apf[(g + 2) % 3]);
#pragma unroll
            for (int n = 0; n < 7; ++n) {
                bf16x8 b = *(const bf16x8*)(&Xl[(n * 16 + lr) * 136 + cc * 32 + lq * 8]);
                acc[0][n] = __builtin_amdgcn_mfma_f32_16x16x32_bf16(apf[g % 3][0], b, acc[0][n], 0, 0, 0);
                acc[1][n] = __builtin_amdgcn_mfma_f32_16x16x32_bf16(apf[g % 3][1], b, acc[1][n], 0, 0, 0);
            }
        }
    }

#pragma unroll
    for (int m = 0; m < 2; ++m) {
        int b_base = mh * 128 + wm * 32 + m * 16 + lq * 4;
#pragma unroll
        for (int n = 0; n < 7; ++n) {
            int ent = ent0 + n * 16 + lr;
            if (ent < N_ENT) {
                float bias = eb[ent];
#pragma unroll
                for (int r = 0; r < 4; ++r) {
                    float v = acc[m][n][r] + bias;
                    out[(size_t)(b_base + r) * N_ENT + ent] = 1.0f / (1.0f + __expf(-v));
                }
            }
        }
    }
}

// ---------------------------------------------------------------------------
extern "C" void kernel_launch(void* const* d_in, const int* in_sizes, int n_in,
                              void* d_out, int out_size, void* d_ws, size_t ws_size,
                              hipStream_t stream) {
    const int*   sub        = (const int*)  d_in[0];
    const int*   rel        = (const int*)  d_in[1];
    const int*   edge_index = (const int*)  d_in[2];
    const int*   edge_type  = (const int*)  d_in[3];
    const float* init_embed = (const float*)d_in[4];
    const float* init_rel   = (const float*)d_in[5];
    const float* loop_rel1  = (const float*)d_in[6];
    const float* loop_rel2  = (const float*)d_in[7];
    const float* w_in1      = (const float*)d_in[8];
    const float* w_out1     = (const float*)d_in[9];
    const float* w_loop1    = (const float*)d_in[10];
    const float* w_rel1     = (const float*)d_in[11];
    const float* b1         = (const float*)d_in[12];
    const float* w_in2      = (const float*)d_in[13];
    const float* w_out2     = (const float*)d_in[14];
    const float* w_loop2    = (const float*)d_in[15];
    const float* w_rel2     = (const float*)d_in[16];
    const float* b2         = (const float*)d_in[17];
    const float* conv_w     = (const float*)d_in[18];
    const float* conv_b     = (const float*)d_in[19];
    const float* bn0_g      = (const float*)d_in[20];
    const float* bn0_b      = (const float*)d_in[21];
    const float* bn1_g      = (const float*)d_in[22];
    const float* bn1_b      = (const float*)d_in[23];
    const float* bn2_g      = (const float*)d_in[24];
    const float* bn2_b      = (const float*)d_in[25];
    const float* fc_w       = (const float*)d_in[26];
    const float* fc_b       = (const float*)d_in[27];
    const float* ent_bias   = (const float*)d_in[28];

    // ---- bf16 region ----
    unsigned short* aggb = (unsigned short*)d_ws;     // 40,000,000
    unsigned short* x0b  = aggb + 40000000;           // 20,000,000 (init; reused as x2b)
    unsigned short* x1b  = x0b  + 20000000;           // 20,000,000
    unsigned short* r0b  = x1b  + 20000000;           //    200,000
    unsigned short* r1b  = r0b  + 200000;             //    200,000
    unsigned short* WT   = r1b  + 200000;             //    150,528 (224*672)
    unsigned short* img  = WT   + 150528;             //    102,400
    unsigned short* IM   = img  + 102400;             //  3,211,264 (50176*64)
    unsigned short* CWT  = IM   + 3211264;            //     13,312
    unsigned short* CO_B = CWT  + 13312;              // 10,035,200 (256*39200)
    unsigned short* hb16 = CO_B + 10035200;           //     57,344 (256*224)
    unsigned short* FWT  = hb16 + 57344;              //  8,153,600 (208*39200)
    // ---- fp32 region ----
    float* fbase = (float*)(FWT + 8153600);
    float* r1f      = fbase;                          // 200,000
    float* r2f      = r1f  + 200000;                  // 200,000
    float* lv       = r2f  + 200000;                  // 256
    float* partials = lv   + 256;                     // 9,318,400 (175*256*208)

    // CSR ints alias CO_B (last CSR read = gather2, before conv writes CO_B)
    int2* epair    = (int2*)CO_B;                     // 500,000 int2
    int* cnt       = (int*)(epair + E_TOT);           // 200,000
    int* row_start = cnt  + NROWS;                    // 200,000
    int* row_cur   = row_start + NROWS;               // 200,000
    int* blockSum  = row_cur + NROWS;                 // 98

    unsigned short* aggIb = aggb;
    unsigned short* aggOb = aggb + (size_t)N_ENT * DIM;
    unsigned short* x2b   = x0b;

    const int gather_blocks = (NROWS + 3) / 4;
    const int layer_nwg     = ((N_ENT + 127) / 128) * 2;   // 1564
    const int logits_nwg    = (N_ENT + 111) / 112;         // 893
    const int wstack_blocks = (224 * 672 + 255) / 256;

    // ---- converts + CSR build ----
    convert_kernel<<<(N_ENT * DIM + 1023) / 1024, 256, 0, stream>>>(init_embed, x0b, N_ENT * DIM);
    convert_kernel<<<(N_REL2 * DIM + 1023) / 1024, 256, 0, stream>>>(init_rel, r0b, N_REL2 * DIM);
    hipMemsetAsync(cnt, 0, (size_t)NROWS * 4, stream);
    hist_kernel<<<(E_TOT + 255) / 256, 256, 0, stream>>>(edge_index, cnt);
    scan1_kernel<<<SNBLK, 256, 0, stream>>>(cnt, row_start, blockSum);
    scan2_kernel<<<1, 1, 0, stream>>>(blockSum);
    scan3_kernel<<<(NROWS + 255) / 256, 256, 0, stream>>>(row_start, row_cur, blockSum);
    fill_kernel<<<(E_TOT + 255) / 256, 256, 0, stream>>>(edge_index, edge_type, row_cur, epair);

    // ---- layer 1 ----
    wstack_kernel<<<wstack_blocks, 256, 0, stream>>>(w_in1, w_out1, w_loop1, WT);
    gather_kernel<<<gather_blocks, 256, 0, stream>>>(x0b, r0b, epair, row_start, cnt, aggb);
    lv_kernel<<<1, 256, 0, stream>>>(loop_rel1, w_loop1, lv);
    layer_mfma_kernel<<<layer_nwg, 256, 0, stream>>>(aggIb, aggOb, x0b, WT, lv, b1, x1b, layer_nwg);
    rgemm_kernel<<<(N_REL2 * DIM + 255) / 256, 256, 0, stream>>>(init_rel, w_rel1, r1f, N_REL2);
    convert_kernel<<<(N_REL2 * DIM + 1023) / 1024, 256, 0, stream>>>(r1f, r1b, N_REL2 * DIM);

    // ---- layer 2 ----
    wstack_kernel<<<wstack_blocks, 256, 0, stream>>>(w_in2, w_out2, w_loop2, WT);
    gather_kernel<<<gather_blocks, 256, 0, stream>>>(x1b, r1b, epair, row_start, cnt, aggb);
    lv_kernel<<<1, 256, 0, stream>>>(loop_rel2, w_loop2, lv);
    layer_mfma_kernel<<<layer_nwg, 256, 0, stream>>>(aggIb, aggOb, x1b, WT, lv, b2, x2b, layer_nwg);
    rgemm_kernel<<<(N_REL2 * DIM + 255) / 256, 256, 0, stream>>>(r1f, w_rel2, r2f, N_REL2);

    // ---- ConvE ----
    img_kernel<<<(BB * 400 + 255) / 256, 256, 0, stream>>>(x2b, r2f, sub, rel,
                                                           bn0_g, bn0_b, img);
    im2col_kernel<<<(50176 * 64 + 255) / 256, 256, 0, stream>>>(img, IM);
    cwt_kernel<<<(208 * 64 + 255) / 256, 256, 0, stream>>>(conv_w, CWT);
    conv_mfma_kernel<<<50176 / 128, 256, 0, stream>>>(IM, CWT, conv_b, bn1_g, bn1_b, CO_B);
    fwt_kernel<<<1225 * 7, 256, 0, stream>>>(fc_w, FWT);
    fc_mfma_kernel<<<FC_KC * 4, 256, 0, stream>>>(CO_B, FWT, partials);
    fc_reduce_kernel<<<(BB * 224 + 255) / 256, 256, 0, stream>>>(partials, fc_b, bn2_g, bn2_b, hb16);

    // ---- logits ----
    logits_mfma_kernel<<<logits_nwg, 512, 0, stream>>>(x2b, hb16, ent_bias, (float*)d_out,
                                                       logits_nwg);
}

// Round 9
// 588.642 us; speedup vs baseline: 8.9562x; 1.0165x over previous
//
#include <hip/hip_runtime.h>
#include <math.h>

#define N_ENT   100000
#define N_REL2  1000
#define E_TOT   500000
#define E_HALF  250000
#define DIM     200
#define BB      256
#define NFILT   200
#define FLATK   39200
#define EPS_BN  1e-5f

#define NROWS   200000          // 100k in-rows + 100k out-rows
#define SCHUNK  2048
#define SNBLK   ((NROWS + SCHUNK - 1) / SCHUNK)   // 98

#define FC_KC   175             // fc split-K chunks (39200 = 175 * 224)
#define FC_KLEN 224             // 7 mfma k-steps

typedef __attribute__((ext_vector_type(8))) short bf16x8;   // 8 bf16 (4 VGPRs)
typedef __attribute__((ext_vector_type(4))) float f32x4;

__device__ __forceinline__ unsigned short f2b(float f) {
    union { float f; unsigned u; } c; c.f = f;
    unsigned u = c.u;
    u += 0x7fffu + ((u >> 16) & 1u);          // round-to-nearest-even
    return (unsigned short)(u >> 16);
}
__device__ __forceinline__ float b2f(unsigned short h) {
    union { unsigned u; float f; } c; c.u = ((unsigned)h) << 16;
    return c.f;
}
__device__ __forceinline__ float fast_tanh(float x) {
    float ax = fabsf(x);
    float e = __expf(-2.0f * ax);             // in (0,1], never overflows
    float t = (1.0f - e) / (1.0f + e);
    return copysignf(t, x);
}

// ---------------------------------------------------------------------------
// fp32 -> bf16 convert
// ---------------------------------------------------------------------------
__global__ void convert_kernel(const float* __restrict__ s, unsigned short* __restrict__ d,
                               int n) {
    int i = (blockIdx.x * 256 + threadIdx.x) * 4;
    if (i + 3 < n) {
        float4 v = *(const float4*)(s + i);
        ushort4 o;
        o.x = f2b(v.x); o.y = f2b(v.y); o.z = f2b(v.z); o.w = f2b(v.w);
        *(ushort4*)(d + i) = o;
    } else {
        for (; i < n; ++i) d[i] = f2b(s[i]);
    }
}

// ---------------------------------------------------------------------------
// Build WstackT[224][672] bf16: WstackT[j][seg*224+k] = Wseg[k][j] (zero-pad)
// ---------------------------------------------------------------------------
__global__ void wstack_kernel(const float* __restrict__ wIn, const float* __restrict__ wOut,
                              const float* __restrict__ wLoop, unsigned short* __restrict__ WT) {
    int g = blockIdx.x * 256 + threadIdx.x;
    if (g >= 224 * 672) return;
    int j = g / 672, t = g - j * 672;
    int seg = t / 224, k = t - seg * 224;
    float v = 0.f;
    if (j < 200 && k < 200)
        v = (seg == 0 ? wIn : seg == 1 ? wOut : wLoop)[k * 200 + j];
    WT[g] = f2b(v);
}

// ---------------------------------------------------------------------------
// fc weight transpose: FWT[j][k] = fc_w[k][j], bf16, j padded to 208.
// ---------------------------------------------------------------------------
__global__ void fwt_kernel(const float* __restrict__ fw, unsigned short* __restrict__ FWT) {
    __shared__ float t[32][33];
    const int bid = blockIdx.x;
    const int kt = bid % 1225, jt = bid / 1225;
    const int tid = threadIdx.x;
#pragma unroll
    for (int it = 0; it < 4; ++it) {
        int idx = tid + it * 256;
        int kk = idx >> 5, jj = idx & 31;
        int j = jt * 32 + jj;
        t[kk][jj] = (j < 200) ? fw[(size_t)(kt * 32 + kk) * 200 + j] : 0.f;
    }
    __syncthreads();
#pragma unroll
    for (int it = 0; it < 4; ++it) {
        int idx = tid + it * 256;
        int jj = idx >> 5, kk = idx & 31;
        int j = jt * 32 + jj;
        if (j < 208)
            FWT[(size_t)j * FLATK + kt * 32 + kk] = f2b(t[kk][jj]);
    }
}

// ---------------------------------------------------------------------------
// CSR build
// ---------------------------------------------------------------------------
__global__ void hist_kernel(const int* __restrict__ ei, int* __restrict__ cnt) {
    int e = blockIdx.x * 256 + threadIdx.x;
    if (e >= E_TOT) return;
    int row = ei[E_TOT + e] + (e < E_HALF ? 0 : N_ENT);
    atomicAdd(&cnt[row], 1);
}

__global__ void scan1_kernel(const int* __restrict__ cnt, int* __restrict__ row_start,
                             int* __restrict__ blockSum) {
    __shared__ int tsum[256];
    const int t = threadIdx.x;
    const int base = blockIdx.x * SCHUNK + t * 8;
    int v[8];
    int s = 0;
#pragma unroll
    for (int i = 0; i < 8; ++i) {
        int idx = base + i;
        int c = (idx < NROWS) ? cnt[idx] : 0;
        v[i] = s;
        s += c;
    }
    tsum[t] = s;
    __syncthreads();
    for (int off = 1; off < 256; off <<= 1) {
        int x = (t >= off) ? tsum[t - off] : 0;
        __syncthreads();
        if (t >= off) tsum[t] += x;
        __syncthreads();
    }
    int texc = (t == 0) ? 0 : tsum[t - 1];
    if (t == 0) blockSum[blockIdx.x] = tsum[255];
#pragma unroll
    for (int i = 0; i < 8; ++i) {
        int idx = base + i;
        if (idx < NROWS) row_start[idx] = texc + v[i];
    }
}

__global__ void scan2_kernel(int* __restrict__ blockSum) {
    int s = 0;
    for (int i = 0; i < SNBLK; ++i) { int c = blockSum[i]; blockSum[i] = s; s += c; }
}

__global__ void scan3_kernel(int* __restrict__ row_start, int* __restrict__ row_cur,
                             const int* __restrict__ blockSum) {
    int i = blockIdx.x * 256 + threadIdx.x;
    if (i >= NROWS) return;
    int v = row_start[i] + blockSum[i / SCHUNK];
    row_start[i] = v;
    row_cur[i] = v;
}

__global__ void fill_kernel(const int* __restrict__ ei, const int* __restrict__ et,
                            int* __restrict__ row_cur, int2* __restrict__ epair) {
    int e = blockIdx.x * 256 + threadIdx.x;
    if (e >= E_TOT) return;
    int row = ei[E_TOT + e] + (e < E_HALF ? 0 : N_ENT);
    int pos = atomicAdd(&row_cur[row], 1);
    epair[pos] = make_int2(ei[e], et[e]);
}

// ---------------------------------------------------------------------------
// gather (bf16): one wave per CSR row, lanes 0..49 own 4 bf16 each; fp32 accum;
// degree loop unrolled x2 with dual accumulators to break the latency chain.
// ---------------------------------------------------------------------------
__global__ void gather_kernel(const unsigned short* __restrict__ x,
                              const unsigned short* __restrict__ r,
                              const int2* __restrict__ epair,
                              const int* __restrict__ row_start, const int* __restrict__ cnt,
                              unsigned short* __restrict__ agg) {
    int wid = blockIdx.x * 4 + (threadIdx.x >> 6);
    if (wid >= NROWS) return;
    int lane = threadIdx.x & 63;
    if (lane >= 50) return;
    int start = row_start[wid];
    int deg = cnt[wid];
    float a0 = 0.f, a1 = 0.f, a2 = 0.f, a3 = 0.f;
    float c0 = 0.f, c1 = 0.f, c2 = 0.f, c3 = 0.f;
    int i = 0;
    for (; i + 2 <= deg; i += 2) {
        int2 e0 = epair[start + i];
        int2 e1 = epair[start + i + 1];
        ushort4 xv0 = *(const ushort4*)(x + (size_t)e0.x * DIM + lane * 4);
        ushort4 rv0 = *(const ushort4*)(r + (size_t)e0.y * DIM + lane * 4);
        ushort4 xv1 = *(const ushort4*)(x + (size_t)e1.x * DIM + lane * 4);
        ushort4 rv1 = *(const ushort4*)(r + (size_t)e1.y * DIM + lane * 4);
        a0 += b2f(xv0.x) - b2f(rv0.x);
        a1 += b2f(xv0.y) - b2f(rv0.y);
        a2 += b2f(xv0.z) - b2f(rv0.z);
        a3 += b2f(xv0.w) - b2f(rv0.w);
        c0 += b2f(xv1.x) - b2f(rv1.x);
        c1 += b2f(xv1.y) - b2f(rv1.y);
        c2 += b2f(xv1.z) - b2f(rv1.z);
        c3 += b2f(xv1.w) - b2f(rv1.w);
    }
    if (i < deg) {
        int2 e = epair[start + i];
        ushort4 xv = *(const ushort4*)(x + (size_t)e.x * DIM + lane * 4);
        ushort4 rv = *(const ushort4*)(r + (size_t)e.y * DIM + lane * 4);
        a0 += b2f(xv.x) - b2f(rv.x);
        a1 += b2f(xv.y) - b2f(rv.y);
        a2 += b2f(xv.z) - b2f(rv.z);
        a3 += b2f(xv.w) - b2f(rv.w);
    }
    float sc = 1.0f / fmaxf((float)deg, 1.0f);
    ushort4 o;
    o.x = f2b((a0 + c0) * sc);
    o.y = f2b((a1 + c1) * sc);
    o.z = f2b((a2 + c2) * sc);
    o.w = f2b((a3 + c3) * sc);
    *(ushort4*)(agg + (size_t)wid * DIM + lane * 4) = o;
}

// ---------------------------------------------------------------------------
// lv = loop_rel @ w_loop   (fp32, one 200-vector)
// ---------------------------------------------------------------------------
__global__ void lv_kernel(const float* __restrict__ lr, const float* __restrict__ wl,
                          float* __restrict__ lv) {
    int j = blockIdx.x * blockDim.x + threadIdx.x;
    if (j >= DIM) return;
    float acc = 0.f;
    for (int k = 0; k < DIM; ++k) acc += lr[k] * wl[k * DIM + j];
    lv[j] = acc;
}

// ---------------------------------------------------------------------------
// r_out = r_in @ w   fp32, tiny (rows=1000)
// ---------------------------------------------------------------------------
__global__ void rgemm_kernel(const float* __restrict__ r, const float* __restrict__ w,
                             float* __restrict__ out, int rows) {
    int g = blockIdx.x * 256 + threadIdx.x;
    if (g >= rows * DIM) return;
    int i = g / DIM, j = g - i * DIM;
    float acc = 0.f;
    for (int k = 0; k < DIM; ++k) acc += r[i * DIM + k] * w[k * DIM + j];
    out[g] = acc;
}

// ---------------------------------------------------------------------------
// MFMA layer v5 (TLP-first): 256 thr = 4 waves, wave = 16 rows x 112 cols
// (acc = 7 f32x4 = 28 regs), block tile 64 rows x 112 cols. LDS [112][136]
// = 30.5 KB; launch_bounds(256,5) -> 5 blocks/CU = 20 waves/CU. A-prefetch
// rotating depth 3, statically indexed via full unroll.
// ---------------------------------------------------------------------------
#define LOAD_A1(g, slot) do {                                                   \
    const unsigned short* Ap_ = Aseg[(g) / 7];                                  \
    apf[slot] = *(const bf16x8*)(Ap_ + (size_t)arow * 200 + ((g) % 7) * 32 + lq * 8); \
} while (0)

__global__ __launch_bounds__(256, 5) void layer_mfma_kernel(
        const unsigned short* __restrict__ aggI, const unsigned short* __restrict__ aggO,
        const unsigned short* __restrict__ xin, const unsigned short* __restrict__ WT,
        const float* __restrict__ lv, const float* __restrict__ bias,
        unsigned short* __restrict__ out, int nwg) {
    __shared__ unsigned short Wl[112 * 136];          // 30,464 B
    const int bid = blockIdx.x;
    const int q = nwg >> 3, rr = nwg & 7;
    const int xcd = bid & 7, idx = bid >> 3;
    const int L = (xcd < rr ? xcd * (q + 1) : rr * (q + 1) + (xcd - rr) * q) + idx;
    const int rowblk  = L >> 1;
    const int colbase = (L & 1) * 112;

    const int tid  = threadIdx.x;
    const int wm   = tid >> 6;
    const int lane = tid & 63;
    const int lr   = lane & 15;
    const int lq   = lane >> 4;
    const int row0 = rowblk * 64;
    const int arow = row0 + wm * 16 + lr;

    const unsigned short* const Aseg[3] = { aggI, aggO, xin };

    f32x4 acc[7];
#pragma unroll
    for (int n = 0; n < 7; ++n) acc[n] = (f32x4){0.f, 0.f, 0.f, 0.f};

    bf16x8 apf[4];                        // rotating A prefetch, depth 3
    LOAD_A1(0, 0);
    LOAD_A1(1, 1);
    LOAD_A1(2, 2);

#pragma unroll
    for (int seg = 0; seg < 3; ++seg) {
#pragma unroll
        for (int ph = 0; ph < 2; ++ph) {
            if (seg + ph) __syncthreads();     // all waves done reading old Wl
            if (ph == 0) {
                // stage k 0..127: 112 cols x 16 int4 = 1792 units (7/thread)
#pragma unroll
                for (int it = 0; it < 7; ++it) {
                    int u = tid + it * 256;
                    int col = u >> 4, kq = u & 15;
                    *(int4*)(&Wl[col * 136 + kq * 8]) =
                        *(const int4*)(WT + (size_t)(colbase + col) * 672 + seg * 224 + kq * 8);
                }
            } else {
                // stage k 128..223: 112 cols x 12 int4 = 1344 units
                for (int u = tid; u < 1344; u += 256) {
                    int col = u / 12, kq = u - col * 12;
                    *(int4*)(&Wl[col * 136 + kq * 8]) =
                        *(const int4*)(WT + (size_t)(colbase + col) * 672 + seg * 224 + 128 + kq * 8);
                }
            }
            __syncthreads();
            const int NC = (ph == 0) ? 4 : 3;
#pragma unroll
            for (int cc = 0; cc < NC; ++cc) {
                const int g = seg * 7 + (ph ? 4 : 0) + cc;     // literal after unroll
                if (g + 3 < 21) LOAD_A1(g + 3, (g + 3) & 3);
#pragma unroll
                for (int n = 0; n < 7; ++n) {
                    bf16x8 b = *(const bf16x8*)(&Wl[(n * 16 + lr) * 136 + cc * 32 + lq * 8]);
                    acc[n] = __builtin_amdgcn_mfma_f32_16x16x32_bf16(apf[g & 3], b, acc[n], 0, 0, 0);
                }
            }
        }
    }

    {
        int rbase = row0 + wm * 16 + lq * 4;
#pragma unroll
        for (int n = 0; n < 7; ++n) {
            int col = colbase + n * 16 + lr;
            if (col < 200) {
                float lvc = lv[col], bc = bias[col];
#pragma unroll
                for (int r2 = 0; r2 < 4; ++r2) {
                    int row = rbase + r2;
                    if (row < N_ENT) {
                        float v = (acc[n][r2] - lvc) * (1.0f / 3.0f) + bc;
                        out[(size_t)row * 200 + col] = f2b(fast_tanh(v));
                    }
                }
            }
        }
    }
}

// ---------------------------------------------------------------------------
// build ConvE input images with BN0 (bf16 out)
// ---------------------------------------------------------------------------
__global__ void img_kernel(const unsigned short* __restrict__ x, const float* __restrict__ r,
                           const int* __restrict__ sub, const int* __restrict__ rel,
                           const float* __restrict__ bn0g, const float* __restrict__ bn0b,
                           unsigned short* __restrict__ img) {
    int g = blockIdx.x * 256 + threadIdx.x;
    if (g >= BB * 2 * DIM) return;
    int b = g / 400, l = g - b * 400;
    int d = l >> 1;
    float v = (l & 1) ? r[(size_t)rel[b] * DIM + d] : b2f(x[(size_t)sub[b] * DIM + d]);
    float s0 = bn0g[0] * rsqrtf(1.0f + EPS_BN);
    img[g] = f2b(v * s0 + bn0b[0]);
}

// ---------------------------------------------------------------------------
// im2col: IM[b*196+p][64], k = i*7+j (49 real, 64 padded with zeros)
// ---------------------------------------------------------------------------
__global__ void im2col_kernel(const unsigned short* __restrict__ img,
                              unsigned short* __restrict__ IM) {
    int g = blockIdx.x * 256 + threadIdx.x;
    if (g >= 50176 * 64) return;
    int row = g >> 6, k = g & 63;
    int b = row / 196, p = row - b * 196;
    int h = p / 14, w = p - h * 14;
    unsigned short v = 0;
    if (k < 49) {
        int i = k / 7, j = k - i * 7;
        v = img[b * 400 + (h + i) * 20 + (w + j)];
    }
    IM[g] = v;
}

// CWT[208][64] bf16: CWT[f][k] = conv_w[f][k], zero-padded
__global__ void cwt_kernel(const float* __restrict__ cw, unsigned short* __restrict__ CWT) {
    int g = blockIdx.x * 256 + threadIdx.x;
    if (g >= 208 * 64) return;
    int f = g >> 6, k = g & 63;
    CWT[g] = (f < 200 && k < 49) ? f2b(cw[f * 49 + k]) : 0;
}

// ---------------------------------------------------------------------------
// conv as MFMA: [50176 x 64] @ [64 x 200(pad 208)], zero-LDS/zero-barrier.
// Epilogue: +conv_b, BN1, relu, write CO_B[b][f*196+p] bf16 (fc A-layout).
// ---------------------------------------------------------------------------
__global__ __launch_bounds__(256) void conv_mfma_kernel(
        const unsigned short* __restrict__ IM, const unsigned short* __restrict__ CWT,
        const float* __restrict__ cb, const float* __restrict__ bn1g,
        const float* __restrict__ bn1b, unsigned short* __restrict__ CO_B) {
    const int tid  = threadIdx.x;
    const int row0 = blockIdx.x * 128;
    const int wave = tid >> 6;
    const int lane = tid & 63;
    const int lr   = lane & 15;
    const int lq   = lane >> 4;
    const int arow = row0 + wave * 32 + lr;

    f32x4 acc[2][13];
#pragma unroll
    for (int m = 0; m < 2; ++m)
#pragma unroll
        for (int n = 0; n < 13; ++n) acc[m][n] = (f32x4){0.f, 0.f, 0.f, 0.f};

#pragma unroll
    for (int c = 0; c < 2; ++c) {
        const int k = c * 32 + lq * 8;
        bf16x8 a0 = *(const bf16x8*)(IM + (size_t)arow * 64 + k);
        bf16x8 a1 = *(const bf16x8*)(IM + (size_t)(arow + 16) * 64 + k);
#pragma unroll
        for (int n = 0; n < 13; ++n) {
            bf16x8 b = *(const bf16x8*)(CWT + (size_t)(n * 16 + lr) * 64 + k);
            acc[0][n] = __builtin_amdgcn_mfma_f32_16x16x32_bf16(a0, b, acc[0][n], 0, 0, 0);
            acc[1][n] = __builtin_amdgcn_mfma_f32_16x16x32_bf16(a1, b, acc[1][n], 0, 0, 0);
        }
    }

#pragma unroll
    for (int m = 0; m < 2; ++m) {
        int grow_base = row0 + wave * 32 + m * 16 + lq * 4;
#pragma unroll
        for (int n = 0; n < 13; ++n) {
            int col = n * 16 + lr;          // filter
            if (col < 200) {
                float s1 = bn1g[col] * rsqrtf(1.0f + EPS_BN);
                float t1 = bn1b[col];
                float cbf = cb[col];
#pragma unroll
                for (int r = 0; r < 4; ++r) {
                    int grow = grow_base + r;          // b*196+p, always < 50176
                    int b = grow / 196, p = grow - b * 196;
                    float v = fmaxf((acc[m][n][r] + cbf) * s1 + t1, 0.f);
                    CO_B[(size_t)b * FLATK + col * 196 + p] = f2b(v);
                }
            }
        }
    }
}

// ---------------------------------------------------------------------------
// fc as MFMA split-K: [256 x 39200] @ [39200 x 208], 175 k-chunks x 4 m-blocks.
// ---------------------------------------------------------------------------
__global__ __launch_bounds__(256) void fc_mfma_kernel(
        const unsigned short* __restrict__ CO_B, const unsigned short* __restrict__ FWT,
        float* __restrict__ partials) {
    const int tid  = threadIdx.x;
    const int kc   = blockIdx.x >> 2;
    const int mb   = blockIdx.x & 3;
    const int wave = tid >> 6;
    const int lane = tid & 63;
    const int lr   = lane & 15;
    const int lq   = lane >> 4;
    const int m0   = mb * 64 + wave * 16;

    f32x4 acc[13];
#pragma unroll
    for (int n = 0; n < 13; ++n) acc[n] = (f32x4){0.f, 0.f, 0.f, 0.f};

#pragma unroll
    for (int s = 0; s < 7; ++s) {
        const int k = kc * FC_KLEN + s * 32 + lq * 8;
        bf16x8 a = *(const bf16x8*)(CO_B + (size_t)(m0 + lr) * FLATK + k);
#pragma unroll
        for (int n = 0; n < 13; ++n) {
            bf16x8 b = *(const bf16x8*)(FWT + (size_t)(n * 16 + lr) * FLATK + k);
            acc[n] = __builtin_amdgcn_mfma_f32_16x16x32_bf16(a, b, acc[n], 0, 0, 0);
        }
    }

    float* slab = partials + (size_t)kc * (BB * 208);
#pragma unroll
    for (int n = 0; n < 13; ++n) {
        int col = n * 16 + lr;
#pragma unroll
        for (int r = 0; r < 4; ++r) {
            int row = m0 + lq * 4 + r;
            slab[(size_t)row * 208 + col] = acc[n][r];
        }
    }
}

// hb16[b][j=224] = relu((sum_kc partial + fc_b)*bn2s+bn2b) bf16, pad j>=200
__global__ void fc_reduce_kernel(const float* __restrict__ partials,
                                 const float* __restrict__ fcb,
                                 const float* __restrict__ g2, const float* __restrict__ b2v,
                                 unsigned short* __restrict__ hb) {
    int g = blockIdx.x * 256 + threadIdx.x;
    if (g >= BB * 224) return;
    int b = g / 224, j = g - b * 224;
    unsigned short o = 0;
    if (j < 200) {
        float s = 0.f;
        const float* p = partials + (size_t)b * 208 + j;
#pragma unroll 5
        for (int c = 0; c < FC_KC; ++c)
            s += p[(size_t)c * (BB * 208)];
        float v = (s + fcb[j]) * (g2[j] * rsqrtf(1.0f + EPS_BN)) + b2v[j];
        o = f2b(fmaxf(v, 0.f));
    }
    hb[g] = o;
}

// ---------------------------------------------------------------------------
// logits MFMA v2: D[b][ent] = sigmoid(h[b]·x[ent] + eb[ent]).
// 893 blocks x 512 thr (8 waves = 2 batch-halves x 4 row-groups).
// Block tile: 256 batch x 112 ents; x-slice staged in LDS [112][136]
// (30.5 KB, coalesced contiguous reads), A=hb via rotating reg prefetch.
// ---------------------------------------------------------------------------
#define LOAD_HB(g, buf) do {                                                    \
    const unsigned short* base_ = hb + (size_t)brow * 224 + (g) * 32 + lq * 8;  \
    buf[0] = *(const bf16x8*)(base_);                                           \
    buf[1] = *(const bf16x8*)(base_ + 16 * 224);                                \
} while (0)

__global__ __launch_bounds__(512, 2) void logits_mfma_kernel(
        const unsigned short* __restrict__ x, const unsigned short* __restrict__ hb,
        const float* __restrict__ eb, float* __restrict__ out, int nwg) {
    __shared__ unsigned short Xl[112 * 136];          // 30,464 B
    const int bid = blockIdx.x;
    const int q = nwg >> 3, rr = nwg & 7;
    const int xcd = bid & 7, idx = bid >> 3;
    const int nb = (xcd < rr ? xcd * (q + 1) : rr * (q + 1) + (xcd - rr) * q) + idx;
    const int ent0 = nb * 112;

    const int tid  = threadIdx.x;
    const int wave = tid >> 6;
    const int mh   = wave >> 2;          // batch half (0/1)
    const int wm   = wave & 3;           // 32-row group
    const int lane = tid & 63;
    const int lr   = lane & 15;
    const int lq   = lane >> 4;
    const int brow = mh * 128 + wm * 32 + lr;

    f32x4 acc[2][7];
#pragma unroll
    for (int m = 0; m < 2; ++m)
#pragma unroll
        for (int n = 0; n < 7; ++n) acc[m][n] = (f32x4){0.f, 0.f, 0.f, 0.f};

    bf16x8 apf[3][2];                     // rotating A prefetch, depth 2
    LOAD_HB(0, apf[0]);
    LOAD_HB(1, apf[1]);

#pragma unroll
    for (int ph = 0; ph < 2; ++ph) {
        if (ph) __syncthreads();
        if (ph == 0) {
            // stage k 0..127: 112 rows x 16 int4 units (contiguous per row)
#pragma unroll
            for (int it = 0; it < 4; ++it) {
                int u = tid + it * 512;
                if (u < 1792) {
                    int row = u >> 4, c = u & 15;
                    int ent = ent0 + row;
                    int4 v = make_int4(0, 0, 0, 0);
                    if (ent < N_ENT)
                        v = *(const int4*)(x + (size_t)ent * 200 + c * 8);
                    *(int4*)(&Xl[row * 136 + c * 8]) = v;
                }
            }
        } else {
            // stage k 128..223: units 16..27 (real to unit 24, then zeros)
            for (int u = tid; u < 1344; u += 512) {
                int row = u / 12, c = u - row * 12;
                int gu = 16 + c;
                int ent = ent0 + row;
                int4 v = make_int4(0, 0, 0, 0);
                if (ent < N_ENT && gu < 25)
                    v = *(const int4*)(x + (size_t)ent * 200 + gu * 8);
                *(int4*)(&Xl[row * 136 + c * 8]) = v;
            }
        }
        __syncthreads();
        const int NC = (ph == 0) ? 4 : 3;
#pragma unroll
        for (int cc = 0; cc < NC; ++cc) {
            const int g = (ph ? 4 : 0) + cc;
            if (g + 2 < 7) LOAD_HB(g + 2, apf[(g + 2) % 3]);
#pragma unroll
            for (int n = 0; n < 7; ++n) {
                bf16x8 b = *(const bf16x8*)(&Xl[(n * 16 + lr) * 136 + cc * 32 + lq * 8]);
                acc[0][n] = __builtin_amdgcn_mfma_f32_16x16x32_bf16(apf[g % 3][0], b, acc[0][n], 0, 0, 0);
                acc[1][n] = __builtin_amdgcn_mfma_f32_16x16x32_bf16(apf[g % 3][1], b, acc[1][n], 0, 0, 0);
            }
        }
    }

#pragma unroll
    for (int m = 0; m < 2; ++m) {
        int b_base = mh * 128 + wm * 32 + m * 16 + lq * 4;
#pragma unroll
        for (int n = 0; n < 7; ++n) {
            int ent = ent0 + n * 16 + lr;
            if (ent < N_ENT) {
                float bias = eb[ent];
#pragma unroll
                for (int r = 0; r < 4; ++r) {
                    float v = acc[m][n][r] + bias;
                    out[(size_t)(b_base + r) * N_ENT + ent] = 1.0f / (1.0f + __expf(-v));
                }
            }
        }
    }
}

// ---------------------------------------------------------------------------
extern "C" void kernel_launch(void* const* d_in, const int* in_sizes, int n_in,
                              void* d_out, int out_size, void* d_ws, size_t ws_size,
                              hipStream_t stream) {
    const int*   sub        = (const int*)  d_in[0];
    const int*   rel        = (const int*)  d_in[1];
    const int*   edge_index = (const int*)  d_in[2];
    const int*   edge_type  = (const int*)  d_in[3];
    const float* init_embed = (const float*)d_in[4];
    const float* init_rel   = (const float*)d_in[5];
    const float* loop_rel1  = (const float*)d_in[6];
    const float* loop_rel2  = (const float*)d_in[7];
    const float* w_in1      = (const float*)d_in[8];
    const float* w_out1     = (const float*)d_in[9];
    const float* w_loop1    = (const float*)d_in[10];
    const float* w_rel1     = (const float*)d_in[11];
    const float* b1         = (const float*)d_in[12];
    const float* w_in2      = (const float*)d_in[13];
    const float* w_out2     = (const float*)d_in[14];
    const float* w_loop2    = (const float*)d_in[15];
    const float* w_rel2     = (const float*)d_in[16];
    const float* b2         = (const float*)d_in[17];
    const float* conv_w     = (const float*)d_in[18];
    const float* conv_b     = (const float*)d_in[19];
    const float* bn0_g      = (const float*)d_in[20];
    const float* bn0_b      = (const float*)d_in[21];
    const float* bn1_g      = (const float*)d_in[22];
    const float* bn1_b      = (const float*)d_in[23];
    const float* bn2_g      = (const float*)d_in[24];
    const float* bn2_b      = (const float*)d_in[25];
    const float* fc_w       = (const float*)d_in[26];
    const float* fc_b       = (const float*)d_in[27];
    const float* ent_bias   = (const float*)d_in[28];

    // ---- bf16 region ----
    unsigned short* aggb = (unsigned short*)d_ws;     // 40,000,000
    unsigned short* x0b  = aggb + 40000000;           // 20,000,000 (init; reused as x2b)
    unsigned short* x1b  = x0b  + 20000000;           // 20,000,000
    unsigned short* r0b  = x1b  + 20000000;           //    200,000
    unsigned short* r1b  = r0b  + 200000;             //    200,000
    unsigned short* WT   = r1b  + 200000;             //    150,528 (224*672)
    unsigned short* img  = WT   + 150528;             //    102,400
    unsigned short* IM   = img  + 102400;             //  3,211,264 (50176*64)
    unsigned short* CWT  = IM   + 3211264;            //     13,312
    unsigned short* CO_B = CWT  + 13312;              // 10,035,200 (256*39200)
    unsigned short* hb16 = CO_B + 10035200;           //     57,344 (256*224)
    unsigned short* FWT  = hb16 + 57344;              //  8,153,600 (208*39200)
    // ---- fp32 region ----
    float* fbase = (float*)(FWT + 8153600);
    float* r1f      = fbase;                          // 200,000
    float* r2f      = r1f  + 200000;                  // 200,000
    float* lv       = r2f  + 200000;                  // 256
    float* partials = lv   + 256;                     // 9,318,400 (175*256*208)

    // CSR ints alias CO_B (last CSR read = gather2, before conv writes CO_B)
    int2* epair    = (int2*)CO_B;                     // 500,000 int2
    int* cnt       = (int*)(epair + E_TOT);           // 200,000
    int* row_start = cnt  + NROWS;                    // 200,000
    int* row_cur   = row_start + NROWS;               // 200,000
    int* blockSum  = row_cur + NROWS;                 // 98

    unsigned short* aggIb = aggb;
    unsigned short* aggOb = aggb + (size_t)N_ENT * DIM;
    unsigned short* x2b   = x0b;

    const int gather_blocks = (NROWS + 3) / 4;
    const int layer_nwg     = ((N_ENT + 63) / 64) * 2;     // 3126 (64-row tiles x 2 col-halves)
    const int logits_nwg    = (N_ENT + 111) / 112;         // 893
    const int wstack_blocks = (224 * 672 + 255) / 256;

    // ---- converts + CSR build ----
    convert_kernel<<<(N_ENT * DIM + 1023) / 1024, 256, 0, stream>>>(init_embed, x0b, N_ENT * DIM);
    convert_kernel<<<(N_REL2 * DIM + 1023) / 1024, 256, 0, stream>>>(init_rel, r0b, N_REL2 * DIM);
    hipMemsetAsync(cnt, 0, (size_t)NROWS * 4, stream);
    hist_kernel<<<(E_TOT + 255) / 256, 256, 0, stream>>>(edge_index, cnt);
    scan1_kernel<<<SNBLK, 256, 0, stream>>>(cnt, row_start, blockSum);
    scan2_kernel<<<1, 1, 0, stream>>>(blockSum);
    scan3_kernel<<<(NROWS + 255) / 256, 256, 0, stream>>>(row_start, row_cur, blockSum);
    fill_kernel<<<(E_TOT + 255) / 256, 256, 0, stream>>>(edge_index, edge_type, row_cur, epair);

    // ---- layer 1 ----
    wstack_kernel<<<wstack_blocks, 256, 0, stream>>>(w_in1, w_out1, w_loop1, WT);
    gather_kernel<<<gather_blocks, 256, 0, stream>>>(x0b, r0b, epair, row_start, cnt, aggb);
    lv_kernel<<<1, 256, 0, stream>>>(loop_rel1, w_loop1, lv);
    layer_mfma_kernel<<<layer_nwg, 256, 0, stream>>>(aggIb, aggOb, x0b, WT, lv, b1, x1b, layer_nwg);
    rgemm_kernel<<<(N_REL2 * DIM + 255) / 256, 256, 0, stream>>>(init_rel, w_rel1, r1f, N_REL2);
    convert_kernel<<<(N_REL2 * DIM + 1023) / 1024, 256, 0, stream>>>(r1f, r1b, N_REL2 * DIM);

    // ---- layer 2 ----
    wstack_kernel<<<wstack_blocks, 256, 0, stream>>>(w_in2, w_out2, w_loop2, WT);
    gather_kernel<<<gather_blocks, 256, 0, stream>>>(x1b, r1b, epair, row_start, cnt, aggb);
    lv_kernel<<<1, 256, 0, stream>>>(loop_rel2, w_loop2, lv);
    layer_mfma_kernel<<<layer_nwg, 256, 0, stream>>>(aggIb, aggOb, x1b, WT, lv, b2, x2b, layer_nwg);
    rgemm_kernel<<<(N_REL2 * DIM + 255) / 256, 256, 0, stream>>>(r1f, w_rel2, r2f, N_REL2);

    // ---- ConvE ----
    img_kernel<<<(BB * 400 + 255) / 256, 256, 0, stream>>>(x2b, r2f, sub, rel,
                                                           bn0_g, bn0_b, img);
    im2col_kernel<<<(50176 * 64 + 255) / 256, 256, 0, stream>>>(img, IM);
    cwt_kernel<<<(208 * 64 + 255) / 256, 256, 0, stream>>>(conv_w, CWT);
    conv_mfma_kernel<<<50176 / 128, 256, 0, stream>>>(IM, CWT, conv_b, bn1_g, bn1_b, CO_B);
    fwt_kernel<<<1225 * 7, 256, 0, stream>>>(fc_w, FWT);
    fc_mfma_kernel<<<FC_KC * 4, 256, 0, stream>>>(CO_B, FWT, partials);
    fc_reduce_kernel<<<(BB * 224 + 255) / 256, 256, 0, stream>>>(partials, fc_b, bn2_g, bn2_b, hb16);

    // ---- logits ----
    logits_mfma_kernel<<<logits_nwg, 512, 0, stream>>>(x2b, hb16, ent_bias, (float*)d_out,
                                                       logits_nwg);
}